// Round 1
// baseline (1001.135 us; speedup 1.0000x reference)
//
#include <hip/hip_runtime.h>
#include <stdint.h>

// ---------------------------------------------------------------- helpers
__device__ __forceinline__ float bf_lo(uint32_t w) { return __uint_as_float(w << 16); }
__device__ __forceinline__ float bf_hi(uint32_t w) { return __uint_as_float(w & 0xffff0000u); }
__device__ __forceinline__ uint16_t f2bf(float f) {
    uint32_t u = __float_as_uint(f);
    uint32_t r = ((u >> 16) & 1u) + 0x7fffu;   // round-to-nearest-even
    return (uint16_t)((u + r) >> 16);
}

#define GF_SIG  1
#define GF_BF16 2

// ---------------------------------------------------------------- GEMM
// C[M,Nc] = (A .* A2?)[M,128] @ W[128,Nc]  (+sigmoid(x+bias))  (store f32 or bf16)
// BM=BN=128, BK=32, 256 threads, 8x8 per thread.
__global__ __launch_bounds__(256) void gemm_k(
    const float* __restrict__ A, const float* __restrict__ A2,
    const float* __restrict__ W, const float* __restrict__ bias,
    void* __restrict__ Cout, int M, int Nc, int flags)
{
    __shared__ float As[128][33];   // pad 33: reads (row+k)%32 conflict-free
    __shared__ float Ws[32][132];   // pad 132: 16B-aligned rows for float4
    const int tid = threadIdx.x;
    const int tx = tid & 15, ty = tid >> 4;
    const int m0 = blockIdx.x * 128;
    const int n0 = blockIdx.y * 128;

    float acc[8][8] = {};

    for (int k0 = 0; k0 < 128; k0 += 32) {
        // stage A (optionally elementwise product): 128x32
#pragma unroll
        for (int i = 0; i < 4; i++) {
            int idx = tid + i * 256;
            int row = idx >> 3;
            int kq  = (idx & 7) << 2;
            float4 v = make_float4(0.f, 0.f, 0.f, 0.f);
            int gm = m0 + row;
            if (gm < M) {
                v = *reinterpret_cast<const float4*>(A + (size_t)gm * 128 + k0 + kq);
                if (A2) {
                    float4 u = *reinterpret_cast<const float4*>(A2 + (size_t)gm * 128 + k0 + kq);
                    v.x *= u.x; v.y *= u.y; v.z *= u.z; v.w *= u.w;
                }
            }
            As[row][kq + 0] = v.x; As[row][kq + 1] = v.y;
            As[row][kq + 2] = v.z; As[row][kq + 3] = v.w;
        }
        // stage W: 32x128
#pragma unroll
        for (int i = 0; i < 4; i++) {
            int idx = tid + i * 256;
            int kr = idx >> 5;
            int nq = (idx & 31) << 2;
            float4 v = *reinterpret_cast<const float4*>(W + (size_t)(k0 + kr) * Nc + n0 + nq);
            *reinterpret_cast<float4*>(&Ws[kr][nq]) = v;
        }
        __syncthreads();
#pragma unroll 8
        for (int k = 0; k < 32; k++) {
            float a[8], w[8];
#pragma unroll
            for (int i = 0; i < 8; i++) a[i] = As[ty * 8 + i][k];
            *reinterpret_cast<float4*>(&w[0]) = *reinterpret_cast<const float4*>(&Ws[k][tx * 8]);
            *reinterpret_cast<float4*>(&w[4]) = *reinterpret_cast<const float4*>(&Ws[k][tx * 8 + 4]);
#pragma unroll
            for (int i = 0; i < 8; i++)
#pragma unroll
                for (int j = 0; j < 8; j++)
                    acc[i][j] = fmaf(a[i], w[j], acc[i][j]);
        }
        __syncthreads();
    }

    const bool sig  = (flags & GF_SIG) != 0;
    const bool tobf = (flags & GF_BF16) != 0;
#pragma unroll
    for (int i = 0; i < 8; i++) {
        int gm = m0 + ty * 8 + i;
        if (gm >= M) continue;
#pragma unroll
        for (int jq = 0; jq < 8; jq += 4) {
            int c = n0 + tx * 8 + jq;
            float v[4];
#pragma unroll
            for (int j = 0; j < 4; j++) {
                float x = acc[i][jq + j];
                if (sig) x = 1.f / (1.f + __expf(-(x + bias[c + j])));
                v[j] = x;
            }
            if (tobf) {
                ushort4 o;
                o.x = f2bf(v[0]); o.y = f2bf(v[1]); o.z = f2bf(v[2]); o.w = f2bf(v[3]);
                *reinterpret_cast<ushort4*>((uint16_t*)Cout + (size_t)gm * Nc + c) = o;
            } else {
                float4 o = make_float4(v[0], v[1], v[2], v[3]);
                *reinterpret_cast<float4*>((float*)Cout + (size_t)gm * Nc + c) = o;
            }
        }
    }
}

// ---------------------------------------------------------------- D x 8 bias projection: B[M,8] = A[M,128] @ w[128,8]
__global__ __launch_bounds__(256) void bias8_k(
    const float* __restrict__ A, const float* __restrict__ w, float* __restrict__ B, int M)
{
    int lane = threadIdx.x & 63;
    int row = blockIdx.x * 4 + (threadIdx.x >> 6);
    if (row >= M) return;
    float2 x = *reinterpret_cast<const float2*>(A + (size_t)row * 128 + 2 * lane);
    const float4* wp = reinterpret_cast<const float4*>(w + (size_t)(2 * lane) * 8);
    float4 wa0 = wp[0], wa1 = wp[1];   // row 2*lane
    float4 wb0 = wp[2], wb1 = wp[3];   // row 2*lane+1
    float p[8];
    p[0] = x.x * wa0.x + x.y * wb0.x;  p[1] = x.x * wa0.y + x.y * wb0.y;
    p[2] = x.x * wa0.z + x.y * wb0.z;  p[3] = x.x * wa0.w + x.y * wb0.w;
    p[4] = x.x * wa1.x + x.y * wb1.x;  p[5] = x.x * wa1.y + x.y * wb1.y;
    p[6] = x.x * wa1.z + x.y * wb1.z;  p[7] = x.x * wa1.w + x.y * wb1.w;
    float r = 0.f;
#pragma unroll
    for (int h = 0; h < 8; h++) {
        float v = p[h];
        v += __shfl_xor(v, 1);  v += __shfl_xor(v, 2);  v += __shfl_xor(v, 4);
        v += __shfl_xor(v, 8);  v += __shfl_xor(v, 16); v += __shfl_xor(v, 32);
        if (lane == h) r = v;
    }
    if (lane < 8) B[(size_t)row * 8 + lane] = r;
}

// ---------------------------------------------------------------- add + LayerNorm (row-wise, D=128)
__global__ __launch_bounds__(256) void addln_k(
    const float* __restrict__ X, const float* __restrict__ Y,
    const float* __restrict__ g, const float* __restrict__ b,
    float* __restrict__ O, int M)
{
    int lane = threadIdx.x & 63;
    int row = blockIdx.x * 4 + (threadIdx.x >> 6);
    if (row >= M) return;
    size_t base = (size_t)row * 128 + 2 * lane;
    float2 xa = *reinterpret_cast<const float2*>(X + base);
    float2 ya = *reinterpret_cast<const float2*>(Y + base);
    float t0 = xa.x + ya.x, t1 = xa.y + ya.y;
    float s = t0 + t1;
#pragma unroll
    for (int o = 1; o < 64; o <<= 1) s += __shfl_xor(s, o);
    float mean = s * (1.f / 128.f);
    float d0 = t0 - mean, d1 = t1 - mean;
    float q = d0 * d0 + d1 * d1;
#pragma unroll
    for (int o = 1; o < 64; o <<= 1) q += __shfl_xor(q, o);
    float rstd = rsqrtf(q * (1.f / 128.f) + 1e-5f);
    float2 gg = *reinterpret_cast<const float2*>(g + 2 * lane);
    float2 bb = *reinterpret_cast<const float2*>(b + 2 * lane);
    float2 o2 = make_float2(gg.x * d0 * rstd + bb.x, gg.y * d1 * rstd + bb.y);
    *reinterpret_cast<float2*>(O + base) = o2;
}

// ---------------------------------------------------------------- CSR build
__global__ void hist_k(const int* __restrict__ idx, int* __restrict__ cnt, int E)
{
    int i = blockIdx.x * blockDim.x + threadIdx.x;
    if (i < E) atomicAdd(&cnt[idx[i]], 1);
}

__global__ __launch_bounds__(1024) void scan_k(
    const int* __restrict__ cnt, int* __restrict__ offs, int* __restrict__ cur, int N)
{
    __shared__ int buf[1024];
    int t = threadIdx.x;
    int running = 0;
    int nIter = (N + 1023) >> 10;
    for (int it = 0; it < nIter; it++) {
        int i = (it << 10) + t;
        int v = (i < N) ? cnt[i] : 0;
        buf[t] = v;
        __syncthreads();
        for (int off = 1; off < 1024; off <<= 1) {
            int x = (t >= off) ? buf[t - off] : 0;
            __syncthreads();
            buf[t] += x;
            __syncthreads();
        }
        int excl = buf[t] - v;
        if (i < N) { offs[i] = running + excl; cur[i] = running + excl; }
        running += buf[1023];
        __syncthreads();
    }
    if (t == 0) offs[N] = running;
}

__global__ void scatter_k(const int* __restrict__ seg, const int* __restrict__ pay,
                          int* __restrict__ cur, int* __restrict__ sorted, int E)
{
    int i = blockIdx.x * blockDim.x + threadIdx.x;
    if (i < E) {
        int p = atomicAdd(&cur[seg[i]], 1);
        sorted[p] = pay[i];
    }
}

// ---------------------------------------------------------------- self-attention over nbr edges (one wave per node, online softmax)
__global__ __launch_bounds__(256) void self_attn_k(
    const uint16_t* __restrict__ qkv, const float* __restrict__ bias1,
    const int* __restrict__ offs, const int* __restrict__ sdst,
    float* __restrict__ out, int N)
{
    int lane = threadIdx.x & 63;
    int n = blockIdx.x * 4 + (threadIdx.x >> 6);
    if (n >= N) return;
    uint32_t qw = *reinterpret_cast<const uint32_t*>(qkv + (size_t)n * 384 + 2 * lane);
    float q0 = bf_lo(qw), q1 = bf_hi(qw);
    float bs = bias1[(size_t)n * 8 + (lane >> 3)];
    int e0 = offs[n], e1 = offs[n + 1];
    float m = -1e30f, den = 0.f, a0 = 0.f, a1 = 0.f;
    for (int e = e0; e < e1; e++) {
        int dst = sdst[e];
        const uint16_t* kp = qkv + (size_t)dst * 384;
        uint32_t kw = *reinterpret_cast<const uint32_t*>(kp + 128 + 2 * lane);
        uint32_t vw = *reinterpret_cast<const uint32_t*>(kp + 256 + 2 * lane);
        float p = q0 * bf_lo(kw) + q1 * bf_hi(kw);
        p += __shfl_xor(p, 1); p += __shfl_xor(p, 2); p += __shfl_xor(p, 4);
        float s = p * 0.25f + bs;
        float mn = fmaxf(m, s);
        float c  = __expf(m - mn);
        float ex = __expf(s - mn);
        a0 = a0 * c + ex * bf_lo(vw);
        a1 = a1 * c + ex * bf_hi(vw);
        den = den * c + ex;
        m = mn;
    }
    float inv = 1.f / (den + 1e-12f);
    size_t ob = (size_t)n * 128 + 2 * lane;
    out[ob] = a0 * inv;
    out[ob + 1] = a1 * inv;
}

// ---------------------------------------------------------------- cross-attention over inc edges
__global__ __launch_bounds__(256) void cross_attn_k(
    const float* __restrict__ Qc, const float* __restrict__ bias_t,
    const uint16_t* __restrict__ KV, const float* __restrict__ bias_s,
    const uint16_t* __restrict__ gsrc,
    const int* __restrict__ offs, const int* __restrict__ ssrc,
    float* __restrict__ out_c, int N)
{
    int lane = threadIdx.x & 63;
    int n = blockIdx.x * 4 + (threadIdx.x >> 6);
    if (n >= N) return;
    float2 q = *reinterpret_cast<const float2*>(Qc + (size_t)n * 128 + 2 * lane);
    float bt = bias_t[(size_t)n * 8 + (lane >> 3)];
    int e0 = offs[n], e1 = offs[n + 1];
    float m = -1e30f, den = 0.f, a0 = 0.f, a1 = 0.f;
    for (int e = e0; e < e1; e++) {
        int src = ssrc[e];
        const uint16_t* kp = KV + (size_t)src * 256;
        uint32_t kw = *reinterpret_cast<const uint32_t*>(kp + 2 * lane);
        uint32_t vw = *reinterpret_cast<const uint32_t*>(kp + 128 + 2 * lane);
        uint32_t gw = *reinterpret_cast<const uint32_t*>(gsrc + (size_t)src * 128 + 2 * lane);
        float bss = bias_s[(size_t)src * 8 + (lane >> 3)];
        float p = q.x * bf_lo(kw) + q.y * bf_hi(kw);
        p += __shfl_xor(p, 1); p += __shfl_xor(p, 2); p += __shfl_xor(p, 4);
        float s = p * 0.25f + bt + bss;
        float mn = fmaxf(m, s);
        float c  = __expf(m - mn);
        float ex = __expf(s - mn);
        a0 = a0 * c + ex * (bf_lo(gw) * bf_lo(vw));
        a1 = a1 * c + ex * (bf_hi(gw) * bf_hi(vw));
        den = den * c + ex;
        m = mn;
    }
    float inv = 1.f / (den + 1e-12f);
    size_t ob = (size_t)n * 128 + 2 * lane;
    out_c[ob] = a0 * inv;
    out_c[ob + 1] = a1 * inv;
}

// ---------------------------------------------------------------- host
static inline size_t smax_(size_t a, size_t b) { return a > b ? a : b; }

extern "C" void kernel_launch(void* const* d_in, const int* in_sizes, int n_in,
                              void* d_out, int out_size, void* d_ws, size_t ws_size,
                              hipStream_t stream)
{
    const float* X          = (const float*)d_in[0];
    const float* Xs         = (const float*)d_in[1];
    const float* W_qkv      = (const float*)d_in[2];
    const float* w_bias     = (const float*)d_in[3];
    const float* W_gate     = (const float*)d_in[4];
    const float* b_gate     = (const float*)d_in[5];
    const float* W_o        = (const float*)d_in[6];
    const float* W_q        = (const float*)d_in[7];
    const float* W_kv       = (const float*)d_in[8];
    const float* w_bias_tgt = (const float*)d_in[9];
    const float* w_bias_src = (const float*)d_in[10];
    const float* W_gate_tgt = (const float*)d_in[11];
    const float* b_gate_tgt = (const float*)d_in[12];
    const float* W_gate_src = (const float*)d_in[13];
    const float* b_gate_src = (const float*)d_in[14];
    const float* W_o2       = (const float*)d_in[15];
    const float* ln1_g      = (const float*)d_in[16];
    const float* ln1_b      = (const float*)d_in[17];
    const float* ln2_g      = (const float*)d_in[18];
    const float* ln2_b      = (const float*)d_in[19];
    const int* nbr_src      = (const int*)d_in[20];
    const int* nbr_dst      = (const int*)d_in[21];
    const int* inc_tgt      = (const int*)d_in[22];
    const int* inc_src      = (const int*)d_in[23];

    const int N  = in_sizes[0] / 128;
    const int NS = in_sizes[1] / 128;
    const int E1 = in_sizes[20];
    const int E2 = in_sizes[22];

    char* ws = (char*)d_ws;
    size_t off = 0;
    auto alloc = [&](size_t bytes) -> void* {
        void* p = ws + off;
        off = (off + bytes + 255) & ~(size_t)255;
        return p;
    };

    // R1: qkv (bf16, N x 384)  /  KV (bf16, NS x 256)
    uint16_t* qkv16 = (uint16_t*)alloc(smax_((size_t)N * 384, (size_t)NS * 256) * 2);
    uint16_t* kv16  = qkv16;
    // R2: gate (f32 N x128) / g_src (bf16 NS x128) / ca (f32 N x128)
    void* R2 = alloc(smax_((size_t)N * 128 * 4, smax_((size_t)NS * 128 * 2, (size_t)N * 128 * 4)));
    float*    gate   = (float*)R2;
    uint16_t* gsrc16 = (uint16_t*)R2;
    float*    ca     = (float*)R2;
    // R3: sa / Qc  (f32 N x128)
    float* saQc = (float*)alloc((size_t)N * 128 * 4);
    // R4: out / out_c (f32 N x128)
    float* outb = (float*)alloc((size_t)N * 128 * 4);
    // R5: h (f32 N x128)
    float* hbuf = (float*)alloc((size_t)N * 128 * 4);
    // R6: bias1 / bias_tgt  (f32 N x 8)
    float* b8a = (float*)alloc((size_t)N * 8 * 4);
    // R7: bias_src (f32 NS x 8)
    float* b8s = (float*)alloc((size_t)NS * 8 * 4);
    // R8: g_tgt (f32 N x128)
    float* gtgt = (float*)alloc((size_t)N * 128 * 4);
    // CSR
    int* cnt    = (int*)alloc((size_t)N * 4);           // also reused as cursor
    int* offs   = (int*)alloc((size_t)(N + 1) * 4);
    int* sorted = (int*)alloc((size_t)(E1 > E2 ? E1 : E2) * 4);
    (void)ws_size; (void)n_in; (void)out_size;

    const int gA  = (N + 127) / 128;
    const int gAs = (NS + 127) / 128;
    const int gW  = (N + 3) / 4;
    const int gWs = (NS + 3) / 4;

    // ---- CSR for nbr edges
    hipMemsetAsync(cnt, 0, (size_t)N * 4, stream);
    hist_k<<<(E1 + 255) / 256, 256, 0, stream>>>(nbr_src, cnt, E1);
    scan_k<<<1, 1024, 0, stream>>>(cnt, offs, cnt, N);
    scatter_k<<<(E1 + 255) / 256, 256, 0, stream>>>(nbr_src, nbr_dst, cnt, sorted, E1);

    // ---- stage 1: projections of X
    gemm_k<<<dim3(gA, 3), 256, 0, stream>>>(X, nullptr, W_qkv, nullptr, qkv16, N, 384, GF_BF16);
    bias8_k<<<gW, 256, 0, stream>>>(X, w_bias, b8a, N);
    gemm_k<<<dim3(gA, 1), 256, 0, stream>>>(X, nullptr, W_gate, b_gate, gate, N, 128, GF_SIG);

    // ---- self-attention
    self_attn_k<<<gW, 256, 0, stream>>>(qkv16, b8a, offs, sorted, outb, N);
    gemm_k<<<dim3(gA, 1), 256, 0, stream>>>(gate, outb, W_o, nullptr, saQc, N, 128, 0);
    addln_k<<<gW, 256, 0, stream>>>(X, saQc, ln1_g, ln1_b, hbuf, N);

    // ---- stage 2 projections
    gemm_k<<<dim3(gA, 1), 256, 0, stream>>>(hbuf, nullptr, W_q, nullptr, saQc, N, 128, 0);      // Qc
    bias8_k<<<gW, 256, 0, stream>>>(hbuf, w_bias_tgt, b8a, N);
    gemm_k<<<dim3(gA, 1), 256, 0, stream>>>(hbuf, nullptr, W_gate_tgt, b_gate_tgt, gtgt, N, 128, GF_SIG);
    gemm_k<<<dim3(gAs, 2), 256, 0, stream>>>(Xs, nullptr, W_kv, nullptr, kv16, NS, 256, GF_BF16);
    bias8_k<<<gWs, 256, 0, stream>>>(Xs, w_bias_src, b8s, NS);
    gemm_k<<<dim3(gAs, 1), 256, 0, stream>>>(Xs, nullptr, W_gate_src, b_gate_src, gsrc16, NS, 128, GF_SIG | GF_BF16);

    // ---- CSR for inc edges
    hipMemsetAsync(cnt, 0, (size_t)N * 4, stream);
    hist_k<<<(E2 + 255) / 256, 256, 0, stream>>>(inc_tgt, cnt, E2);
    scan_k<<<1, 1024, 0, stream>>>(cnt, offs, cnt, N);
    scatter_k<<<(E2 + 255) / 256, 256, 0, stream>>>(inc_tgt, inc_src, cnt, sorted, E2);

    // ---- cross-attention
    cross_attn_k<<<gW, 256, 0, stream>>>(saQc, b8a, kv16, b8s, gsrc16, offs, sorted, outb, N);
    gemm_k<<<dim3(gA, 1), 256, 0, stream>>>(gtgt, outb, W_o2, nullptr, ca, N, 128, 0);
    addln_k<<<gW, 256, 0, stream>>>(hbuf, ca, ln2_g, ln2_b, (float*)d_out, N);
}

// Round 2
// 613.323 us; speedup vs baseline: 1.6323x; 1.6323x over previous
//
#include <hip/hip_runtime.h>
#include <stdint.h>

// ---------------------------------------------------------------- helpers
__device__ __forceinline__ float bf_lo(uint32_t w) { return __uint_as_float(w << 16); }
__device__ __forceinline__ float bf_hi(uint32_t w) { return __uint_as_float(w & 0xffff0000u); }
__device__ __forceinline__ uint16_t f2bf(float f) {
    uint32_t u = __float_as_uint(f);
    uint32_t r = ((u >> 16) & 1u) + 0x7fffu;   // round-to-nearest-even
    return (uint16_t)((u + r) >> 16);
}
__device__ __forceinline__ void gload_lds16(const void* g, void* l) {
    __builtin_amdgcn_global_load_lds(
        (const __attribute__((address_space(1))) void*)g,
        (__attribute__((address_space(3))) void*)l, 16, 0, 0);
}

typedef __attribute__((ext_vector_type(8))) short bf16x8;
typedef __attribute__((ext_vector_type(4))) float f32x4;

#define GF_SIG  1
#define GF_BF16 2

// ---------------------------------------------------------------- MFMA GEMM
// C[M,Nc] = A[M,128](bf16) @ W[128,Nc]; WT is W^T stored [Nc][128] bf16.
// One 128x128 output tile per block; whole K=128 staged in LDS (no K loop).
// Operands swapped (D = C^T) so each lane's 4 acc elems are 4 consecutive
// columns -> vectorized epilogue stores. XOR swizzle (chunk ^= row&7) applied
// on the GLOBAL source during global_load_lds staging + on ds_read (rule #21).
__global__ __launch_bounds__(256) void gemm_mfma_k(
    const uint16_t* __restrict__ A,   // [Mpad][128] bf16
    const uint16_t* __restrict__ WT,  // [Nc][128]  bf16
    const float* __restrict__ bias,   // for GF_SIG
    void* __restrict__ C, int M, int Nc, int flags)
{
    __shared__ uint16_t As[128 * 128];   // 32 KB
    __shared__ uint16_t Ws[128 * 128];   // 32 KB
    const int tid = threadIdx.x;
    const int wid = tid >> 6;
    const int lane = tid & 63;
    const int m0 = blockIdx.x * 128;
    const int n0 = blockIdx.y * 128;

    {
        const uint16_t* Ab = A + (size_t)m0 * 128;
        const uint16_t* Wb = WT + (size_t)n0 * 128;
#pragma unroll
        for (int it = 0; it < 8; ++it) {
            int idx = it * 256 + tid;          // 16B-chunk index (2048 per tile)
            int r = idx >> 4, c = idx & 15;
            int gc = c ^ (r & 7);              // inverse-swizzled source
            uint16_t* ldsA = As + (size_t)(it * 256 + wid * 64) * 8;  // wave-uniform base
            uint16_t* ldsW = Ws + (size_t)(it * 256 + wid * 64) * 8;
            gload_lds16(Ab + (size_t)r * 128 + gc * 8, ldsA);
            gload_lds16(Wb + (size_t)r * 128 + gc * 8, ldsW);
        }
    }
    __syncthreads();

    const int wr = wid >> 1, wc = wid & 1;     // 2x2 waves, 64x64 each
    const int l15 = lane & 15, l4 = lane >> 4;

    f32x4 acc[4][4];                           // [ni][mi]
#pragma unroll
    for (int i = 0; i < 4; i++)
#pragma unroll
        for (int j = 0; j < 4; j++) acc[i][j] = (f32x4){0.f, 0.f, 0.f, 0.f};

#pragma unroll
    for (int kk = 0; kk < 4; ++kk) {
        bf16x8 af[4], bff[4];
#pragma unroll
        for (int ni = 0; ni < 4; ++ni) {
            int r = wc * 64 + ni * 16 + l15;
            int cc = (kk * 4 + l4) ^ (r & 7);
            af[ni] = *(const bf16x8*)(Ws + r * 128 + cc * 8);
        }
#pragma unroll
        for (int mi = 0; mi < 4; ++mi) {
            int r = wr * 64 + mi * 16 + l15;
            int cc = (kk * 4 + l4) ^ (r & 7);
            bff[mi] = *(const bf16x8*)(As + r * 128 + cc * 8);
        }
#pragma unroll
        for (int ni = 0; ni < 4; ++ni)
#pragma unroll
            for (int mi = 0; mi < 4; ++mi)
                acc[ni][mi] = __builtin_amdgcn_mfma_f32_16x16x32_bf16(
                    af[ni], bff[mi], acc[ni][mi], 0, 0, 0);
    }

    const bool sig  = (flags & GF_SIG) != 0;
    const bool tobf = (flags & GF_BF16) != 0;
#pragma unroll
    for (int mi = 0; mi < 4; ++mi) {
        int gm = m0 + wr * 64 + mi * 16 + l15;
        if (gm >= M) continue;
#pragma unroll
        for (int ni = 0; ni < 4; ++ni) {
            int gn = n0 + wc * 64 + ni * 16 + l4 * 4;
            f32x4 v = acc[ni][mi];
            if (sig) {
                float4 bb = *(const float4*)(bias + gn);
                v.x = 1.f / (1.f + __expf(-(v.x + bb.x)));
                v.y = 1.f / (1.f + __expf(-(v.y + bb.y)));
                v.z = 1.f / (1.f + __expf(-(v.z + bb.z)));
                v.w = 1.f / (1.f + __expf(-(v.w + bb.w)));
            }
            if (tobf) {
                ushort4 o;
                o.x = f2bf(v.x); o.y = f2bf(v.y); o.z = f2bf(v.z); o.w = f2bf(v.w);
                *reinterpret_cast<ushort4*>((uint16_t*)C + (size_t)gm * Nc + gn) = o;
            } else {
                *reinterpret_cast<float4*>((float*)C + (size_t)gm * Nc + gn) =
                    make_float4(v.x, v.y, v.z, v.w);
            }
        }
    }
}

// ---------------------------------------------------------------- casts
__global__ void castbf_k(const float* __restrict__ in, uint16_t* __restrict__ out, int n4)
{
    int i = blockIdx.x * blockDim.x + threadIdx.x;
    int stride = gridDim.x * blockDim.x;
    for (; i < n4; i += stride) {
        float4 v = reinterpret_cast<const float4*>(in)[i];
        ushort4 o;
        o.x = f2bf(v.x); o.y = f2bf(v.y); o.z = f2bf(v.z); o.w = f2bf(v.w);
        reinterpret_cast<ushort4*>(out)[i] = o;
    }
}

// WT[n*128+k] = bf16(W[k*Nc+n])
__global__ void castWT_k(const float* __restrict__ W, uint16_t* __restrict__ WT, int Nc)
{
    int i = blockIdx.x * blockDim.x + threadIdx.x;
    if (i >= 128 * Nc) return;
    int n = i >> 7, k = i & 127;
    WT[i] = f2bf(W[(size_t)k * Nc + n]);
}

// ---------------------------------------------------------------- D x 8 bias projection
__global__ __launch_bounds__(256) void bias8_k(
    const float* __restrict__ Af, const uint16_t* __restrict__ Ab,
    const float* __restrict__ w, float* __restrict__ B, int M)
{
    int lane = threadIdx.x & 63;
    int row = blockIdx.x * 4 + (threadIdx.x >> 6);
    if (row >= M) return;
    float x0, x1;
    if (Ab) {
        uint32_t wv = *reinterpret_cast<const uint32_t*>(Ab + (size_t)row * 128 + 2 * lane);
        x0 = bf_lo(wv); x1 = bf_hi(wv);
    } else {
        float2 x = *reinterpret_cast<const float2*>(Af + (size_t)row * 128 + 2 * lane);
        x0 = x.x; x1 = x.y;
    }
    const float4* wp = reinterpret_cast<const float4*>(w + (size_t)(2 * lane) * 8);
    float4 wa0 = wp[0], wa1 = wp[1];
    float4 wb0 = wp[2], wb1 = wp[3];
    float p[8];
    p[0] = x0 * wa0.x + x1 * wb0.x;  p[1] = x0 * wa0.y + x1 * wb0.y;
    p[2] = x0 * wa0.z + x1 * wb0.z;  p[3] = x0 * wa0.w + x1 * wb0.w;
    p[4] = x0 * wa1.x + x1 * wb1.x;  p[5] = x0 * wa1.y + x1 * wb1.y;
    p[6] = x0 * wa1.z + x1 * wb1.z;  p[7] = x0 * wa1.w + x1 * wb1.w;
    float r = 0.f;
#pragma unroll
    for (int h = 0; h < 8; h++) {
        float v = p[h];
        v += __shfl_xor(v, 1);  v += __shfl_xor(v, 2);  v += __shfl_xor(v, 4);
        v += __shfl_xor(v, 8);  v += __shfl_xor(v, 16); v += __shfl_xor(v, 32);
        if (lane == h) r = v;
    }
    if (lane < 8) B[(size_t)row * 8 + lane] = r;
}

// ---------------------------------------------------------------- add + LayerNorm
__global__ __launch_bounds__(256) void addln_k(
    const float* __restrict__ Xf, const uint16_t* __restrict__ Xb,
    const float* __restrict__ Y,
    const float* __restrict__ g, const float* __restrict__ b,
    float* __restrict__ Of, uint16_t* __restrict__ Ob, int M)
{
    int lane = threadIdx.x & 63;
    int row = blockIdx.x * 4 + (threadIdx.x >> 6);
    if (row >= M) return;
    size_t base = (size_t)row * 128 + 2 * lane;
    float x0, x1;
    if (Xb) {
        uint32_t wv = *reinterpret_cast<const uint32_t*>(Xb + base);
        x0 = bf_lo(wv); x1 = bf_hi(wv);
    } else {
        float2 xa = *reinterpret_cast<const float2*>(Xf + base);
        x0 = xa.x; x1 = xa.y;
    }
    float2 ya = *reinterpret_cast<const float2*>(Y + base);
    float t0 = x0 + ya.x, t1 = x1 + ya.y;
    float s = t0 + t1;
#pragma unroll
    for (int o = 1; o < 64; o <<= 1) s += __shfl_xor(s, o);
    float mean = s * (1.f / 128.f);
    float d0 = t0 - mean, d1 = t1 - mean;
    float q = d0 * d0 + d1 * d1;
#pragma unroll
    for (int o = 1; o < 64; o <<= 1) q += __shfl_xor(q, o);
    float rstd = rsqrtf(q * (1.f / 128.f) + 1e-5f);
    float2 gg = *reinterpret_cast<const float2*>(g + 2 * lane);
    float2 bb = *reinterpret_cast<const float2*>(b + 2 * lane);
    float o0 = gg.x * d0 * rstd + bb.x, o1 = gg.y * d1 * rstd + bb.y;
    if (Of) *reinterpret_cast<float2*>(Of + base) = make_float2(o0, o1);
    if (Ob) {
        uint32_t pk = (uint32_t)f2bf(o0) | ((uint32_t)f2bf(o1) << 16);
        *reinterpret_cast<uint32_t*>(Ob + base) = pk;
    }
}

// ---------------------------------------------------------------- CSR build
__global__ void hist_k(const int* __restrict__ idx, int* __restrict__ cnt, int E)
{
    int i = blockIdx.x * blockDim.x + threadIdx.x;
    if (i < E) atomicAdd(&cnt[idx[i]], 1);
}

__global__ __launch_bounds__(1024) void scan_k(
    const int* __restrict__ cnt, int* __restrict__ offs, int* __restrict__ cur, int N)
{
    __shared__ int wsum[16], wpre[17];
    int t = threadIdx.x, wid = t >> 6, lane = t & 63;
    int running = 0;
    int nIter = (N + 1023) >> 10;
    for (int it = 0; it < nIter; ++it) {
        int i = (it << 10) + t;
        int v = (i < N) ? cnt[i] : 0;
        int s = v;
#pragma unroll
        for (int o = 1; o < 64; o <<= 1) { int x = __shfl_up(s, o); if (lane >= o) s += x; }
        if (lane == 63) wsum[wid] = s;
        __syncthreads();
        if (wid == 0) {
            int w = (lane < 16) ? wsum[lane] : 0;
            int ws_ = w;
#pragma unroll
            for (int o = 1; o < 16; o <<= 1) { int x = __shfl_up(ws_, o); if (lane >= o) ws_ += x; }
            if (lane < 16) wpre[lane] = ws_ - w;
            if (lane == 15) wpre[16] = ws_;
        }
        __syncthreads();
        int excl = running + wpre[wid] + (s - v);
        if (i < N) { offs[i] = excl; cur[i] = excl; }
        running += wpre[16];
        __syncthreads();
    }
    if (t == 0) offs[N] = running;
}

__global__ void scatter_k(const int* __restrict__ seg, const int* __restrict__ pay,
                          int* __restrict__ cur, int* __restrict__ sorted, int E)
{
    int i = blockIdx.x * blockDim.x + threadIdx.x;
    if (i < E) {
        int p = atomicAdd(&cur[seg[i]], 1);
        sorted[p] = pay[i];
    }
}

// ---------------------------------------------------------------- self-attention (dual online-softmax states, fused gate-mul + bf16 out)
__global__ __launch_bounds__(256) void self_attn_k(
    const uint16_t* __restrict__ qkv, const float* __restrict__ bias1,
    const int* __restrict__ offs, const int* __restrict__ sdst,
    const float* __restrict__ gate, uint16_t* __restrict__ Aout, int N)
{
    int lane = threadIdx.x & 63;
    int n = blockIdx.x * 4 + (threadIdx.x >> 6);
    if (n >= N) return;
    uint32_t qw = *reinterpret_cast<const uint32_t*>(qkv + (size_t)n * 384 + 2 * lane);
    float q0 = bf_lo(qw), q1 = bf_hi(qw);
    float bs = bias1[(size_t)n * 8 + (lane >> 3)];
    int e0 = offs[n], e1 = offs[n + 1];
    float m1 = -1e30f, d1 = 0.f, p1a = 0.f, p1b = 0.f;
    float m2 = -1e30f, d2 = 0.f, p2a = 0.f, p2b = 0.f;
    int e = e0;
    for (; e + 2 <= e1; e += 2) {
        int dA = sdst[e], dB = sdst[e + 1];
        const uint16_t* kA = qkv + (size_t)dA * 384;
        const uint16_t* kB = qkv + (size_t)dB * 384;
        uint32_t kwA = *reinterpret_cast<const uint32_t*>(kA + 128 + 2 * lane);
        uint32_t vwA = *reinterpret_cast<const uint32_t*>(kA + 256 + 2 * lane);
        uint32_t kwB = *reinterpret_cast<const uint32_t*>(kB + 128 + 2 * lane);
        uint32_t vwB = *reinterpret_cast<const uint32_t*>(kB + 256 + 2 * lane);
        float sA = q0 * bf_lo(kwA) + q1 * bf_hi(kwA);
        float sB = q0 * bf_lo(kwB) + q1 * bf_hi(kwB);
        sA += __shfl_xor(sA, 1); sA += __shfl_xor(sA, 2); sA += __shfl_xor(sA, 4);
        sB += __shfl_xor(sB, 1); sB += __shfl_xor(sB, 2); sB += __shfl_xor(sB, 4);
        sA = sA * 0.25f + bs;    sB = sB * 0.25f + bs;
        float mnA = fmaxf(m1, sA), mnB = fmaxf(m2, sB);
        float cA = __expf(m1 - mnA), exA = __expf(sA - mnA);
        float cB = __expf(m2 - mnB), exB = __expf(sB - mnB);
        p1a = p1a * cA + exA * bf_lo(vwA); p1b = p1b * cA + exA * bf_hi(vwA);
        d1 = d1 * cA + exA; m1 = mnA;
        p2a = p2a * cB + exB * bf_lo(vwB); p2b = p2b * cB + exB * bf_hi(vwB);
        d2 = d2 * cB + exB; m2 = mnB;
    }
    if (e < e1) {
        int dA = sdst[e];
        const uint16_t* kA = qkv + (size_t)dA * 384;
        uint32_t kwA = *reinterpret_cast<const uint32_t*>(kA + 128 + 2 * lane);
        uint32_t vwA = *reinterpret_cast<const uint32_t*>(kA + 256 + 2 * lane);
        float sA = q0 * bf_lo(kwA) + q1 * bf_hi(kwA);
        sA += __shfl_xor(sA, 1); sA += __shfl_xor(sA, 2); sA += __shfl_xor(sA, 4);
        sA = sA * 0.25f + bs;
        float mnA = fmaxf(m1, sA);
        float cA = __expf(m1 - mnA), exA = __expf(sA - mnA);
        p1a = p1a * cA + exA * bf_lo(vwA); p1b = p1b * cA + exA * bf_hi(vwA);
        d1 = d1 * cA + exA; m1 = mnA;
    }
    float mn = fmaxf(m1, m2);
    float c1 = __expf(m1 - mn), c2 = __expf(m2 - mn);
    float den = d1 * c1 + d2 * c2;
    float a0 = p1a * c1 + p2a * c2, a1 = p1b * c1 + p2b * c2;
    float inv = 1.f / (den + 1e-12f);
    float2 g = *reinterpret_cast<const float2*>(gate + (size_t)n * 128 + 2 * lane);
    a0 *= inv * g.x; a1 *= inv * g.y;
    uint32_t pk = (uint32_t)f2bf(a0) | ((uint32_t)f2bf(a1) << 16);
    *reinterpret_cast<uint32_t*>(Aout + (size_t)n * 128 + 2 * lane) = pk;
}

// ---------------------------------------------------------------- cross-attention (dual states, fused g_tgt-mul + bf16 out)
__global__ __launch_bounds__(256) void cross_attn_k(
    const float* __restrict__ Qc, const float* __restrict__ bias_t,
    const uint16_t* __restrict__ KV, const float* __restrict__ bias_s,
    const uint16_t* __restrict__ gsrc,
    const int* __restrict__ offs, const int* __restrict__ ssrc,
    const float* __restrict__ gtgt, uint16_t* __restrict__ Aout, int N)
{
    int lane = threadIdx.x & 63;
    int n = blockIdx.x * 4 + (threadIdx.x >> 6);
    if (n >= N) return;
    float2 q = *reinterpret_cast<const float2*>(Qc + (size_t)n * 128 + 2 * lane);
    float bt = bias_t[(size_t)n * 8 + (lane >> 3)];
    int e0 = offs[n], e1 = offs[n + 1];
    float m1 = -1e30f, d1 = 0.f, p1a = 0.f, p1b = 0.f;
    float m2 = -1e30f, d2 = 0.f, p2a = 0.f, p2b = 0.f;
    int e = e0;
    for (; e + 2 <= e1; e += 2) {
        int sa_ = ssrc[e], sb_ = ssrc[e + 1];
        const uint16_t* kA = KV + (size_t)sa_ * 256;
        const uint16_t* kB = KV + (size_t)sb_ * 256;
        uint32_t kwA = *reinterpret_cast<const uint32_t*>(kA + 2 * lane);
        uint32_t vwA = *reinterpret_cast<const uint32_t*>(kA + 128 + 2 * lane);
        uint32_t gwA = *reinterpret_cast<const uint32_t*>(gsrc + (size_t)sa_ * 128 + 2 * lane);
        uint32_t kwB = *reinterpret_cast<const uint32_t*>(kB + 2 * lane);
        uint32_t vwB = *reinterpret_cast<const uint32_t*>(kB + 128 + 2 * lane);
        uint32_t gwB = *reinterpret_cast<const uint32_t*>(gsrc + (size_t)sb_ * 128 + 2 * lane);
        float bsA = bias_s[(size_t)sa_ * 8 + (lane >> 3)];
        float bsB = bias_s[(size_t)sb_ * 8 + (lane >> 3)];
        float sA = q.x * bf_lo(kwA) + q.y * bf_hi(kwA);
        float sB = q.x * bf_lo(kwB) + q.y * bf_hi(kwB);
        sA += __shfl_xor(sA, 1); sA += __shfl_xor(sA, 2); sA += __shfl_xor(sA, 4);
        sB += __shfl_xor(sB, 1); sB += __shfl_xor(sB, 2); sB += __shfl_xor(sB, 4);
        sA = sA * 0.25f + bt + bsA;  sB = sB * 0.25f + bt + bsB;
        float mnA = fmaxf(m1, sA), mnB = fmaxf(m2, sB);
        float cA = __expf(m1 - mnA), exA = __expf(sA - mnA);
        float cB = __expf(m2 - mnB), exB = __expf(sB - mnB);
        p1a = p1a * cA + exA * (bf_lo(gwA) * bf_lo(vwA));
        p1b = p1b * cA + exA * (bf_hi(gwA) * bf_hi(vwA));
        d1 = d1 * cA + exA; m1 = mnA;
        p2a = p2a * cB + exB * (bf_lo(gwB) * bf_lo(vwB));
        p2b = p2b * cB + exB * (bf_hi(gwB) * bf_hi(vwB));
        d2 = d2 * cB + exB; m2 = mnB;
    }
    if (e < e1) {
        int sa_ = ssrc[e];
        const uint16_t* kA = KV + (size_t)sa_ * 256;
        uint32_t kwA = *reinterpret_cast<const uint32_t*>(kA + 2 * lane);
        uint32_t vwA = *reinterpret_cast<const uint32_t*>(kA + 128 + 2 * lane);
        uint32_t gwA = *reinterpret_cast<const uint32_t*>(gsrc + (size_t)sa_ * 128 + 2 * lane);
        float bsA = bias_s[(size_t)sa_ * 8 + (lane >> 3)];
        float sA = q.x * bf_lo(kwA) + q.y * bf_hi(kwA);
        sA += __shfl_xor(sA, 1); sA += __shfl_xor(sA, 2); sA += __shfl_xor(sA, 4);
        sA = sA * 0.25f + bt + bsA;
        float mnA = fmaxf(m1, sA);
        float cA = __expf(m1 - mnA), exA = __expf(sA - mnA);
        p1a = p1a * cA + exA * (bf_lo(gwA) * bf_lo(vwA));
        p1b = p1b * cA + exA * (bf_hi(gwA) * bf_hi(vwA));
        d1 = d1 * cA + exA; m1 = mnA;
    }
    float mn = fmaxf(m1, m2);
    float c1 = __expf(m1 - mn), c2 = __expf(m2 - mn);
    float den = d1 * c1 + d2 * c2;
    float a0 = p1a * c1 + p2a * c2, a1 = p1b * c1 + p2b * c2;
    float inv = 1.f / (den + 1e-12f);
    float2 g = *reinterpret_cast<const float2*>(gtgt + (size_t)n * 128 + 2 * lane);
    a0 *= inv * g.x; a1 *= inv * g.y;
    uint32_t pk = (uint32_t)f2bf(a0) | ((uint32_t)f2bf(a1) << 16);
    *reinterpret_cast<uint32_t*>(Aout + (size_t)n * 128 + 2 * lane) = pk;
}

// ---------------------------------------------------------------- host
static inline size_t smax_(size_t a, size_t b) { return a > b ? a : b; }

extern "C" void kernel_launch(void* const* d_in, const int* in_sizes, int n_in,
                              void* d_out, int out_size, void* d_ws, size_t ws_size,
                              hipStream_t stream)
{
    const float* X          = (const float*)d_in[0];
    const float* Xs         = (const float*)d_in[1];
    const float* W_qkv      = (const float*)d_in[2];
    const float* w_bias     = (const float*)d_in[3];
    const float* W_gate     = (const float*)d_in[4];
    const float* b_gate     = (const float*)d_in[5];
    const float* W_o        = (const float*)d_in[6];
    const float* W_q        = (const float*)d_in[7];
    const float* W_kv       = (const float*)d_in[8];
    const float* w_bias_tgt = (const float*)d_in[9];
    const float* w_bias_src = (const float*)d_in[10];
    const float* W_gate_tgt = (const float*)d_in[11];
    const float* b_gate_tgt = (const float*)d_in[12];
    const float* W_gate_src = (const float*)d_in[13];
    const float* b_gate_src = (const float*)d_in[14];
    const float* W_o2       = (const float*)d_in[15];
    const float* ln1_g      = (const float*)d_in[16];
    const float* ln1_b      = (const float*)d_in[17];
    const float* ln2_g      = (const float*)d_in[18];
    const float* ln2_b      = (const float*)d_in[19];
    const int* nbr_src      = (const int*)d_in[20];
    const int* nbr_dst      = (const int*)d_in[21];
    const int* inc_tgt      = (const int*)d_in[22];
    const int* inc_src      = (const int*)d_in[23];

    const int N  = in_sizes[0] / 128;
    const int NS = in_sizes[1] / 128;
    const int E1 = in_sizes[20];
    const int E2 = in_sizes[22];
    const int Npad  = (N + 127) & ~127;
    const int NSpad = (NS + 127) & ~127;

    char* ws = (char*)d_ws;
    size_t off = 0;
    auto alloc = [&](size_t bytes) -> void* {
        void* p = ws + off;
        off = (off + bytes + 255) & ~(size_t)255;
        return p;
    };

    uint16_t* Xb   = (uint16_t*)alloc((size_t)Npad * 128 * 2);
    uint16_t* Xsb  = (uint16_t*)alloc((size_t)NSpad * 128 * 2);
    uint16_t* WTq  = (uint16_t*)alloc((size_t)384 * 128 * 2);
    uint16_t* WTg  = (uint16_t*)alloc((size_t)128 * 128 * 2);
    uint16_t* WTo  = (uint16_t*)alloc((size_t)128 * 128 * 2);
    uint16_t* WTq2 = (uint16_t*)alloc((size_t)128 * 128 * 2);
    uint16_t* WTgt = (uint16_t*)alloc((size_t)128 * 128 * 2);
    uint16_t* WTkv = (uint16_t*)alloc((size_t)256 * 128 * 2);
    uint16_t* WTgs = (uint16_t*)alloc((size_t)128 * 128 * 2);
    uint16_t* WTo2 = (uint16_t*)alloc((size_t)128 * 128 * 2);
    // S1: qkv16 [N,384] bf16, later kv16 [NS,256] bf16
    uint16_t* S1 = (uint16_t*)alloc(smax_((size_t)N * 384, (size_t)NS * 256) * 2);
    uint16_t* qkv16 = S1;
    uint16_t* kv16  = S1;
    // S2: gate f32 [N,128] -> sa f32 [N,128] -> gsrc16 bf16 [NS,128] -> ca f32 [N,128]
    void* S2 = alloc(smax_((size_t)N * 128 * 4, (size_t)NS * 128 * 2));
    float*    gate   = (float*)S2;
    float*    sa     = (float*)S2;
    uint16_t* gsrc16 = (uint16_t*)S2;
    float*    ca     = (float*)S2;
    float*    Qc   = (float*)alloc((size_t)N * 128 * 4);
    uint16_t* Awo  = (uint16_t*)alloc((size_t)Npad * 128 * 2);   // gate*out / gtgt*out_c, bf16
    uint16_t* hb   = (uint16_t*)alloc((size_t)Npad * 128 * 2);   // h bf16
    float*    b8a  = (float*)alloc((size_t)N * 8 * 4);
    float*    b8s  = (float*)alloc((size_t)NS * 8 * 4);
    float*    gtgt = (float*)alloc((size_t)N * 128 * 4);
    int* cnt    = (int*)alloc((size_t)N * 4);
    int* offs   = (int*)alloc((size_t)(N + 1) * 4);
    int* sorted = (int*)alloc((size_t)(E1 > E2 ? E1 : E2) * 4);
    (void)ws_size; (void)n_in; (void)out_size;

    const int gA  = Npad / 128;
    const int gAs = NSpad / 128;
    const int gW  = (N + 3) / 4;
    const int gWs = (NS + 3) / 4;

    // ---- prep: casts
    castbf_k<<<2048, 256, 0, stream>>>(X,  Xb,  N * 32);
    castbf_k<<<2048, 256, 0, stream>>>(Xs, Xsb, NS * 32);
    castWT_k<<<(128 * 384 + 255) / 256, 256, 0, stream>>>(W_qkv, WTq, 384);
    castWT_k<<<64, 256, 0, stream>>>(W_gate, WTg, 128);
    castWT_k<<<64, 256, 0, stream>>>(W_o, WTo, 128);
    castWT_k<<<64, 256, 0, stream>>>(W_q, WTq2, 128);
    castWT_k<<<64, 256, 0, stream>>>(W_gate_tgt, WTgt, 128);
    castWT_k<<<(128 * 256 + 255) / 256, 256, 0, stream>>>(W_kv, WTkv, 256);
    castWT_k<<<64, 256, 0, stream>>>(W_gate_src, WTgs, 128);
    castWT_k<<<64, 256, 0, stream>>>(W_o2, WTo2, 128);

    // ---- CSR for nbr edges
    hipMemsetAsync(cnt, 0, (size_t)N * 4, stream);
    hist_k<<<(E1 + 255) / 256, 256, 0, stream>>>(nbr_src, cnt, E1);
    scan_k<<<1, 1024, 0, stream>>>(cnt, offs, cnt, N);
    scatter_k<<<(E1 + 255) / 256, 256, 0, stream>>>(nbr_src, nbr_dst, cnt, sorted, E1);

    // ---- stage 1 projections
    gemm_mfma_k<<<dim3(gA, 3), 256, 0, stream>>>(Xb, WTq, nullptr, qkv16, N, 384, GF_BF16);
    bias8_k<<<gW, 256, 0, stream>>>(X, nullptr, w_bias, b8a, N);
    gemm_mfma_k<<<dim3(gA, 1), 256, 0, stream>>>(Xb, WTg, b_gate, gate, N, 128, GF_SIG);

    // ---- self-attention (writes gate*out as bf16 A for W_o)
    self_attn_k<<<gW, 256, 0, stream>>>(qkv16, b8a, offs, sorted, gate, Awo, N);
    gemm_mfma_k<<<dim3(gA, 1), 256, 0, stream>>>(Awo, WTo, nullptr, sa, N, 128, 0);
    addln_k<<<gW, 256, 0, stream>>>(X, nullptr, sa, ln1_g, ln1_b, nullptr, hb, N);

    // ---- stage 2 projections
    gemm_mfma_k<<<dim3(gA, 1), 256, 0, stream>>>(hb, WTq2, nullptr, Qc, N, 128, 0);
    bias8_k<<<gW, 256, 0, stream>>>(nullptr, hb, w_bias_tgt, b8a, N);
    gemm_mfma_k<<<dim3(gA, 1), 256, 0, stream>>>(hb, WTgt, b_gate_tgt, gtgt, N, 128, GF_SIG);
    gemm_mfma_k<<<dim3(gAs, 2), 256, 0, stream>>>(Xsb, WTkv, nullptr, kv16, NS, 256, GF_BF16);
    bias8_k<<<gWs, 256, 0, stream>>>(Xs, nullptr, w_bias_src, b8s, NS);
    gemm_mfma_k<<<dim3(gAs, 1), 256, 0, stream>>>(Xsb, WTgs, b_gate_src, gsrc16, NS, 128, GF_SIG | GF_BF16);

    // ---- CSR for inc edges
    hipMemsetAsync(cnt, 0, (size_t)N * 4, stream);
    hist_k<<<(E2 + 255) / 256, 256, 0, stream>>>(inc_tgt, cnt, E2);
    scan_k<<<1, 1024, 0, stream>>>(cnt, offs, cnt, N);
    scatter_k<<<(E2 + 255) / 256, 256, 0, stream>>>(inc_tgt, inc_src, cnt, sorted, E2);

    // ---- cross-attention (writes gtgt*out_c as bf16 A for W_o2)
    cross_attn_k<<<gW, 256, 0, stream>>>(Qc, b8a, kv16, b8s, gsrc16, offs, sorted, gtgt, Awo, N);
    gemm_mfma_k<<<dim3(gA, 1), 256, 0, stream>>>(Awo, WTo2, nullptr, ca, N, 128, 0);
    addln_k<<<gW, 256, 0, stream>>>(nullptr, hb, ca, ln2_g, ln2_b, (float*)d_out, nullptr, N);
}

// Round 3
// 550.292 us; speedup vs baseline: 1.8193x; 1.1145x over previous
//
#include <hip/hip_runtime.h>
#include <stdint.h>

// ---------------------------------------------------------------- helpers
__device__ __forceinline__ float bf_lo(uint32_t w) { return __uint_as_float(w << 16); }
__device__ __forceinline__ float bf_hi(uint32_t w) { return __uint_as_float(w & 0xffff0000u); }
__device__ __forceinline__ float bfu(uint16_t u) { return __uint_as_float((uint32_t)u << 16); }
__device__ __forceinline__ uint16_t f2bf(float f) {
    uint32_t u = __float_as_uint(f);
    uint32_t r = ((u >> 16) & 1u) + 0x7fffu;   // round-to-nearest-even
    return (uint16_t)((u + r) >> 16);
}
__device__ __forceinline__ uint32_t pk2bf(float a, float b) {
    return (uint32_t)f2bf(a) | ((uint32_t)f2bf(b) << 16);
}
__device__ __forceinline__ void gload_lds16(const void* g, void* l) {
    __builtin_amdgcn_global_load_lds(
        (const __attribute__((address_space(1))) void*)g,
        (__attribute__((address_space(3))) void*)l, 16, 0, 0);
}

typedef __attribute__((ext_vector_type(8))) short bf16x8;
typedef __attribute__((ext_vector_type(4))) float f32x4;

#define GF_SIG    1
#define GF_BF16   2
#define GF_KVI_K  4
#define GF_KVI_V  8
#define GF_MULV  16

// ---------------------------------------------------------------- MFMA GEMM
// C[M,128-chunk] = A[M,128](bf16) @ W-chunk; WT is W^T [rows][128] bf16.
// One 128x128 tile/block, whole K=128 in LDS. XOR swizzle both-sides (rule 21).
// Store paths: plain f32 / plain bf16 / interleaved-KV bf16 (8B per dim-pair:
// [K2p,K2p+1,V2p,V2p+1]); optional fused sigmoid(+bias) and V-multiply (aux).
__global__ __launch_bounds__(256) void gemm_mfma_k(
    const uint16_t* __restrict__ A,    // [Mpad][128] bf16
    const uint16_t* __restrict__ WT,   // [>=128][128] bf16 (chunk base)
    const float* __restrict__ bias,    // for GF_SIG
    const uint16_t* __restrict__ aux,  // [M][128] bf16, for GF_MULV
    void* __restrict__ C, int M, int Nc, int flags)
{
    __shared__ uint16_t As[128 * 128];
    __shared__ uint16_t Ws[128 * 128];
    const int tid = threadIdx.x;
    const int wid = tid >> 6;
    const int lane = tid & 63;
    const int m0 = blockIdx.x * 128;
    const int n0 = blockIdx.y * 128;

    {
        const uint16_t* Ab = A + (size_t)m0 * 128;
        const uint16_t* Wb = WT + (size_t)n0 * 128;
#pragma unroll
        for (int it = 0; it < 8; ++it) {
            int idx = it * 256 + tid;
            int r = idx >> 4, c = idx & 15;
            int gc = c ^ (r & 7);
            uint16_t* ldsA = As + (size_t)(it * 256 + wid * 64) * 8;
            uint16_t* ldsW = Ws + (size_t)(it * 256 + wid * 64) * 8;
            gload_lds16(Ab + (size_t)r * 128 + gc * 8, ldsA);
            gload_lds16(Wb + (size_t)r * 128 + gc * 8, ldsW);
        }
    }
    __syncthreads();

    const int wr = wid >> 1, wc = wid & 1;
    const int l15 = lane & 15, l4 = lane >> 4;

    f32x4 acc[4][4];
#pragma unroll
    for (int i = 0; i < 4; i++)
#pragma unroll
        for (int j = 0; j < 4; j++) acc[i][j] = (f32x4){0.f, 0.f, 0.f, 0.f};

#pragma unroll
    for (int kk = 0; kk < 4; ++kk) {
        bf16x8 af[4], bff[4];
#pragma unroll
        for (int ni = 0; ni < 4; ++ni) {
            int r = wc * 64 + ni * 16 + l15;
            int cc = (kk * 4 + l4) ^ (r & 7);
            af[ni] = *(const bf16x8*)(Ws + r * 128 + cc * 8);
        }
#pragma unroll
        for (int mi = 0; mi < 4; ++mi) {
            int r = wr * 64 + mi * 16 + l15;
            int cc = (kk * 4 + l4) ^ (r & 7);
            bff[mi] = *(const bf16x8*)(As + r * 128 + cc * 8);
        }
#pragma unroll
        for (int ni = 0; ni < 4; ++ni)
#pragma unroll
            for (int mi = 0; mi < 4; ++mi)
                acc[ni][mi] = __builtin_amdgcn_mfma_f32_16x16x32_bf16(
                    af[ni], bff[mi], acc[ni][mi], 0, 0, 0);
    }

    const bool sig  = (flags & GF_SIG) != 0;
    const bool tobf = (flags & GF_BF16) != 0;
    const bool kvi  = (flags & (GF_KVI_K | GF_KVI_V)) != 0;
    const bool mulv = (flags & GF_MULV) != 0;
    const int  which = (flags & GF_KVI_V) ? 2 : 0;
#pragma unroll
    for (int mi = 0; mi < 4; ++mi) {
        int gm = m0 + wr * 64 + mi * 16 + l15;
        if (gm >= M) continue;
#pragma unroll
        for (int ni = 0; ni < 4; ++ni) {
            int gn = n0 + wc * 64 + ni * 16 + l4 * 4;
            f32x4 v = acc[ni][mi];
            if (sig) {
                float4 bb = *(const float4*)(bias + gn);
                v.x = 1.f / (1.f + __expf(-(v.x + bb.x)));
                v.y = 1.f / (1.f + __expf(-(v.y + bb.y)));
                v.z = 1.f / (1.f + __expf(-(v.z + bb.z)));
                v.w = 1.f / (1.f + __expf(-(v.w + bb.w)));
            }
            if (mulv) {
                ushort4 vs = *(const ushort4*)(aux + (size_t)gm * 128 + gn);
                v.x *= bfu(vs.x); v.y *= bfu(vs.y); v.z *= bfu(vs.z); v.w *= bfu(vs.w);
            }
            if (kvi) {
                uint16_t* op = (uint16_t*)C + (size_t)gm * 256 + gn * 2 + which;
                *reinterpret_cast<uint32_t*>(op)     = pk2bf(v.x, v.y);
                *reinterpret_cast<uint32_t*>(op + 4) = pk2bf(v.z, v.w);
            } else if (tobf) {
                ushort4 o;
                o.x = f2bf(v.x); o.y = f2bf(v.y); o.z = f2bf(v.z); o.w = f2bf(v.w);
                *reinterpret_cast<ushort4*>((uint16_t*)C + (size_t)gm * Nc + gn) = o;
            } else {
                *reinterpret_cast<float4*>((float*)C + (size_t)gm * Nc + gn) =
                    make_float4(v.x, v.y, v.z, v.w);
            }
        }
    }
}

// ---------------------------------------------------------------- casts
__global__ void castbf_k(const float* __restrict__ in, uint16_t* __restrict__ out, int n4)
{
    int i = blockIdx.x * blockDim.x + threadIdx.x;
    int stride = gridDim.x * blockDim.x;
    for (; i < n4; i += stride) {
        float4 v = reinterpret_cast<const float4*>(in)[i];
        ushort4 o;
        o.x = f2bf(v.x); o.y = f2bf(v.y); o.z = f2bf(v.z); o.w = f2bf(v.w);
        reinterpret_cast<ushort4*>(out)[i] = o;
    }
}

// WT[n*128+k] = bf16(W[k*Nc+n])
__global__ void castWT_k(const float* __restrict__ W, uint16_t* __restrict__ WT, int Nc)
{
    int i = blockIdx.x * blockDim.x + threadIdx.x;
    if (i >= 128 * Nc) return;
    int n = i >> 7, k = i & 127;
    WT[i] = f2bf(W[(size_t)k * Nc + n]);
}

// ---------------------------------------------------------------- D x 8 bias projection (bf16 A)
__global__ __launch_bounds__(256) void bias8_k(
    const uint16_t* __restrict__ Ab, const float* __restrict__ w,
    float* __restrict__ B, int M)
{
    int lane = threadIdx.x & 63;
    int row = blockIdx.x * 4 + (threadIdx.x >> 6);
    if (row >= M) return;
    uint32_t wv = *reinterpret_cast<const uint32_t*>(Ab + (size_t)row * 128 + 2 * lane);
    float x0 = bf_lo(wv), x1 = bf_hi(wv);
    const float4* wp = reinterpret_cast<const float4*>(w + (size_t)(2 * lane) * 8);
    float4 wa0 = wp[0], wa1 = wp[1];
    float4 wb0 = wp[2], wb1 = wp[3];
    float p[8];
    p[0] = x0 * wa0.x + x1 * wb0.x;  p[1] = x0 * wa0.y + x1 * wb0.y;
    p[2] = x0 * wa0.z + x1 * wb0.z;  p[3] = x0 * wa0.w + x1 * wb0.w;
    p[4] = x0 * wa1.x + x1 * wb1.x;  p[5] = x0 * wa1.y + x1 * wb1.y;
    p[6] = x0 * wa1.z + x1 * wb1.z;  p[7] = x0 * wa1.w + x1 * wb1.w;
    float r = 0.f;
#pragma unroll
    for (int h = 0; h < 8; h++) {
        float v = p[h];
        v += __shfl_xor(v, 1);  v += __shfl_xor(v, 2);  v += __shfl_xor(v, 4);
        v += __shfl_xor(v, 8);  v += __shfl_xor(v, 16); v += __shfl_xor(v, 32);
        if (lane == h) r = v;
    }
    if (lane < 8) B[(size_t)row * 8 + lane] = r;
}

// ---------------------------------------------------------------- add + LayerNorm
__global__ __launch_bounds__(256) void addln_k(
    const float* __restrict__ Xf, const uint16_t* __restrict__ Xb,
    const float* __restrict__ Y,
    const float* __restrict__ g, const float* __restrict__ b,
    float* __restrict__ Of, uint16_t* __restrict__ Ob, int M)
{
    int lane = threadIdx.x & 63;
    int row = blockIdx.x * 4 + (threadIdx.x >> 6);
    if (row >= M) return;
    size_t base = (size_t)row * 128 + 2 * lane;
    float x0, x1;
    if (Xb) {
        uint32_t wv = *reinterpret_cast<const uint32_t*>(Xb + base);
        x0 = bf_lo(wv); x1 = bf_hi(wv);
    } else {
        float2 xa = *reinterpret_cast<const float2*>(Xf + base);
        x0 = xa.x; x1 = xa.y;
    }
    float2 ya = *reinterpret_cast<const float2*>(Y + base);
    float t0 = x0 + ya.x, t1 = x1 + ya.y;
    float s = t0 + t1;
#pragma unroll
    for (int o = 1; o < 64; o <<= 1) s += __shfl_xor(s, o);
    float mean = s * (1.f / 128.f);
    float d0 = t0 - mean, d1 = t1 - mean;
    float q = d0 * d0 + d1 * d1;
#pragma unroll
    for (int o = 1; o < 64; o <<= 1) q += __shfl_xor(q, o);
    float rstd = rsqrtf(q * (1.f / 128.f) + 1e-5f);
    float2 gg = *reinterpret_cast<const float2*>(g + 2 * lane);
    float2 bb = *reinterpret_cast<const float2*>(b + 2 * lane);
    float o0 = gg.x * d0 * rstd + bb.x, o1 = gg.y * d1 * rstd + bb.y;
    if (Of) *reinterpret_cast<float2*>(Of + base) = make_float2(o0, o1);
    if (Ob) *reinterpret_cast<uint32_t*>(Ob + base) = pk2bf(o0, o1);
}

// ---------------------------------------------------------------- CSR build
__global__ void hist_k(const int* __restrict__ idx, int* __restrict__ cnt, int E)
{
    int i = blockIdx.x * blockDim.x + threadIdx.x;
    if (i < E) atomicAdd(&cnt[idx[i]], 1);
}

// hierarchical scan: 2048 elems/block
__global__ __launch_bounds__(256) void scan1_k(
    const int* __restrict__ cnt, int* __restrict__ pre, int* __restrict__ bsum, int N)
{
    __shared__ int wtot[4];
    int t = threadIdx.x, lane = t & 63, wid = t >> 6;
    int base = blockIdx.x * 2048 + t * 8;
    int v[8];
    if (base + 8 <= N) {
        int4 a = *reinterpret_cast<const int4*>(cnt + base);
        int4 b = *reinterpret_cast<const int4*>(cnt + base + 4);
        v[0] = a.x; v[1] = a.y; v[2] = a.z; v[3] = a.w;
        v[4] = b.x; v[5] = b.y; v[6] = b.z; v[7] = b.w;
    } else {
#pragma unroll
        for (int i = 0; i < 8; i++) v[i] = (base + i < N) ? cnt[base + i] : 0;
    }
    int inc_[8]; int s = 0;
#pragma unroll
    for (int i = 0; i < 8; i++) { s += v[i]; inc_[i] = s; }
    int tot = s;
    int wp = tot;
#pragma unroll
    for (int o = 1; o < 64; o <<= 1) { int x = __shfl_up(wp, o); if (lane >= o) wp += x; }
    if (lane == 63) wtot[wid] = wp;
    __syncthreads();
    int wex = 0;
    for (int w = 0; w < wid; w++) wex += wtot[w];
    int tex = wex + wp - tot;
#pragma unroll
    for (int i = 0; i < 8; i++)
        if (base + i < N) pre[base + i] = tex + inc_[i] - v[i];
    if (t == 255) bsum[blockIdx.x] = wex + wp;
}

__global__ void scan2_k(int* __restrict__ bsum, int B)
{
    int lane = threadIdx.x;
    int v = (lane < B) ? bsum[lane] : 0;
    int s = v;
#pragma unroll
    for (int o = 1; o < 64; o <<= 1) { int x = __shfl_up(s, o); if (lane >= o) s += x; }
    if (lane < B) bsum[lane] = s - v;
}

__global__ __launch_bounds__(256) void scan3_k(
    const int* __restrict__ pre, const int* __restrict__ bsum,
    int* __restrict__ offs, int* __restrict__ cur, int N, int E)
{
    int base = blockIdx.x * 2048 + threadIdx.x * 8;
    int add = bsum[blockIdx.x];
    if (base + 8 <= N) {
        int4 a = *reinterpret_cast<const int4*>(pre + base);
        int4 b = *reinterpret_cast<const int4*>(pre + base + 4);
        a.x += add; a.y += add; a.z += add; a.w += add;
        b.x += add; b.y += add; b.z += add; b.w += add;
        *reinterpret_cast<int4*>(offs + base) = a;
        *reinterpret_cast<int4*>(offs + base + 4) = b;
        *reinterpret_cast<int4*>(cur + base) = a;
        *reinterpret_cast<int4*>(cur + base + 4) = b;
    } else {
#pragma unroll
        for (int i = 0; i < 8; i++)
            if (base + i < N) { int x = pre[base + i] + add; offs[base + i] = x; cur[base + i] = x; }
    }
    if (blockIdx.x == 0 && threadIdx.x == 0) offs[N] = E;
}

__global__ void scatter_k(const int* __restrict__ seg, const int* __restrict__ pay,
                          int* __restrict__ cur, int* __restrict__ sorted, int E)
{
    int i = blockIdx.x * blockDim.x + threadIdx.x;
    if (i < E) {
        int p = atomicAdd(&cur[seg[i]], 1);
        sorted[p] = pay[i];
    }
}

// ---------------------------------------------------------------- edge step (online softmax, one interleaved 8B load)
#define EDGE_STEP(J, IDX)                                                        \
    {                                                                            \
        int dst = sdst[IDX];                                                     \
        uint2 kv = *reinterpret_cast<const uint2*>(kvi + (size_t)dst * 256 + lane * 4); \
        float s = q0 * bf_lo(kv.x) + q1 * bf_hi(kv.x);                           \
        s += __shfl_xor(s, 1); s += __shfl_xor(s, 2); s += __shfl_xor(s, 4);     \
        s = s * 0.25f + bs;                                                      \
        float mn = fmaxf(m##J, s);                                               \
        float c = __expf(m##J - mn), ex = __expf(s - mn);                        \
        pa##J = pa##J * c + ex * bf_lo(kv.y);                                    \
        pb##J = pb##J * c + ex * bf_hi(kv.y);                                    \
        dd##J = dd##J * c + ex; m##J = mn;                                       \
    }

__global__ __launch_bounds__(256) void self_attn_k(
    const uint16_t* __restrict__ Qb, const uint16_t* __restrict__ kvi,
    const float* __restrict__ bias1,
    const int* __restrict__ offs, const int* __restrict__ sdst,
    const uint16_t* __restrict__ g16, uint16_t* __restrict__ Aout, int N)
{
    int lane = threadIdx.x & 63;
    int n = blockIdx.x * 4 + (threadIdx.x >> 6);
    if (n >= N) return;
    uint32_t qw = *reinterpret_cast<const uint32_t*>(Qb + (size_t)n * 128 + 2 * lane);
    float q0 = bf_lo(qw), q1 = bf_hi(qw);
    float bs = bias1[(size_t)n * 8 + (lane >> 3)];
    int e0 = offs[n], e1 = offs[n + 1];
    float m0 = -1e30f, dd0 = 0.f, pa0 = 0.f, pb0 = 0.f;
    float m1 = -1e30f, dd1 = 0.f, pa1 = 0.f, pb1 = 0.f;
    float m2 = -1e30f, dd2 = 0.f, pa2 = 0.f, pb2 = 0.f;
    float m3 = -1e30f, dd3 = 0.f, pa3 = 0.f, pb3 = 0.f;
    int e = e0;
    for (; e + 4 <= e1; e += 4) {
        EDGE_STEP(0, e)
        EDGE_STEP(1, e + 1)
        EDGE_STEP(2, e + 2)
        EDGE_STEP(3, e + 3)
    }
    for (; e < e1; ++e) EDGE_STEP(0, e)
    // merge 4 states
    float mA = fmaxf(m0, m1), cA0 = __expf(m0 - mA), cA1 = __expf(m1 - mA);
    float dA = dd0 * cA0 + dd1 * cA1, paA = pa0 * cA0 + pa1 * cA1, pbA = pb0 * cA0 + pb1 * cA1;
    float mB = fmaxf(m2, m3), cB0 = __expf(m2 - mB), cB1 = __expf(m3 - mB);
    float dB = dd2 * cB0 + dd3 * cB1, paB = pa2 * cB0 + pa3 * cB1, pbB = pb2 * cB0 + pb3 * cB1;
    float mf = fmaxf(mA, mB), cf0 = __expf(mA - mf), cf1 = __expf(mB - mf);
    float den = dA * cf0 + dB * cf1;
    float a0 = paA * cf0 + paB * cf1, a1 = pbA * cf0 + pbB * cf1;
    float inv = 1.f / (den + 1e-12f);
    uint32_t gw = *reinterpret_cast<const uint32_t*>(g16 + (size_t)n * 128 + 2 * lane);
    a0 *= inv * bf_lo(gw); a1 *= inv * bf_hi(gw);
    *reinterpret_cast<uint32_t*>(Aout + (size_t)n * 128 + 2 * lane) = pk2bf(a0, a1);
}

#define CEDGE_STEP(J, IDX)                                                       \
    {                                                                            \
        int src = ssrc[IDX];                                                     \
        uint2 kv = *reinterpret_cast<const uint2*>(kvgi + (size_t)src * 256 + lane * 4); \
        float bss = bias_s[(size_t)src * 8 + (lane >> 3)];                       \
        float s = q0 * bf_lo(kv.x) + q1 * bf_hi(kv.x);                           \
        s += __shfl_xor(s, 1); s += __shfl_xor(s, 2); s += __shfl_xor(s, 4);     \
        s = s * 0.25f + bt + bss;                                                \
        float mn = fmaxf(m##J, s);                                               \
        float c = __expf(m##J - mn), ex = __expf(s - mn);                        \
        pa##J = pa##J * c + ex * bf_lo(kv.y);                                    \
        pb##J = pb##J * c + ex * bf_hi(kv.y);                                    \
        dd##J = dd##J * c + ex; m##J = mn;                                       \
    }

__global__ __launch_bounds__(256) void cross_attn_k(
    const uint16_t* __restrict__ Qcb, const float* __restrict__ bias_t,
    const uint16_t* __restrict__ kvgi, const float* __restrict__ bias_s,
    const int* __restrict__ offs, const int* __restrict__ ssrc,
    const uint16_t* __restrict__ g16, uint16_t* __restrict__ Aout, int N)
{
    int lane = threadIdx.x & 63;
    int n = blockIdx.x * 4 + (threadIdx.x >> 6);
    if (n >= N) return;
    uint32_t qw = *reinterpret_cast<const uint32_t*>(Qcb + (size_t)n * 128 + 2 * lane);
    float q0 = bf_lo(qw), q1 = bf_hi(qw);
    float bt = bias_t[(size_t)n * 8 + (lane >> 3)];
    int e0 = offs[n], e1 = offs[n + 1];
    float m0 = -1e30f, dd0 = 0.f, pa0 = 0.f, pb0 = 0.f;
    float m1 = -1e30f, dd1 = 0.f, pa1 = 0.f, pb1 = 0.f;
    float m2 = -1e30f, dd2 = 0.f, pa2 = 0.f, pb2 = 0.f;
    float m3 = -1e30f, dd3 = 0.f, pa3 = 0.f, pb3 = 0.f;
    int e = e0;
    for (; e + 4 <= e1; e += 4) {
        CEDGE_STEP(0, e)
        CEDGE_STEP(1, e + 1)
        CEDGE_STEP(2, e + 2)
        CEDGE_STEP(3, e + 3)
    }
    for (; e < e1; ++e) CEDGE_STEP(0, e)
    float mA = fmaxf(m0, m1), cA0 = __expf(m0 - mA), cA1 = __expf(m1 - mA);
    float dA = dd0 * cA0 + dd1 * cA1, paA = pa0 * cA0 + pa1 * cA1, pbA = pb0 * cA0 + pb1 * cA1;
    float mB = fmaxf(m2, m3), cB0 = __expf(m2 - mB), cB1 = __expf(m3 - mB);
    float dB = dd2 * cB0 + dd3 * cB1, paB = pa2 * cB0 + pa3 * cB1, pbB = pb2 * cB0 + pb3 * cB1;
    float mf = fmaxf(mA, mB), cf0 = __expf(mA - mf), cf1 = __expf(mB - mf);
    float den = dA * cf0 + dB * cf1;
    float a0 = paA * cf0 + paB * cf1, a1 = pbA * cf0 + pbB * cf1;
    float inv = 1.f / (den + 1e-12f);
    uint32_t gw = *reinterpret_cast<const uint32_t*>(g16 + (size_t)n * 128 + 2 * lane);
    a0 *= inv * bf_lo(gw); a1 *= inv * bf_hi(gw);
    *reinterpret_cast<uint32_t*>(Aout + (size_t)n * 128 + 2 * lane) = pk2bf(a0, a1);
}

// ---------------------------------------------------------------- host
static inline size_t smax_(size_t a, size_t b) { return a > b ? a : b; }

extern "C" void kernel_launch(void* const* d_in, const int* in_sizes, int n_in,
                              void* d_out, int out_size, void* d_ws, size_t ws_size,
                              hipStream_t stream)
{
    const float* X          = (const float*)d_in[0];
    const float* Xs         = (const float*)d_in[1];
    const float* W_qkv      = (const float*)d_in[2];
    const float* w_bias     = (const float*)d_in[3];
    const float* W_gate     = (const float*)d_in[4];
    const float* b_gate     = (const float*)d_in[5];
    const float* W_o        = (const float*)d_in[6];
    const float* W_q        = (const float*)d_in[7];
    const float* W_kv       = (const float*)d_in[8];
    const float* w_bias_tgt = (const float*)d_in[9];
    const float* w_bias_src = (const float*)d_in[10];
    const float* W_gate_tgt = (const float*)d_in[11];
    const float* b_gate_tgt = (const float*)d_in[12];
    const float* W_gate_src = (const float*)d_in[13];
    const float* b_gate_src = (const float*)d_in[14];
    const float* W_o2       = (const float*)d_in[15];
    const float* ln1_g      = (const float*)d_in[16];
    const float* ln1_b      = (const float*)d_in[17];
    const float* ln2_g      = (const float*)d_in[18];
    const float* ln2_b      = (const float*)d_in[19];
    const int* nbr_src      = (const int*)d_in[20];
    const int* nbr_dst      = (const int*)d_in[21];
    const int* inc_tgt      = (const int*)d_in[22];
    const int* inc_src      = (const int*)d_in[23];

    const int N  = in_sizes[0] / 128;
    const int NS = in_sizes[1] / 128;
    const int E1 = in_sizes[20];
    const int E2 = in_sizes[22];
    const int Npad  = (N + 127) & ~127;
    const int NSpad = (NS + 127) & ~127;

    char* ws = (char*)d_ws;
    size_t off = 0;
    auto alloc = [&](size_t bytes) -> void* {
        void* p = ws + off;
        off = (off + bytes + 255) & ~(size_t)255;
        return p;
    };

    uint16_t* Xb   = (uint16_t*)alloc((size_t)Npad * 128 * 2);
    uint16_t* Xsb  = (uint16_t*)alloc((size_t)NSpad * 128 * 2);
    uint16_t* WTq  = (uint16_t*)alloc((size_t)384 * 128 * 2);
    uint16_t* WTg  = (uint16_t*)alloc((size_t)128 * 128 * 2);
    uint16_t* WTo  = (uint16_t*)alloc((size_t)128 * 128 * 2);
    uint16_t* WTq2 = (uint16_t*)alloc((size_t)128 * 128 * 2);
    uint16_t* WTgt = (uint16_t*)alloc((size_t)128 * 128 * 2);
    uint16_t* WTkv = (uint16_t*)alloc((size_t)256 * 128 * 2);
    uint16_t* WTgs = (uint16_t*)alloc((size_t)128 * 128 * 2);
    uint16_t* WTo2 = (uint16_t*)alloc((size_t)128 * 128 * 2);
    // S1: phase1 {Qb [Npad][128] + kvi [Npad][256]} / phase2 {kvgi [NSpad][256] + V16 [NSpad][128]}
    size_t s1a = (size_t)Npad * 128 * 2 + (size_t)Npad * 256 * 2;
    size_t s1b = (size_t)NSpad * 256 * 2 + (size_t)NSpad * 128 * 2;
    uint16_t* S1 = (uint16_t*)alloc(smax_(s1a, s1b));
    uint16_t* Qb   = S1;
    uint16_t* kvi  = S1 + (size_t)Npad * 128;
    uint16_t* kvgi = S1;
    uint16_t* V16  = S1 + (size_t)NSpad * 256;
    // S2: sa f32 -> ca f32
    float* S2 = (float*)alloc((size_t)N * 128 * 4);
    float* sa = S2;
    float* ca = S2;
    uint16_t* g16  = (uint16_t*)alloc((size_t)N * 128 * 2);   // gate / gtgt bf16
    uint16_t* Qcb  = (uint16_t*)alloc((size_t)N * 128 * 2);
    uint16_t* Awo  = (uint16_t*)alloc((size_t)Npad * 128 * 2);
    uint16_t* hb   = (uint16_t*)alloc((size_t)Npad * 128 * 2);
    float*    b8a  = (float*)alloc((size_t)N * 8 * 4);
    float*    b8s  = (float*)alloc((size_t)NS * 8 * 4);
    int* cnt    = (int*)alloc((size_t)N * 4);   // counts, then cursor
    int* pre    = (int*)alloc((size_t)N * 4);
    int* bsum   = (int*)alloc(256 * 4);
    int* offs   = (int*)alloc((size_t)(N + 1) * 4);
    int* sorted = (int*)alloc((size_t)(E1 > E2 ? E1 : E2) * 4);
    (void)ws_size; (void)n_in; (void)out_size;

    const int gA  = Npad / 128;
    const int gAs = NSpad / 128;
    const int gW  = (N + 3) / 4;
    const int gWs = (NS + 3) / 4;
    const int B1  = (N + 2047) / 2048;

    // ---- prep: casts
    castbf_k<<<2048, 256, 0, stream>>>(X,  Xb,  N * 32);
    castbf_k<<<2048, 256, 0, stream>>>(Xs, Xsb, NS * 32);
    castWT_k<<<(128 * 384 + 255) / 256, 256, 0, stream>>>(W_qkv, WTq, 384);
    castWT_k<<<64, 256, 0, stream>>>(W_gate, WTg, 128);
    castWT_k<<<64, 256, 0, stream>>>(W_o, WTo, 128);
    castWT_k<<<64, 256, 0, stream>>>(W_q, WTq2, 128);
    castWT_k<<<64, 256, 0, stream>>>(W_gate_tgt, WTgt, 128);
    castWT_k<<<(128 * 256 + 255) / 256, 256, 0, stream>>>(W_kv, WTkv, 256);
    castWT_k<<<64, 256, 0, stream>>>(W_gate_src, WTgs, 128);
    castWT_k<<<64, 256, 0, stream>>>(W_o2, WTo2, 128);

    // ---- CSR for nbr edges
    hipMemsetAsync(cnt, 0, (size_t)N * 4, stream);
    hist_k<<<(E1 + 255) / 256, 256, 0, stream>>>(nbr_src, cnt, E1);
    scan1_k<<<B1, 256, 0, stream>>>(cnt, pre, bsum, N);
    scan2_k<<<1, 64, 0, stream>>>(bsum, B1);
    scan3_k<<<B1, 256, 0, stream>>>(pre, bsum, offs, cnt, N, E1);
    scatter_k<<<(E1 + 255) / 256, 256, 0, stream>>>(nbr_src, nbr_dst, cnt, sorted, E1);

    // ---- stage 1 projections (Q plain bf16; K,V interleaved)
    gemm_mfma_k<<<dim3(gA, 1), 256, 0, stream>>>(Xb, WTq,             nullptr, nullptr, Qb,  N, 128, GF_BF16);
    gemm_mfma_k<<<dim3(gA, 1), 256, 0, stream>>>(Xb, WTq + 128 * 128, nullptr, nullptr, kvi, N, 128, GF_KVI_K);
    gemm_mfma_k<<<dim3(gA, 1), 256, 0, stream>>>(Xb, WTq + 256 * 128, nullptr, nullptr, kvi, N, 128, GF_KVI_V);
    bias8_k<<<gW, 256, 0, stream>>>(Xb, w_bias, b8a, N);
    gemm_mfma_k<<<dim3(gA, 1), 256, 0, stream>>>(Xb, WTg, b_gate, nullptr, g16, N, 128, GF_SIG | GF_BF16);

    // ---- self-attention (fused gate-mul, bf16 out)
    self_attn_k<<<gW, 256, 0, stream>>>(Qb, kvi, b8a, offs, sorted, g16, Awo, N);
    gemm_mfma_k<<<dim3(gA, 1), 256, 0, stream>>>(Awo, WTo, nullptr, nullptr, sa, N, 128, 0);
    addln_k<<<gW, 256, 0, stream>>>(X, nullptr, sa, ln1_g, ln1_b, nullptr, hb, N);

    // ---- stage 2 projections
    gemm_mfma_k<<<dim3(gA, 1), 256, 0, stream>>>(hb, WTq2, nullptr, nullptr, Qcb, N, 128, GF_BF16);
    bias8_k<<<gW, 256, 0, stream>>>(hb, w_bias_tgt, b8a, N);
    gemm_mfma_k<<<dim3(gA, 1), 256, 0, stream>>>(hb, WTgt, b_gate_tgt, nullptr, g16, N, 128, GF_SIG | GF_BF16);
    gemm_mfma_k<<<dim3(gAs, 1), 256, 0, stream>>>(Xsb, WTkv,             nullptr, nullptr, kvgi, NS, 128, GF_KVI_K);
    gemm_mfma_k<<<dim3(gAs, 1), 256, 0, stream>>>(Xsb, WTkv + 128 * 128, nullptr, nullptr, V16,  NS, 128, GF_BF16);
    bias8_k<<<gWs, 256, 0, stream>>>(Xsb, w_bias_src, b8s, NS);
    // gv = sigmoid(Xs@Wgs+b) * Vc  -> interleaved V slots of kvgi
    gemm_mfma_k<<<dim3(gAs, 1), 256, 0, stream>>>(Xsb, WTgs, b_gate_src, V16, kvgi, NS, 128, GF_SIG | GF_MULV | GF_KVI_V);

    // ---- CSR for inc edges
    hipMemsetAsync(cnt, 0, (size_t)N * 4, stream);
    hist_k<<<(E2 + 255) / 256, 256, 0, stream>>>(inc_tgt, cnt, E2);
    scan1_k<<<B1, 256, 0, stream>>>(cnt, pre, bsum, N);
    scan2_k<<<1, 64, 0, stream>>>(bsum, B1);
    scan3_k<<<B1, 256, 0, stream>>>(pre, bsum, offs, cnt, N, E2);
    scatter_k<<<(E2 + 255) / 256, 256, 0, stream>>>(inc_tgt, inc_src, cnt, sorted, E2);

    // ---- cross-attention (fused gtgt-mul, bf16 out)
    cross_attn_k<<<gW, 256, 0, stream>>>(Qcb, b8a, kvgi, b8s, offs, sorted, g16, Awo, N);
    gemm_mfma_k<<<dim3(gA, 1), 256, 0, stream>>>(Awo, WTo2, nullptr, nullptr, ca, N, 128, 0);
    addln_k<<<gW, 256, 0, stream>>>(nullptr, hb, ca, ln2_g, ln2_b, (float*)d_out, nullptr, N);
}

// Round 4
// 510.889 us; speedup vs baseline: 1.9596x; 1.0771x over previous
//
#include <hip/hip_runtime.h>
#include <stdint.h>

// ---------------------------------------------------------------- helpers
__device__ __forceinline__ float bf_lo(uint32_t w) { return __uint_as_float(w << 16); }
__device__ __forceinline__ float bf_hi(uint32_t w) { return __uint_as_float(w & 0xffff0000u); }
__device__ __forceinline__ float bfu(uint16_t u) { return __uint_as_float((uint32_t)u << 16); }
__device__ __forceinline__ uint16_t f2bf(float f) {
    uint32_t u = __float_as_uint(f);
    uint32_t r = ((u >> 16) & 1u) + 0x7fffu;   // round-to-nearest-even
    return (uint16_t)((u + r) >> 16);
}
__device__ __forceinline__ uint32_t pk2bf(float a, float b) {
    return (uint32_t)f2bf(a) | ((uint32_t)f2bf(b) << 16);
}
__device__ __forceinline__ void gload_lds16(const void* g, void* l) {
    __builtin_amdgcn_global_load_lds(
        (const __attribute__((address_space(1))) void*)g,
        (__attribute__((address_space(3))) void*)l, 16, 0, 0);
}

typedef __attribute__((ext_vector_type(8))) short bf16x8;
typedef __attribute__((ext_vector_type(4))) float f32x4;

#define QSCALE 0.25f

// gemm epilogue modes
#define M_F32  0   // f32 out [M][128]
#define M_BF16 1   // bf16 out [M][128]
#define M_QS   2   // bf16 out, scaled by QSCALE (Q projections)
#define M_SIG  3   // sigmoid(acc+bias), bf16 out [M][128]
#define M_KVIK 4   // interleaved K slot of [M][256]
#define M_KVIV 5   // interleaved V slot of [M][256]
#define M_GV   6   // sigmoid(acc+bias) * aux, into interleaved V slot

struct GemmJob { const uint16_t* WT; const float* bias; const uint16_t* aux; void* out; int mode; };
struct GemmJobs { GemmJob j[4]; };

// ---------------------------------------------------------------- MFMA GEMM (jobs variant)
// Each blockIdx.y is an independent 128-col job sharing A[M,128] bf16.
// Whole K=128 staged in LDS; XOR swizzle both-sides (rule 21); D=C^T operand
// swap so each lane's 4 acc elems are 4 consecutive columns.
__global__ __launch_bounds__(256) void multi_gemm_k(
    const uint16_t* __restrict__ A, GemmJobs jobs, int M)
{
    __shared__ uint16_t As[128 * 128];
    __shared__ uint16_t Ws[128 * 128];
    const GemmJob jb = jobs.j[blockIdx.y];
    const int tid = threadIdx.x;
    const int wid = tid >> 6;
    const int lane = tid & 63;
    const int m0 = blockIdx.x * 128;

    {
        const uint16_t* Ab = A + (size_t)m0 * 128;
        const uint16_t* Wb = jb.WT;
#pragma unroll
        for (int it = 0; it < 8; ++it) {
            int idx = it * 256 + tid;
            int r = idx >> 4, c = idx & 15;
            int gc = c ^ (r & 7);
            uint16_t* ldsA = As + (size_t)(it * 256 + wid * 64) * 8;
            uint16_t* ldsW = Ws + (size_t)(it * 256 + wid * 64) * 8;
            gload_lds16(Ab + (size_t)r * 128 + gc * 8, ldsA);
            gload_lds16(Wb + (size_t)r * 128 + gc * 8, ldsW);
        }
    }
    __syncthreads();

    const int wr = wid >> 1, wc = wid & 1;
    const int l15 = lane & 15, l4 = lane >> 4;

    f32x4 acc[4][4];
#pragma unroll
    for (int i = 0; i < 4; i++)
#pragma unroll
        for (int j = 0; j < 4; j++) acc[i][j] = (f32x4){0.f, 0.f, 0.f, 0.f};

#pragma unroll
    for (int kk = 0; kk < 4; ++kk) {
        bf16x8 af[4], bff[4];
#pragma unroll
        for (int ni = 0; ni < 4; ++ni) {
            int r = wc * 64 + ni * 16 + l15;
            int cc = (kk * 4 + l4) ^ (r & 7);
            af[ni] = *(const bf16x8*)(Ws + r * 128 + cc * 8);
        }
#pragma unroll
        for (int mi = 0; mi < 4; ++mi) {
            int r = wr * 64 + mi * 16 + l15;
            int cc = (kk * 4 + l4) ^ (r & 7);
            bff[mi] = *(const bf16x8*)(As + r * 128 + cc * 8);
        }
#pragma unroll
        for (int ni = 0; ni < 4; ++ni)
#pragma unroll
            for (int mi = 0; mi < 4; ++mi)
                acc[ni][mi] = __builtin_amdgcn_mfma_f32_16x16x32_bf16(
                    af[ni], bff[mi], acc[ni][mi], 0, 0, 0);
    }

    const int mode = jb.mode;
#pragma unroll
    for (int mi = 0; mi < 4; ++mi) {
        int gm = m0 + wr * 64 + mi * 16 + l15;
        if (gm >= M) continue;
#pragma unroll
        for (int ni = 0; ni < 4; ++ni) {
            int gn = wc * 64 + ni * 16 + l4 * 4;
            f32x4 v = acc[ni][mi];
            if (mode == M_SIG || mode == M_GV) {
                float4 bb = *(const float4*)(jb.bias + gn);
                v.x = 1.f / (1.f + __expf(-(v.x + bb.x)));
                v.y = 1.f / (1.f + __expf(-(v.y + bb.y)));
                v.z = 1.f / (1.f + __expf(-(v.z + bb.z)));
                v.w = 1.f / (1.f + __expf(-(v.w + bb.w)));
            }
            if (mode == M_QS) { v.x *= QSCALE; v.y *= QSCALE; v.z *= QSCALE; v.w *= QSCALE; }
            if (mode == M_GV) {
                ushort4 vs = *(const ushort4*)(jb.aux + (size_t)gm * 128 + gn);
                v.x *= bfu(vs.x); v.y *= bfu(vs.y); v.z *= bfu(vs.z); v.w *= bfu(vs.w);
            }
            if (mode == M_KVIK || mode == M_KVIV || mode == M_GV) {
                int which = (mode == M_KVIK) ? 0 : 2;
                uint16_t* op = (uint16_t*)jb.out + (size_t)gm * 256 + gn * 2 + which;
                *reinterpret_cast<uint32_t*>(op)     = pk2bf(v.x, v.y);
                *reinterpret_cast<uint32_t*>(op + 4) = pk2bf(v.z, v.w);
            } else if (mode == M_F32) {
                *reinterpret_cast<float4*>((float*)jb.out + (size_t)gm * 128 + gn) =
                    make_float4(v.x, v.y, v.z, v.w);
            } else {
                ushort4 o;
                o.x = f2bf(v.x); o.y = f2bf(v.y); o.z = f2bf(v.z); o.w = f2bf(v.w);
                *reinterpret_cast<ushort4*>((uint16_t*)jb.out + (size_t)gm * 128 + gn) = o;
            }
        }
    }
}

// ---------------------------------------------------------------- casts
__global__ void castbf_k(const float* __restrict__ in, uint16_t* __restrict__ out, int n4)
{
    int i = blockIdx.x * blockDim.x + threadIdx.x;
    int stride = gridDim.x * blockDim.x;
    for (; i < n4; i += stride) {
        float4 v = reinterpret_cast<const float4*>(in)[i];
        ushort4 o;
        o.x = f2bf(v.x); o.y = f2bf(v.y); o.z = f2bf(v.z); o.w = f2bf(v.w);
        reinterpret_cast<ushort4*>(out)[i] = o;
    }
}

// WT[n*128+k] = bf16(W[k*Nc+n]) for arbitrary Nc
__global__ void castWT_k(const float* __restrict__ W, uint16_t* __restrict__ WT, int Nc)
{
    int i = blockIdx.x * blockDim.x + threadIdx.x;
    if (i >= 128 * Nc) return;
    int n = i >> 7, k = i & 127;
    WT[i] = f2bf(W[(size_t)k * Nc + n]);
}

// six 128x128 transposes in one dispatch
struct WT6 { const float* src[6]; uint16_t* dst[6]; };
__global__ void castWT6_k(WT6 jb)
{
    int y = blockIdx.y;
    const float* W = jb.src[y];
    uint16_t* WT = jb.dst[y];
    int i = blockIdx.x * 256 + threadIdx.x;   // 16384 per matrix
    int n = i >> 7, k = i & 127;
    WT[i] = f2bf(W[k * 128 + n]);
}

// ---------------------------------------------------------------- D x 8 bias projection (bf16 A)
__global__ __launch_bounds__(256) void bias8_k(
    const uint16_t* __restrict__ Ab, const float* __restrict__ w,
    float* __restrict__ B, int M)
{
    int lane = threadIdx.x & 63;
    int row = blockIdx.x * 4 + (threadIdx.x >> 6);
    if (row >= M) return;
    uint32_t wv = *reinterpret_cast<const uint32_t*>(Ab + (size_t)row * 128 + 2 * lane);
    float x0 = bf_lo(wv), x1 = bf_hi(wv);
    const float4* wp = reinterpret_cast<const float4*>(w + (size_t)(2 * lane) * 8);
    float4 wa0 = wp[0], wa1 = wp[1];
    float4 wb0 = wp[2], wb1 = wp[3];
    float p[8];
    p[0] = x0 * wa0.x + x1 * wb0.x;  p[1] = x0 * wa0.y + x1 * wb0.y;
    p[2] = x0 * wa0.z + x1 * wb0.z;  p[3] = x0 * wa0.w + x1 * wb0.w;
    p[4] = x0 * wa1.x + x1 * wb1.x;  p[5] = x0 * wa1.y + x1 * wb1.y;
    p[6] = x0 * wa1.z + x1 * wb1.z;  p[7] = x0 * wa1.w + x1 * wb1.w;
    float r = 0.f;
#pragma unroll
    for (int h = 0; h < 8; h++) {
        float v = p[h];
        v += __shfl_xor(v, 1);  v += __shfl_xor(v, 2);  v += __shfl_xor(v, 4);
        v += __shfl_xor(v, 8);  v += __shfl_xor(v, 16); v += __shfl_xor(v, 32);
        if (lane == h) r = v;
    }
    if (lane < 8) B[(size_t)row * 8 + lane] = r;
}

// ---------------------------------------------------------------- add + LayerNorm
__global__ __launch_bounds__(256) void addln_k(
    const float* __restrict__ Xf, const uint16_t* __restrict__ Xb,
    const float* __restrict__ Y,
    const float* __restrict__ g, const float* __restrict__ b,
    float* __restrict__ Of, uint16_t* __restrict__ Ob, int M)
{
    int lane = threadIdx.x & 63;
    int row = blockIdx.x * 4 + (threadIdx.x >> 6);
    if (row >= M) return;
    size_t base = (size_t)row * 128 + 2 * lane;
    float x0, x1;
    if (Xb) {
        uint32_t wv = *reinterpret_cast<const uint32_t*>(Xb + base);
        x0 = bf_lo(wv); x1 = bf_hi(wv);
    } else {
        float2 xa = *reinterpret_cast<const float2*>(Xf + base);
        x0 = xa.x; x1 = xa.y;
    }
    float2 ya = *reinterpret_cast<const float2*>(Y + base);
    float t0 = x0 + ya.x, t1 = x1 + ya.y;
    float s = t0 + t1;
#pragma unroll
    for (int o = 1; o < 64; o <<= 1) s += __shfl_xor(s, o);
    float mean = s * (1.f / 128.f);
    float d0 = t0 - mean, d1 = t1 - mean;
    float q = d0 * d0 + d1 * d1;
#pragma unroll
    for (int o = 1; o < 64; o <<= 1) q += __shfl_xor(q, o);
    float rstd = rsqrtf(q * (1.f / 128.f) + 1e-5f);
    float2 gg = *reinterpret_cast<const float2*>(g + 2 * lane);
    float2 bb = *reinterpret_cast<const float2*>(b + 2 * lane);
    float o0 = gg.x * d0 * rstd + bb.x, o1 = gg.y * d1 * rstd + bb.y;
    if (Of) *reinterpret_cast<float2*>(Of + base) = make_float2(o0, o1);
    if (Ob) *reinterpret_cast<uint32_t*>(Ob + base) = pk2bf(o0, o1);
}

// ---------------------------------------------------------------- merged CSR build (both edge lists, 2N segments)
__global__ void hist2_k(const int* __restrict__ s1, const int* __restrict__ s2,
                        int* __restrict__ cnt, int E1, int E2, int N)
{
    int i = blockIdx.x * blockDim.x + threadIdx.x;
    if (i < E1) atomicAdd(&cnt[s1[i]], 1);
    else if (i < E1 + E2) atomicAdd(&cnt[N + s2[i - E1]], 1);
}

__global__ __launch_bounds__(256) void scan1_k(
    const int* __restrict__ cnt, int* __restrict__ pre, int* __restrict__ bsum, int N)
{
    __shared__ int wtot[4];
    int t = threadIdx.x, lane = t & 63, wid = t >> 6;
    int base = blockIdx.x * 2048 + t * 8;
    int v[8];
    if (base + 8 <= N) {
        int4 a = *reinterpret_cast<const int4*>(cnt + base);
        int4 b = *reinterpret_cast<const int4*>(cnt + base + 4);
        v[0] = a.x; v[1] = a.y; v[2] = a.z; v[3] = a.w;
        v[4] = b.x; v[5] = b.y; v[6] = b.z; v[7] = b.w;
    } else {
#pragma unroll
        for (int i = 0; i < 8; i++) v[i] = (base + i < N) ? cnt[base + i] : 0;
    }
    int inc_[8]; int s = 0;
#pragma unroll
    for (int i = 0; i < 8; i++) { s += v[i]; inc_[i] = s; }
    int tot = s;
    int wp = tot;
#pragma unroll
    for (int o = 1; o < 64; o <<= 1) { int x = __shfl_up(wp, o); if (lane >= o) wp += x; }
    if (lane == 63) wtot[wid] = wp;
    __syncthreads();
    int wex = 0;
    for (int w = 0; w < wid; w++) wex += wtot[w];
    int tex = wex + wp - tot;
#pragma unroll
    for (int i = 0; i < 8; i++)
        if (base + i < N) pre[base + i] = tex + inc_[i] - v[i];
    if (t == 255) bsum[blockIdx.x] = wex + wp;
}

__global__ void scan2_k(int* __restrict__ bsum, int B)
{
    int lane = threadIdx.x;
    int v = (lane < B) ? bsum[lane] : 0;
    int s = v;
#pragma unroll
    for (int o = 1; o < 64; o <<= 1) { int x = __shfl_up(s, o); if (lane >= o) s += x; }
    if (lane < B) bsum[lane] = s - v;
}

__global__ __launch_bounds__(256) void scan3_k(
    const int* __restrict__ pre, const int* __restrict__ bsum,
    int* __restrict__ offs, int* __restrict__ cur, int N, int E)
{
    int base = blockIdx.x * 2048 + threadIdx.x * 8;
    int add = bsum[blockIdx.x];
    if (base + 8 <= N) {
        int4 a = *reinterpret_cast<const int4*>(pre + base);
        int4 b = *reinterpret_cast<const int4*>(pre + base + 4);
        a.x += add; a.y += add; a.z += add; a.w += add;
        b.x += add; b.y += add; b.z += add; b.w += add;
        *reinterpret_cast<int4*>(offs + base) = a;
        *reinterpret_cast<int4*>(offs + base + 4) = b;
        *reinterpret_cast<int4*>(cur + base) = a;
        *reinterpret_cast<int4*>(cur + base + 4) = b;
    } else {
#pragma unroll
        for (int i = 0; i < 8; i++)
            if (base + i < N) { int x = pre[base + i] + add; offs[base + i] = x; cur[base + i] = x; }
    }
    if (blockIdx.x == 0 && threadIdx.x == 0) offs[N] = E;
}

__global__ void scatter2_k(const int* __restrict__ s1, const int* __restrict__ p1,
                           const int* __restrict__ s2, const int* __restrict__ p2,
                           int* __restrict__ cur, int* __restrict__ sorted,
                           int E1, int E2, int N)
{
    int i = blockIdx.x * blockDim.x + threadIdx.x;
    if (i < E1) {
        int p = atomicAdd(&cur[s1[i]], 1);
        sorted[p] = p1[i];
    } else if (i < E1 + E2) {
        int j = i - E1;
        int p = atomicAdd(&cur[N + s2[j]], 1);
        sorted[p] = p2[j];
    }
}

// ---------------------------------------------------------------- self-attention (max-free softmax)
// Q prescaled by 0.25 at projection; scores bounded (|s|<~14) so plain
// sum-of-exp is exact-enough; 1e-30 guard makes empty segments output 0.
#define SEDGE(J, IDX)                                                            \
    {                                                                            \
        int dst = sdst[IDX];                                                     \
        uint2 kv = *reinterpret_cast<const uint2*>(kb + ((size_t)dst << 8));     \
        float s = q0 * bf_lo(kv.x) + q1 * bf_hi(kv.x);                           \
        s += __shfl_xor(s, 1); s += __shfl_xor(s, 2); s += __shfl_xor(s, 4);     \
        float w = __expf(s + bs);                                                \
        pa##J = fmaf(w, bf_lo(kv.y), pa##J);                                     \
        pb##J = fmaf(w, bf_hi(kv.y), pb##J);                                     \
        dn##J += w;                                                              \
    }

__global__ __launch_bounds__(256) void self_attn_k(
    const uint16_t* __restrict__ Qb, const uint16_t* __restrict__ kvi,
    const float* __restrict__ bias1,
    const int* __restrict__ offs, const int* __restrict__ sdst,
    const uint16_t* __restrict__ g16, uint16_t* __restrict__ Aout, int N)
{
    int lane = threadIdx.x & 63;
    int n = blockIdx.x * 4 + (threadIdx.x >> 6);
    if (n >= N) return;
    uint32_t qw = *reinterpret_cast<const uint32_t*>(Qb + (size_t)n * 128 + 2 * lane);
    float q0 = bf_lo(qw), q1 = bf_hi(qw);
    float bs = bias1[(size_t)n * 8 + (lane >> 3)];
    int e0 = offs[n], e1 = offs[n + 1];
    const uint16_t* kb = kvi + lane * 4;
    float dn0 = 0.f, pa0 = 0.f, pb0 = 0.f;
    float dn1 = 0.f, pa1 = 0.f, pb1 = 0.f;
    int e = e0;
    for (; e + 4 <= e1; e += 4) {
        SEDGE(0, e)
        SEDGE(1, e + 1)
        SEDGE(0, e + 2)
        SEDGE(1, e + 3)
    }
    for (; e < e1; ++e) SEDGE(0, e)
    float den = dn0 + dn1, a0 = pa0 + pa1, a1 = pb0 + pb1;
    float inv = 1.f / (den + 1e-30f);
    uint32_t gw = *reinterpret_cast<const uint32_t*>(g16 + (size_t)n * 128 + 2 * lane);
    a0 *= inv * bf_lo(gw); a1 *= inv * bf_hi(gw);
    *reinterpret_cast<uint32_t*>(Aout + (size_t)n * 128 + 2 * lane) = pk2bf(a0, a1);
}

// ---------------------------------------------------------------- cross-attention (max-free, V pre-gated at projection)
#define CEDGE(J, IDX)                                                            \
    {                                                                            \
        int src = ssrc[IDX];                                                     \
        uint2 kv = *reinterpret_cast<const uint2*>(kb + ((size_t)src << 8));     \
        float bss = bias_s[(size_t)src * 8 + (lane >> 3)];                       \
        float s = q0 * bf_lo(kv.x) + q1 * bf_hi(kv.x);                           \
        s += __shfl_xor(s, 1); s += __shfl_xor(s, 2); s += __shfl_xor(s, 4);     \
        float w = __expf(s + bt + bss);                                          \
        pa##J = fmaf(w, bf_lo(kv.y), pa##J);                                     \
        pb##J = fmaf(w, bf_hi(kv.y), pb##J);                                     \
        dn##J += w;                                                              \
    }

__global__ __launch_bounds__(256) void cross_attn_k(
    const uint16_t* __restrict__ Qcb, const float* __restrict__ bias_t,
    const uint16_t* __restrict__ kvgi, const float* __restrict__ bias_s,
    const int* __restrict__ offs, const int* __restrict__ ssrc,
    const uint16_t* __restrict__ g16, uint16_t* __restrict__ Aout, int N)
{
    int lane = threadIdx.x & 63;
    int n = blockIdx.x * 4 + (threadIdx.x >> 6);
    if (n >= N) return;
    uint32_t qw = *reinterpret_cast<const uint32_t*>(Qcb + (size_t)n * 128 + 2 * lane);
    float q0 = bf_lo(qw), q1 = bf_hi(qw);
    float bt = bias_t[(size_t)n * 8 + (lane >> 3)];
    int e0 = offs[n], e1 = offs[n + 1];
    const uint16_t* kb = kvgi + lane * 4;
    float dn0 = 0.f, pa0 = 0.f, pb0 = 0.f;
    float dn1 = 0.f, pa1 = 0.f, pb1 = 0.f;
    int e = e0;
    for (; e + 4 <= e1; e += 4) {
        CEDGE(0, e)
        CEDGE(1, e + 1)
        CEDGE(0, e + 2)
        CEDGE(1, e + 3)
    }
    for (; e < e1; ++e) CEDGE(0, e)
    float den = dn0 + dn1, a0 = pa0 + pa1, a1 = pb0 + pb1;
    float inv = 1.f / (den + 1e-30f);
    uint32_t gw = *reinterpret_cast<const uint32_t*>(g16 + (size_t)n * 128 + 2 * lane);
    a0 *= inv * bf_lo(gw); a1 *= inv * bf_hi(gw);
    *reinterpret_cast<uint32_t*>(Aout + (size_t)n * 128 + 2 * lane) = pk2bf(a0, a1);
}

// ---------------------------------------------------------------- host
static inline size_t smax_(size_t a, size_t b) { return a > b ? a : b; }

extern "C" void kernel_launch(void* const* d_in, const int* in_sizes, int n_in,
                              void* d_out, int out_size, void* d_ws, size_t ws_size,
                              hipStream_t stream)
{
    const float* X          = (const float*)d_in[0];
    const float* Xs         = (const float*)d_in[1];
    const float* W_qkv      = (const float*)d_in[2];
    const float* w_bias     = (const float*)d_in[3];
    const float* W_gate     = (const float*)d_in[4];
    const float* b_gate     = (const float*)d_in[5];
    const float* W_o        = (const float*)d_in[6];
    const float* W_q        = (const float*)d_in[7];
    const float* W_kv       = (const float*)d_in[8];
    const float* w_bias_tgt = (const float*)d_in[9];
    const float* w_bias_src = (const float*)d_in[10];
    const float* W_gate_tgt = (const float*)d_in[11];
    const float* b_gate_tgt = (const float*)d_in[12];
    const float* W_gate_src = (const float*)d_in[13];
    const float* b_gate_src = (const float*)d_in[14];
    const float* W_o2       = (const float*)d_in[15];
    const float* ln1_g      = (const float*)d_in[16];
    const float* ln1_b      = (const float*)d_in[17];
    const float* ln2_g      = (const float*)d_in[18];
    const float* ln2_b      = (const float*)d_in[19];
    const int* nbr_src      = (const int*)d_in[20];
    const int* nbr_dst      = (const int*)d_in[21];
    const int* inc_tgt      = (const int*)d_in[22];
    const int* inc_src      = (const int*)d_in[23];

    const int N  = in_sizes[0] / 128;
    const int NS = in_sizes[1] / 128;
    const int E1 = in_sizes[20];
    const int E2 = in_sizes[22];
    const int Et = E1 + E2;
    const int NN = 2 * N;
    const int Npad  = (N + 127) & ~127;
    const int NSpad = (NS + 127) & ~127;

    char* ws = (char*)d_ws;
    size_t off = 0;
    auto alloc = [&](size_t bytes) -> void* {
        void* p = ws + off;
        off = (off + bytes + 255) & ~(size_t)255;
        return p;
    };

    uint16_t* Xb   = (uint16_t*)alloc((size_t)Npad * 128 * 2);
    uint16_t* Xsb  = (uint16_t*)alloc((size_t)NSpad * 128 * 2);
    uint16_t* WTq  = (uint16_t*)alloc((size_t)384 * 128 * 2);
    uint16_t* WTkv = (uint16_t*)alloc((size_t)256 * 128 * 2);
    uint16_t* WTg  = (uint16_t*)alloc((size_t)128 * 128 * 2);
    uint16_t* WTo  = (uint16_t*)alloc((size_t)128 * 128 * 2);
    uint16_t* WTq2 = (uint16_t*)alloc((size_t)128 * 128 * 2);
    uint16_t* WTgt = (uint16_t*)alloc((size_t)128 * 128 * 2);
    uint16_t* WTgs = (uint16_t*)alloc((size_t)128 * 128 * 2);
    uint16_t* WTo2 = (uint16_t*)alloc((size_t)128 * 128 * 2);
    // S1: phase1 {Qb [Npad][128] + kvi [Npad][256]} / phase2 {kvgi [NSpad][256] + V16 [NSpad][128]}
    size_t s1a = (size_t)Npad * 384 * 2;
    size_t s1b = (size_t)NSpad * 384 * 2;
    uint16_t* S1 = (uint16_t*)alloc(smax_(s1a, s1b));
    uint16_t* Qb   = S1;
    uint16_t* kvi  = S1 + (size_t)Npad * 128;
    uint16_t* kvgi = S1;
    uint16_t* V16  = S1 + (size_t)NSpad * 256;
    // S2: sa f32 -> ca f32
    float* S2 = (float*)alloc((size_t)N * 128 * 4);
    float* sa = S2;
    float* ca = S2;
    uint16_t* g16  = (uint16_t*)alloc((size_t)N * 128 * 2);   // gate, then gtgt
    uint16_t* Qcb  = (uint16_t*)alloc((size_t)N * 128 * 2);
    uint16_t* Awo  = (uint16_t*)alloc((size_t)Npad * 128 * 2);
    uint16_t* hb   = (uint16_t*)alloc((size_t)Npad * 128 * 2);
    float*    b8a  = (float*)alloc((size_t)N * 8 * 4);
    float*    b8s  = (float*)alloc((size_t)NS * 8 * 4);
    int* cnt    = (int*)alloc((size_t)NN * 4);   // counts, then cursor
    int* pre    = (int*)alloc((size_t)NN * 4);
    int* bsum   = (int*)alloc(256 * 4);
    int* offs   = (int*)alloc((size_t)(NN + 1) * 4);
    int* sorted = (int*)alloc((size_t)Et * 4);
    (void)ws_size; (void)n_in; (void)out_size;

    const int gA  = Npad / 128;
    const int gAs = NSpad / 128;
    const int gW  = (N + 3) / 4;
    const int gWs = (NS + 3) / 4;
    const int B1  = (NN + 2047) / 2048;   // <= 64 for N<=65k

    // ---- prep: casts (weights + activations)
    castbf_k<<<2048, 256, 0, stream>>>(X,  Xb,  N * 32);
    castbf_k<<<2048, 256, 0, stream>>>(Xs, Xsb, NS * 32);
    castWT_k<<<(128 * 384 + 255) / 256, 256, 0, stream>>>(W_qkv, WTq, 384);
    castWT_k<<<(128 * 256 + 255) / 256, 256, 0, stream>>>(W_kv, WTkv, 256);
    {
        WT6 jb;
        jb.src[0] = W_gate;     jb.dst[0] = WTg;
        jb.src[1] = W_o;        jb.dst[1] = WTo;
        jb.src[2] = W_q;        jb.dst[2] = WTq2;
        jb.src[3] = W_gate_tgt; jb.dst[3] = WTgt;
        jb.src[4] = W_gate_src; jb.dst[4] = WTgs;
        jb.src[5] = W_o2;       jb.dst[5] = WTo2;
        castWT6_k<<<dim3(64, 6), 256, 0, stream>>>(jb);
    }

    // ---- merged CSR build (both edge lists)
    hipMemsetAsync(cnt, 0, (size_t)NN * 4, stream);
    hist2_k<<<(Et + 255) / 256, 256, 0, stream>>>(nbr_src, inc_tgt, cnt, E1, E2, N);
    scan1_k<<<B1, 256, 0, stream>>>(cnt, pre, bsum, NN);
    scan2_k<<<1, 64, 0, stream>>>(bsum, B1);
    scan3_k<<<B1, 256, 0, stream>>>(pre, bsum, offs, cnt, NN, Et);
    scatter2_k<<<(Et + 255) / 256, 256, 0, stream>>>(nbr_src, nbr_dst, inc_tgt, inc_src,
                                                     cnt, sorted, E1, E2, N);

    // ---- stage 1 projections: Q(x0.25), K, V interleaved, gate — one dispatch
    {
        GemmJobs jb;
        jb.j[0] = { WTq,             nullptr, nullptr, Qb,  M_QS };
        jb.j[1] = { WTq + 128 * 128, nullptr, nullptr, kvi, M_KVIK };
        jb.j[2] = { WTq + 256 * 128, nullptr, nullptr, kvi, M_KVIV };
        jb.j[3] = { WTg,             b_gate,  nullptr, g16, M_SIG };
        multi_gemm_k<<<dim3(gA, 4), 256, 0, stream>>>(Xb, jb, N);
    }
    bias8_k<<<gW, 256, 0, stream>>>(Xb, w_bias, b8a, N);

    // ---- self-attention (fused gate-mul, bf16 out)
    self_attn_k<<<gW, 256, 0, stream>>>(Qb, kvi, b8a, offs, sorted, g16, Awo, N);
    {
        GemmJobs jb;
        jb.j[0] = { WTo, nullptr, nullptr, sa, M_F32 };
        multi_gemm_k<<<dim3(gA, 1), 256, 0, stream>>>(Awo, jb, N);
    }
    addln_k<<<gW, 256, 0, stream>>>(X, nullptr, sa, ln1_g, ln1_b, nullptr, hb, N);

    // ---- stage 2 projections
    {
        GemmJobs jb;
        jb.j[0] = { WTq2, nullptr,    nullptr, Qcb, M_QS };
        jb.j[1] = { WTgt, b_gate_tgt, nullptr, g16, M_SIG };
        multi_gemm_k<<<dim3(gA, 2), 256, 0, stream>>>(hb, jb, N);
    }
    bias8_k<<<gW, 256, 0, stream>>>(hb, w_bias_tgt, b8a, N);
    {
        GemmJobs jb;
        jb.j[0] = { WTkv,             nullptr, nullptr, kvgi, M_KVIK };
        jb.j[1] = { WTkv + 128 * 128, nullptr, nullptr, V16,  M_BF16 };
        multi_gemm_k<<<dim3(gAs, 2), 256, 0, stream>>>(Xsb, jb, NS);
    }
    {
        GemmJobs jb;   // gv = sigmoid(Xs@Wgs+b) * Vc -> interleaved V slot
        jb.j[0] = { WTgs, b_gate_src, V16, kvgi, M_GV };
        multi_gemm_k<<<dim3(gAs, 1), 256, 0, stream>>>(Xsb, jb, NS);
    }
    bias8_k<<<gWs, 256, 0, stream>>>(Xsb, w_bias_src, b8s, NS);

    // ---- cross-attention (fused gtgt-mul, bf16 out)
    cross_attn_k<<<gW, 256, 0, stream>>>(Qcb, b8a, kvgi, b8s, offs + N, sorted, g16, Awo, N);
    {
        GemmJobs jb;
        jb.j[0] = { WTo2, nullptr, nullptr, ca, M_F32 };
        multi_gemm_k<<<dim3(gA, 1), 256, 0, stream>>>(Awo, jb, N);
    }
    addln_k<<<gW, 256, 0, stream>>>(nullptr, hb, ca, ln2_g, ln2_b, (float*)d_out, nullptr, N);
}

// Round 5
// 494.617 us; speedup vs baseline: 2.0241x; 1.0329x over previous
//
#include <hip/hip_runtime.h>
#include <stdint.h>

// ---------------------------------------------------------------- helpers
__device__ __forceinline__ float bf_lo(uint32_t w) { return __uint_as_float(w << 16); }
__device__ __forceinline__ float bf_hi(uint32_t w) { return __uint_as_float(w & 0xffff0000u); }
__device__ __forceinline__ float bfu(uint16_t u) { return __uint_as_float((uint32_t)u << 16); }
__device__ __forceinline__ uint16_t f2bf(float f) {
    uint32_t u = __float_as_uint(f);
    uint32_t r = ((u >> 16) & 1u) + 0x7fffu;   // round-to-nearest-even
    return (uint16_t)((u + r) >> 16);
}
__device__ __forceinline__ uint32_t pk2bf(float a, float b) {
    return (uint32_t)f2bf(a) | ((uint32_t)f2bf(b) << 16);
}
__device__ __forceinline__ void gload_lds16(const void* g, void* l) {
    __builtin_amdgcn_global_load_lds(
        (const __attribute__((address_space(1))) void*)g,
        (__attribute__((address_space(3))) void*)l, 16, 0, 0);
}

typedef __attribute__((ext_vector_type(8))) short bf16x8;
typedef __attribute__((ext_vector_type(4))) float f32x4;

#define QSCALE 0.25f

// gemm epilogue modes
#define M_F32  0
#define M_BF16 1
#define M_QS   2
#define M_SIG  3
#define M_KVIK 4
#define M_KVIV 5
#define M_GV   6

struct GemmJob { const uint16_t* WT; const float* bias; const uint16_t* aux; void* out; int mode; };
struct GemmJobs { GemmJob j[4]; };

// ---------------------------------------------------------------- MFMA GEMM (jobs variant)
__global__ __launch_bounds__(256) void multi_gemm_k(
    const uint16_t* __restrict__ A, GemmJobs jobs, int M)
{
    __shared__ uint16_t As[128 * 128];
    __shared__ uint16_t Ws[128 * 128];
    const GemmJob jb = jobs.j[blockIdx.y];
    const int tid = threadIdx.x;
    const int wid = tid >> 6;
    const int lane = tid & 63;
    const int m0 = blockIdx.x * 128;

    {
        const uint16_t* Ab = A + (size_t)m0 * 128;
        const uint16_t* Wb = jb.WT;
#pragma unroll
        for (int it = 0; it < 8; ++it) {
            int idx = it * 256 + tid;
            int r = idx >> 4, c = idx & 15;
            int gc = c ^ (r & 7);
            uint16_t* ldsA = As + (size_t)(it * 256 + wid * 64) * 8;
            uint16_t* ldsW = Ws + (size_t)(it * 256 + wid * 64) * 8;
            gload_lds16(Ab + (size_t)r * 128 + gc * 8, ldsA);
            gload_lds16(Wb + (size_t)r * 128 + gc * 8, ldsW);
        }
    }
    __syncthreads();

    const int wr = wid >> 1, wc = wid & 1;
    const int l15 = lane & 15, l4 = lane >> 4;

    f32x4 acc[4][4];
#pragma unroll
    for (int i = 0; i < 4; i++)
#pragma unroll
        for (int j = 0; j < 4; j++) acc[i][j] = (f32x4){0.f, 0.f, 0.f, 0.f};

#pragma unroll
    for (int kk = 0; kk < 4; ++kk) {
        bf16x8 af[4], bff[4];
#pragma unroll
        for (int ni = 0; ni < 4; ++ni) {
            int r = wc * 64 + ni * 16 + l15;
            int cc = (kk * 4 + l4) ^ (r & 7);
            af[ni] = *(const bf16x8*)(Ws + r * 128 + cc * 8);
        }
#pragma unroll
        for (int mi = 0; mi < 4; ++mi) {
            int r = wr * 64 + mi * 16 + l15;
            int cc = (kk * 4 + l4) ^ (r & 7);
            bff[mi] = *(const bf16x8*)(As + r * 128 + cc * 8);
        }
#pragma unroll
        for (int ni = 0; ni < 4; ++ni)
#pragma unroll
            for (int mi = 0; mi < 4; ++mi)
                acc[ni][mi] = __builtin_amdgcn_mfma_f32_16x16x32_bf16(
                    af[ni], bff[mi], acc[ni][mi], 0, 0, 0);
    }

    const int mode = jb.mode;
#pragma unroll
    for (int mi = 0; mi < 4; ++mi) {
        int gm = m0 + wr * 64 + mi * 16 + l15;
        if (gm >= M) continue;
#pragma unroll
        for (int ni = 0; ni < 4; ++ni) {
            int gn = wc * 64 + ni * 16 + l4 * 4;
            f32x4 v = acc[ni][mi];
            if (mode == M_SIG || mode == M_GV) {
                float4 bb = *(const float4*)(jb.bias + gn);
                v.x = 1.f / (1.f + __expf(-(v.x + bb.x)));
                v.y = 1.f / (1.f + __expf(-(v.y + bb.y)));
                v.z = 1.f / (1.f + __expf(-(v.z + bb.z)));
                v.w = 1.f / (1.f + __expf(-(v.w + bb.w)));
            }
            if (mode == M_QS) { v.x *= QSCALE; v.y *= QSCALE; v.z *= QSCALE; v.w *= QSCALE; }
            if (mode == M_GV) {
                ushort4 vs = *(const ushort4*)(jb.aux + (size_t)gm * 128 + gn);
                v.x *= bfu(vs.x); v.y *= bfu(vs.y); v.z *= bfu(vs.z); v.w *= bfu(vs.w);
            }
            if (mode == M_KVIK || mode == M_KVIV || mode == M_GV) {
                int which = (mode == M_KVIK) ? 0 : 2;
                uint16_t* op = (uint16_t*)jb.out + (size_t)gm * 256 + gn * 2 + which;
                *reinterpret_cast<uint32_t*>(op)     = pk2bf(v.x, v.y);
                *reinterpret_cast<uint32_t*>(op + 4) = pk2bf(v.z, v.w);
            } else if (mode == M_F32) {
                *reinterpret_cast<float4*>((float*)jb.out + (size_t)gm * 128 + gn) =
                    make_float4(v.x, v.y, v.z, v.w);
            } else {
                ushort4 o;
                o.x = f2bf(v.x); o.y = f2bf(v.y); o.z = f2bf(v.z); o.w = f2bf(v.w);
                *reinterpret_cast<ushort4*>((uint16_t*)jb.out + (size_t)gm * 128 + gn) = o;
            }
        }
    }
}

// ---------------------------------------------------------------- casts
__global__ void castbf_k(const float* __restrict__ in, uint16_t* __restrict__ out, int n4)
{
    int i = blockIdx.x * blockDim.x + threadIdx.x;
    int stride = gridDim.x * blockDim.x;
    for (; i < n4; i += stride) {
        float4 v = reinterpret_cast<const float4*>(in)[i];
        ushort4 o;
        o.x = f2bf(v.x); o.y = f2bf(v.y); o.z = f2bf(v.z); o.w = f2bf(v.w);
        reinterpret_cast<ushort4*>(out)[i] = o;
    }
}

__global__ void castWT_k(const float* __restrict__ W, uint16_t* __restrict__ WT, int Nc)
{
    int i = blockIdx.x * blockDim.x + threadIdx.x;
    if (i >= 128 * Nc) return;
    int n = i >> 7, k = i & 127;
    WT[i] = f2bf(W[(size_t)k * Nc + n]);
}

struct WT6 { const float* src[6]; uint16_t* dst[6]; };
__global__ void castWT6_k(WT6 jb)
{
    int y = blockIdx.y;
    const float* W = jb.src[y];
    uint16_t* WT = jb.dst[y];
    int i = blockIdx.x * 256 + threadIdx.x;
    int n = i >> 7, k = i & 127;
    WT[i] = f2bf(W[k * 128 + n]);
}

// ---------------------------------------------------------------- D x 8 bias projection (bf16 A)
__global__ __launch_bounds__(256) void bias8_k(
    const uint16_t* __restrict__ Ab, const float* __restrict__ w,
    float* __restrict__ B, int M)
{
    int lane = threadIdx.x & 63;
    int row = blockIdx.x * 4 + (threadIdx.x >> 6);
    if (row >= M) return;
    uint32_t wv = *reinterpret_cast<const uint32_t*>(Ab + (size_t)row * 128 + 2 * lane);
    float x0 = bf_lo(wv), x1 = bf_hi(wv);
    const float4* wp = reinterpret_cast<const float4*>(w + (size_t)(2 * lane) * 8);
    float4 wa0 = wp[0], wa1 = wp[1];
    float4 wb0 = wp[2], wb1 = wp[3];
    float p[8];
    p[0] = x0 * wa0.x + x1 * wb0.x;  p[1] = x0 * wa0.y + x1 * wb0.y;
    p[2] = x0 * wa0.z + x1 * wb0.z;  p[3] = x0 * wa0.w + x1 * wb0.w;
    p[4] = x0 * wa1.x + x1 * wb1.x;  p[5] = x0 * wa1.y + x1 * wb1.y;
    p[6] = x0 * wa1.z + x1 * wb1.z;  p[7] = x0 * wa1.w + x1 * wb1.w;
    float r = 0.f;
#pragma unroll
    for (int h = 0; h < 8; h++) {
        float v = p[h];
        v += __shfl_xor(v, 1);  v += __shfl_xor(v, 2);  v += __shfl_xor(v, 4);
        v += __shfl_xor(v, 8);  v += __shfl_xor(v, 16); v += __shfl_xor(v, 32);
        if (lane == h) r = v;
    }
    if (lane < 8) B[(size_t)row * 8 + lane] = r;
}

// ---------------------------------------------------------------- add + LayerNorm
__global__ __launch_bounds__(256) void addln_k(
    const float* __restrict__ Xf, const uint16_t* __restrict__ Xb,
    const float* __restrict__ Y,
    const float* __restrict__ g, const float* __restrict__ b,
    float* __restrict__ Of, uint16_t* __restrict__ Ob, int M)
{
    int lane = threadIdx.x & 63;
    int row = blockIdx.x * 4 + (threadIdx.x >> 6);
    if (row >= M) return;
    size_t base = (size_t)row * 128 + 2 * lane;
    float x0, x1;
    if (Xb) {
        uint32_t wv = *reinterpret_cast<const uint32_t*>(Xb + base);
        x0 = bf_lo(wv); x1 = bf_hi(wv);
    } else {
        float2 xa = *reinterpret_cast<const float2*>(Xf + base);
        x0 = xa.x; x1 = xa.y;
    }
    float2 ya = *reinterpret_cast<const float2*>(Y + base);
    float t0 = x0 + ya.x, t1 = x1 + ya.y;
    float s = t0 + t1;
#pragma unroll
    for (int o = 1; o < 64; o <<= 1) s += __shfl_xor(s, o);
    float mean = s * (1.f / 128.f);
    float d0 = t0 - mean, d1 = t1 - mean;
    float q = d0 * d0 + d1 * d1;
#pragma unroll
    for (int o = 1; o < 64; o <<= 1) q += __shfl_xor(q, o);
    float rstd = rsqrtf(q * (1.f / 128.f) + 1e-5f);
    float2 gg = *reinterpret_cast<const float2*>(g + 2 * lane);
    float2 bb = *reinterpret_cast<const float2*>(b + 2 * lane);
    float o0 = gg.x * d0 * rstd + bb.x, o1 = gg.y * d1 * rstd + bb.y;
    if (Of) *reinterpret_cast<float2*>(Of + base) = make_float2(o0, o1);
    if (Ob) *reinterpret_cast<uint32_t*>(Ob + base) = pk2bf(o0, o1);
}

// ---------------------------------------------------------------- bucketed CSR build
// seg(i) = nbr_src[i] for i<E1, else N+inc_tgt[i-E1]; payload likewise.
#define NBKT_MAX 256

// per-block LDS bucket histogram -> global bucket counts
__global__ __launch_bounds__(256) void binH_k(
    const int* __restrict__ s1, const int* __restrict__ s2,
    int* __restrict__ bktcnt, int E1, int E2, int N, int shift, int nbkt, int chunk)
{
    __shared__ int hist[NBKT_MAX];
    int t = threadIdx.x;
    for (int i = t; i < nbkt; i += 256) hist[i] = 0;
    __syncthreads();
    int Et = E1 + E2;
    int base = blockIdx.x * chunk;
    int end = min(base + chunk, Et);
    for (int i = base + t; i < end; i += 256) {
        int seg = (i < E1) ? s1[i] : N + s2[i - E1];
        atomicAdd(&hist[seg >> shift], 1);
    }
    __syncthreads();
    for (int i = t; i < nbkt; i += 256)
        if (hist[i]) atomicAdd(&bktcnt[i], hist[i]);
}

// exclusive scan of bucket counts -> bases + cursors (nbkt <= 256)
__global__ __launch_bounds__(256) void bktscan_k(
    const int* __restrict__ bktcnt, int* __restrict__ bktbase,
    int* __restrict__ bktcur, int nbkt)
{
    __shared__ int wt[4];
    int t = threadIdx.x, lane = t & 63, w = t >> 6;
    int v = (t < nbkt) ? bktcnt[t] : 0;
    int s = v;
#pragma unroll
    for (int o = 1; o < 64; o <<= 1) { int x = __shfl_up(s, o); if (lane >= o) s += x; }
    if (lane == 63) wt[w] = s;
    __syncthreads();
    int add = 0;
    for (int i = 0; i < w; i++) add += wt[i];
    int excl = add + s - v;
    if (t < nbkt) { bktbase[t] = excl; bktcur[t] = excl; }
    if (t == nbkt - 1) bktbase[nbkt] = excl + v;
}

// bucket-partition (seg,pay) pairs into tmp
__global__ __launch_bounds__(256) void binA_k(
    const int* __restrict__ s1, const int* __restrict__ p1,
    const int* __restrict__ s2, const int* __restrict__ p2,
    int* __restrict__ bktcur, uint2* __restrict__ tmp,
    int E1, int E2, int N, int shift, int nbkt, int chunk)
{
    __shared__ int hist[NBKT_MAX];
    __shared__ int lcur[NBKT_MAX];
    int t = threadIdx.x;
    int Et = E1 + E2;
    int base = blockIdx.x * chunk;
    int end = min(base + chunk, Et);
    for (int i = t; i < nbkt; i += 256) hist[i] = 0;
    __syncthreads();
    for (int i = base + t; i < end; i += 256) {
        int seg = (i < E1) ? s1[i] : N + s2[i - E1];
        atomicAdd(&hist[seg >> shift], 1);
    }
    __syncthreads();
    for (int i = t; i < nbkt; i += 256) {
        int c = hist[i];
        lcur[i] = c ? atomicAdd(&bktcur[i], c) : 0;
    }
    __syncthreads();
    for (int i = base + t; i < end; i += 256) {
        int seg, pay;
        if (i < E1) { seg = s1[i]; pay = p1[i]; }
        else        { seg = N + s2[i - E1]; pay = p2[i - E1]; }
        int p = atomicAdd(&lcur[seg >> shift], 1);
        tmp[p] = make_uint2((uint32_t)seg, (uint32_t)pay);
    }
}

// per-bucket LDS per-segment histogram -> cnt (coalesced, no global atomics)
__global__ __launch_bounds__(256) void binC_k(
    const uint2* __restrict__ tmp, const int* __restrict__ bktbase,
    int* __restrict__ cnt, int NN, int spb)
{
    extern __shared__ int hist[];
    int b = blockIdx.x, t = threadIdx.x;
    int s0 = b * spb;
    int segs = min(spb, NN - s0);
    for (int i = t; i < segs; i += 256) hist[i] = 0;
    __syncthreads();
    int p0 = bktbase[b], p1 = bktbase[b + 1];
    for (int i = p0 + t; i < p1; i += 256)
        atomicAdd(&hist[(int)tmp[i].x - s0], 1);
    __syncthreads();
    for (int i = t; i < segs; i += 256) cnt[s0 + i] = hist[i];
}

// final scatter: reads sequential, writes/atomics L2-window-local
__global__ void binB_k(const uint2* __restrict__ tmp, int* __restrict__ cur,
                       int* __restrict__ sorted, int Et)
{
    int i = blockIdx.x * blockDim.x + threadIdx.x;
    if (i < Et) {
        uint2 pr = tmp[i];
        int p = atomicAdd(&cur[pr.x], 1);
        sorted[p] = (int)pr.y;
    }
}

// ---------------------------------------------------------------- segment-count scans (unchanged)
__global__ __launch_bounds__(256) void scan1_k(
    const int* __restrict__ cnt, int* __restrict__ pre, int* __restrict__ bsum, int N)
{
    __shared__ int wtot[4];
    int t = threadIdx.x, lane = t & 63, wid = t >> 6;
    int base = blockIdx.x * 2048 + t * 8;
    int v[8];
    if (base + 8 <= N) {
        int4 a = *reinterpret_cast<const int4*>(cnt + base);
        int4 b = *reinterpret_cast<const int4*>(cnt + base + 4);
        v[0] = a.x; v[1] = a.y; v[2] = a.z; v[3] = a.w;
        v[4] = b.x; v[5] = b.y; v[6] = b.z; v[7] = b.w;
    } else {
#pragma unroll
        for (int i = 0; i < 8; i++) v[i] = (base + i < N) ? cnt[base + i] : 0;
    }
    int inc_[8]; int s = 0;
#pragma unroll
    for (int i = 0; i < 8; i++) { s += v[i]; inc_[i] = s; }
    int tot = s;
    int wp = tot;
#pragma unroll
    for (int o = 1; o < 64; o <<= 1) { int x = __shfl_up(wp, o); if (lane >= o) wp += x; }
    if (lane == 63) wtot[wid] = wp;
    __syncthreads();
    int wex = 0;
    for (int w = 0; w < wid; w++) wex += wtot[w];
    int tex = wex + wp - tot;
#pragma unroll
    for (int i = 0; i < 8; i++)
        if (base + i < N) pre[base + i] = tex + inc_[i] - v[i];
    if (t == 255) bsum[blockIdx.x] = wex + wp;
}

__global__ void scan2_k(int* __restrict__ bsum, int B)
{
    int lane = threadIdx.x;
    int v = (lane < B) ? bsum[lane] : 0;
    int s = v;
#pragma unroll
    for (int o = 1; o < 64; o <<= 1) { int x = __shfl_up(s, o); if (lane >= o) s += x; }
    if (lane < B) bsum[lane] = s - v;
}

__global__ __launch_bounds__(256) void scan3_k(
    const int* __restrict__ pre, const int* __restrict__ bsum,
    int* __restrict__ offs, int* __restrict__ cur, int N, int E)
{
    int base = blockIdx.x * 2048 + threadIdx.x * 8;
    int add = bsum[blockIdx.x];
    if (base + 8 <= N) {
        int4 a = *reinterpret_cast<const int4*>(pre + base);
        int4 b = *reinterpret_cast<const int4*>(pre + base + 4);
        a.x += add; a.y += add; a.z += add; a.w += add;
        b.x += add; b.y += add; b.z += add; b.w += add;
        *reinterpret_cast<int4*>(offs + base) = a;
        *reinterpret_cast<int4*>(offs + base + 4) = b;
        *reinterpret_cast<int4*>(cur + base) = a;
        *reinterpret_cast<int4*>(cur + base + 4) = b;
    } else {
#pragma unroll
        for (int i = 0; i < 8; i++)
            if (base + i < N) { int x = pre[base + i] + add; offs[base + i] = x; cur[base + i] = x; }
    }
    if (blockIdx.x == 0 && threadIdx.x == 0) offs[N] = E;
}

// ---------------------------------------------------------------- self-attention (max-free softmax)
#define SEDGE(J, IDX)                                                            \
    {                                                                            \
        int dst = sdst[IDX];                                                     \
        uint2 kv = *reinterpret_cast<const uint2*>(kb + ((size_t)dst << 8));     \
        float s = q0 * bf_lo(kv.x) + q1 * bf_hi(kv.x);                           \
        s += __shfl_xor(s, 1); s += __shfl_xor(s, 2); s += __shfl_xor(s, 4);     \
        float w = __expf(s + bs);                                                \
        pa##J = fmaf(w, bf_lo(kv.y), pa##J);                                     \
        pb##J = fmaf(w, bf_hi(kv.y), pb##J);                                     \
        dn##J += w;                                                              \
    }

__global__ __launch_bounds__(256) void self_attn_k(
    const uint16_t* __restrict__ Qb, const uint16_t* __restrict__ kvi,
    const float* __restrict__ bias1,
    const int* __restrict__ offs, const int* __restrict__ sdst,
    const uint16_t* __restrict__ g16, uint16_t* __restrict__ Aout, int N)
{
    int lane = threadIdx.x & 63;
    int n = blockIdx.x * 4 + (threadIdx.x >> 6);
    if (n >= N) return;
    uint32_t qw = *reinterpret_cast<const uint32_t*>(Qb + (size_t)n * 128 + 2 * lane);
    float q0 = bf_lo(qw), q1 = bf_hi(qw);
    float bs = bias1[(size_t)n * 8 + (lane >> 3)];
    int e0 = offs[n], e1 = offs[n + 1];
    const uint16_t* kb = kvi + lane * 4;
    float dn0 = 0.f, pa0 = 0.f, pb0 = 0.f;
    float dn1 = 0.f, pa1 = 0.f, pb1 = 0.f;
    int e = e0;
    for (; e + 4 <= e1; e += 4) {
        SEDGE(0, e)
        SEDGE(1, e + 1)
        SEDGE(0, e + 2)
        SEDGE(1, e + 3)
    }
    for (; e < e1; ++e) SEDGE(0, e)
    float den = dn0 + dn1, a0 = pa0 + pa1, a1 = pb0 + pb1;
    float inv = 1.f / (den + 1e-30f);
    uint32_t gw = *reinterpret_cast<const uint32_t*>(g16 + (size_t)n * 128 + 2 * lane);
    a0 *= inv * bf_lo(gw); a1 *= inv * bf_hi(gw);
    *reinterpret_cast<uint32_t*>(Aout + (size_t)n * 128 + 2 * lane) = pk2bf(a0, a1);
}

// ---------------------------------------------------------------- cross-attention (max-free, V pre-gated)
#define CEDGE(J, IDX)                                                            \
    {                                                                            \
        int src = ssrc[IDX];                                                     \
        uint2 kv = *reinterpret_cast<const uint2*>(kb + ((size_t)src << 8));     \
        float bss = bias_s[(size_t)src * 8 + (lane >> 3)];                       \
        float s = q0 * bf_lo(kv.x) + q1 * bf_hi(kv.x);                           \
        s += __shfl_xor(s, 1); s += __shfl_xor(s, 2); s += __shfl_xor(s, 4);     \
        float w = __expf(s + bt + bss);                                          \
        pa##J = fmaf(w, bf_lo(kv.y), pa##J);                                     \
        pb##J = fmaf(w, bf_hi(kv.y), pb##J);                                     \
        dn##J += w;                                                              \
    }

__global__ __launch_bounds__(256) void cross_attn_k(
    const uint16_t* __restrict__ Qcb, const float* __restrict__ bias_t,
    const uint16_t* __restrict__ kvgi, const float* __restrict__ bias_s,
    const int* __restrict__ offs, const int* __restrict__ ssrc,
    const uint16_t* __restrict__ g16, uint16_t* __restrict__ Aout, int N)
{
    int lane = threadIdx.x & 63;
    int n = blockIdx.x * 4 + (threadIdx.x >> 6);
    if (n >= N) return;
    uint32_t qw = *reinterpret_cast<const uint32_t*>(Qcb + (size_t)n * 128 + 2 * lane);
    float q0 = bf_lo(qw), q1 = bf_hi(qw);
    float bt = bias_t[(size_t)n * 8 + (lane >> 3)];
    int e0 = offs[n], e1 = offs[n + 1];
    const uint16_t* kb = kvgi + lane * 4;
    float dn0 = 0.f, pa0 = 0.f, pb0 = 0.f;
    float dn1 = 0.f, pa1 = 0.f, pb1 = 0.f;
    int e = e0;
    for (; e + 4 <= e1; e += 4) {
        CEDGE(0, e)
        CEDGE(1, e + 1)
        CEDGE(0, e + 2)
        CEDGE(1, e + 3)
    }
    for (; e < e1; ++e) CEDGE(0, e)
    float den = dn0 + dn1, a0 = pa0 + pa1, a1 = pb0 + pb1;
    float inv = 1.f / (den + 1e-30f);
    uint32_t gw = *reinterpret_cast<const uint32_t*>(g16 + (size_t)n * 128 + 2 * lane);
    a0 *= inv * bf_lo(gw); a1 *= inv * bf_hi(gw);
    *reinterpret_cast<uint32_t*>(Aout + (size_t)n * 128 + 2 * lane) = pk2bf(a0, a1);
}

// ---------------------------------------------------------------- host
static inline size_t smax_(size_t a, size_t b) { return a > b ? a : b; }

extern "C" void kernel_launch(void* const* d_in, const int* in_sizes, int n_in,
                              void* d_out, int out_size, void* d_ws, size_t ws_size,
                              hipStream_t stream)
{
    const float* X          = (const float*)d_in[0];
    const float* Xs         = (const float*)d_in[1];
    const float* W_qkv      = (const float*)d_in[2];
    const float* w_bias     = (const float*)d_in[3];
    const float* W_gate     = (const float*)d_in[4];
    const float* b_gate     = (const float*)d_in[5];
    const float* W_o        = (const float*)d_in[6];
    const float* W_q        = (const float*)d_in[7];
    const float* W_kv       = (const float*)d_in[8];
    const float* w_bias_tgt = (const float*)d_in[9];
    const float* w_bias_src = (const float*)d_in[10];
    const float* W_gate_tgt = (const float*)d_in[11];
    const float* b_gate_tgt = (const float*)d_in[12];
    const float* W_gate_src = (const float*)d_in[13];
    const float* b_gate_src = (const float*)d_in[14];
    const float* W_o2       = (const float*)d_in[15];
    const float* ln1_g      = (const float*)d_in[16];
    const float* ln1_b      = (const float*)d_in[17];
    const float* ln2_g      = (const float*)d_in[18];
    const float* ln2_b      = (const float*)d_in[19];
    const int* nbr_src      = (const int*)d_in[20];
    const int* nbr_dst      = (const int*)d_in[21];
    const int* inc_tgt      = (const int*)d_in[22];
    const int* inc_src      = (const int*)d_in[23];

    const int N  = in_sizes[0] / 128;
    const int NS = in_sizes[1] / 128;
    const int E1 = in_sizes[20];
    const int E2 = in_sizes[22];
    const int Et = E1 + E2;
    const int NN = 2 * N;
    const int Npad  = (N + 127) & ~127;
    const int NSpad = (NS + 127) & ~127;

    // bucket geometry: spb = 2^shift segments/bucket, nbkt <= 256
    int shift = 9;
    while (((NN + (1 << shift) - 1) >> shift) > NBKT_MAX) ++shift;
    const int spb  = 1 << shift;
    const int nbkt = (NN + spb - 1) >> shift;

    char* ws = (char*)d_ws;
    size_t off = 0;
    auto alloc = [&](size_t bytes) -> void* {
        void* p = ws + off;
        off = (off + bytes + 255) & ~(size_t)255;
        return p;
    };

    uint16_t* Xb   = (uint16_t*)alloc((size_t)Npad * 128 * 2);
    uint16_t* Xsb  = (uint16_t*)alloc((size_t)NSpad * 128 * 2);
    uint16_t* WTq  = (uint16_t*)alloc((size_t)384 * 128 * 2);
    uint16_t* WTkv = (uint16_t*)alloc((size_t)256 * 128 * 2);
    uint16_t* WTg  = (uint16_t*)alloc((size_t)128 * 128 * 2);
    uint16_t* WTo  = (uint16_t*)alloc((size_t)128 * 128 * 2);
    uint16_t* WTq2 = (uint16_t*)alloc((size_t)128 * 128 * 2);
    uint16_t* WTgt = (uint16_t*)alloc((size_t)128 * 128 * 2);
    uint16_t* WTgs = (uint16_t*)alloc((size_t)128 * 128 * 2);
    uint16_t* WTo2 = (uint16_t*)alloc((size_t)128 * 128 * 2);
    // S1: phase1 {Qb + kvi} / phase2 {kvgi + V16}; also aliased by CSR tmp pairs
    size_t s1a = (size_t)Npad * 384 * 2;
    size_t s1b = (size_t)NSpad * 384 * 2;
    size_t s1c = (size_t)Et * 8;
    uint16_t* S1 = (uint16_t*)alloc(smax_(smax_(s1a, s1b), s1c));
    uint16_t* Qb   = S1;
    uint16_t* kvi  = S1 + (size_t)Npad * 128;
    uint16_t* kvgi = S1;
    uint16_t* V16  = S1 + (size_t)NSpad * 256;
    uint2*    tmp  = (uint2*)S1;          // CSR pairs; dead before S1 reused
    float* S2 = (float*)alloc((size_t)N * 128 * 4);
    float* sa = S2;
    float* ca = S2;
    uint16_t* g16  = (uint16_t*)alloc((size_t)N * 128 * 2);
    uint16_t* Qcb  = (uint16_t*)alloc((size_t)N * 128 * 2);
    uint16_t* Awo  = (uint16_t*)alloc((size_t)Npad * 128 * 2);
    uint16_t* hb   = (uint16_t*)alloc((size_t)Npad * 128 * 2);
    float*    b8a  = (float*)alloc((size_t)N * 8 * 4);
    float*    b8s  = (float*)alloc((size_t)NS * 8 * 4);
    int* cnt    = (int*)alloc((size_t)NN * 4);   // counts, then cursor
    int* pre    = (int*)alloc((size_t)NN * 4);
    int* bsum   = (int*)alloc(256 * 4);
    int* offs   = (int*)alloc((size_t)(NN + 1) * 4);
    int* sorted = (int*)alloc((size_t)Et * 4);
    int* bktcnt = (int*)alloc((size_t)NBKT_MAX * 4);
    int* bktbase= (int*)alloc((size_t)(NBKT_MAX + 1) * 4);
    int* bktcur = (int*)alloc((size_t)NBKT_MAX * 4);
    (void)ws_size; (void)n_in; (void)out_size;

    const int gA  = Npad / 128;
    const int gAs = NSpad / 128;
    const int gW  = (N + 3) / 4;
    const int gWs = (NS + 3) / 4;
    const int B1  = (NN + 2047) / 2048;
    const int BINB = 128;                       // blocks for binH/binA
    const int chunk = (Et + BINB - 1) / BINB;

    // ---- prep: casts (weights + activations)
    castbf_k<<<2048, 256, 0, stream>>>(X,  Xb,  N * 32);
    castbf_k<<<2048, 256, 0, stream>>>(Xs, Xsb, NS * 32);
    castWT_k<<<(128 * 384 + 255) / 256, 256, 0, stream>>>(W_qkv, WTq, 384);
    castWT_k<<<(128 * 256 + 255) / 256, 256, 0, stream>>>(W_kv, WTkv, 256);
    {
        WT6 jb;
        jb.src[0] = W_gate;     jb.dst[0] = WTg;
        jb.src[1] = W_o;        jb.dst[1] = WTo;
        jb.src[2] = W_q;        jb.dst[2] = WTq2;
        jb.src[3] = W_gate_tgt; jb.dst[3] = WTgt;
        jb.src[4] = W_gate_src; jb.dst[4] = WTgs;
        jb.src[5] = W_o2;       jb.dst[5] = WTo2;
        castWT6_k<<<dim3(64, 6), 256, 0, stream>>>(jb);
    }

    // ---- bucketed CSR build (both edge lists, 2N segments)
    hipMemsetAsync(bktcnt, 0, (size_t)NBKT_MAX * 4, stream);
    binH_k<<<BINB, 256, 0, stream>>>(nbr_src, inc_tgt, bktcnt, E1, E2, N, shift, nbkt, chunk);
    bktscan_k<<<1, 256, 0, stream>>>(bktcnt, bktbase, bktcur, nbkt);
    binA_k<<<BINB, 256, 0, stream>>>(nbr_src, nbr_dst, inc_tgt, inc_src,
                                     bktcur, tmp, E1, E2, N, shift, nbkt, chunk);
    binC_k<<<nbkt, 256, spb * 4, stream>>>(tmp, bktbase, cnt, NN, spb);
    scan1_k<<<B1, 256, 0, stream>>>(cnt, pre, bsum, NN);
    scan2_k<<<1, 64, 0, stream>>>(bsum, B1);
    scan3_k<<<B1, 256, 0, stream>>>(pre, bsum, offs, cnt, NN, Et);
    binB_k<<<(Et + 255) / 256, 256, 0, stream>>>(tmp, cnt, sorted, Et);

    // ---- stage 1 projections: Q(x0.25), K, V interleaved, gate — one dispatch
    {
        GemmJobs jb;
        jb.j[0] = { WTq,             nullptr, nullptr, Qb,  M_QS };
        jb.j[1] = { WTq + 128 * 128, nullptr, nullptr, kvi, M_KVIK };
        jb.j[2] = { WTq + 256 * 128, nullptr, nullptr, kvi, M_KVIV };
        jb.j[3] = { WTg,             b_gate,  nullptr, g16, M_SIG };
        multi_gemm_k<<<dim3(gA, 4), 256, 0, stream>>>(Xb, jb, N);
    }
    bias8_k<<<gW, 256, 0, stream>>>(Xb, w_bias, b8a, N);

    // ---- self-attention (fused gate-mul, bf16 out)
    self_attn_k<<<gW, 256, 0, stream>>>(Qb, kvi, b8a, offs, sorted, g16, Awo, N);
    {
        GemmJobs jb;
        jb.j[0] = { WTo, nullptr, nullptr, sa, M_F32 };
        multi_gemm_k<<<dim3(gA, 1), 256, 0, stream>>>(Awo, jb, N);
    }
    addln_k<<<gW, 256, 0, stream>>>(X, nullptr, sa, ln1_g, ln1_b, nullptr, hb, N);

    // ---- stage 2 projections
    {
        GemmJobs jb;
        jb.j[0] = { WTq2, nullptr,    nullptr, Qcb, M_QS };
        jb.j[1] = { WTgt, b_gate_tgt, nullptr, g16, M_SIG };
        multi_gemm_k<<<dim3(gA, 2), 256, 0, stream>>>(hb, jb, N);
    }
    bias8_k<<<gW, 256, 0, stream>>>(hb, w_bias_tgt, b8a, N);
    {
        GemmJobs jb;
        jb.j[0] = { WTkv,             nullptr, nullptr, kvgi, M_KVIK };
        jb.j[1] = { WTkv + 128 * 128, nullptr, nullptr, V16,  M_BF16 };
        multi_gemm_k<<<dim3(gAs, 2), 256, 0, stream>>>(Xsb, jb, NS);
    }
    {
        GemmJobs jb;   // gv = sigmoid(Xs@Wgs+b) * Vc -> interleaved V slot
        jb.j[0] = { WTgs, b_gate_src, V16, kvgi, M_GV };
        multi_gemm_k<<<dim3(gAs, 1), 256, 0, stream>>>(Xsb, jb, NS);
    }
    bias8_k<<<gWs, 256, 0, stream>>>(Xsb, w_bias_src, b8s, NS);

    // ---- cross-attention (fused gtgt-mul, bf16 out)
    cross_attn_k<<<gW, 256, 0, stream>>>(Qcb, b8a, kvgi, b8s, offs + N, sorted, g16, Awo, N);
    {
        GemmJobs jb;
        jb.j[0] = { WTo2, nullptr, nullptr, ca, M_F32 };
        multi_gemm_k<<<dim3(gA, 1), 256, 0, stream>>>(Awo, jb, N);
    }
    addln_k<<<gW, 256, 0, stream>>>(nullptr, hb, ca, ln2_g, ln2_b, (float*)d_out, nullptr, N);
}

// Round 6
// 437.361 us; speedup vs baseline: 2.2890x; 1.1309x over previous
//
#include <hip/hip_runtime.h>
#include <stdint.h>

// ---------------------------------------------------------------- helpers
__device__ __forceinline__ float bf_lo(uint32_t w) { return __uint_as_float(w << 16); }
__device__ __forceinline__ float bf_hi(uint32_t w) { return __uint_as_float(w & 0xffff0000u); }
__device__ __forceinline__ float bfu(uint16_t u) { return __uint_as_float((uint32_t)u << 16); }
__device__ __forceinline__ uint16_t f2bf(float f) {
    uint32_t u = __float_as_uint(f);
    uint32_t r = ((u >> 16) & 1u) + 0x7fffu;   // round-to-nearest-even
    return (uint16_t)((u + r) >> 16);
}
__device__ __forceinline__ uint32_t pk2bf(float a, float b) {
    return (uint32_t)f2bf(a) | ((uint32_t)f2bf(b) << 16);
}
__device__ __forceinline__ void gload_lds16(const void* g, void* l) {
    __builtin_amdgcn_global_load_lds(
        (const __attribute__((address_space(1))) void*)g,
        (__attribute__((address_space(3))) void*)l, 16, 0, 0);
}

typedef __attribute__((ext_vector_type(8))) short bf16x8;
typedef __attribute__((ext_vector_type(4))) float f32x4;

#define LOG2E 1.4426950408889634f
#define QSC2  (0.25f * LOG2E)      // fold 1/sqrt(dk) and log2e into Q

// gemm epilogue modes
#define M_BF16 0   // bf16 out [M][128]
#define M_QS   1   // bf16 out, scaled by QSC2
#define M_SIG  2   // sigmoid(acc+bias), bf16 out
#define M_KVIK 3   // interleaved K slot of [M][256]
#define M_KVIV 4   // interleaved V slot
#define M_GV   5   // sigmoid(acc+bias) * aux -> interleaved V slot
#define M_LN1  6   // LN(residf32 + acc) -> bf16 out
#define M_LN2  7   // LN(residbf16 + acc) -> f32 out

struct GemmJob {
    const uint16_t* A; const uint16_t* WT; const float* bias;
    const uint16_t* aux; const void* resid;
    const float* lng; const float* lnb;
    void* out; int M; int mode;
};
struct GemmJobs { GemmJob j[4]; };

// ---------------------------------------------------------------- MFMA GEMM (multi-job, multi-A)
// One 128x128 tile/block, whole K=128 in LDS, XOR swizzle both-sides (rule 21),
// D=C^T operand swap so lane's 4 acc elems are 4 consecutive columns.
__global__ __launch_bounds__(256) void multi_gemm_k(GemmJobs jobs)
{
    __shared__ uint16_t As[128 * 128];
    __shared__ uint16_t Ws[128 * 128];
    const GemmJob jb = jobs.j[blockIdx.y];
    const int m0 = blockIdx.x * 128;
    if (m0 >= jb.M) return;
    const int tid = threadIdx.x;
    const int wid = tid >> 6;
    const int lane = tid & 63;

    {
        const uint16_t* Ab = jb.A + (size_t)m0 * 128;
        const uint16_t* Wb = jb.WT;
#pragma unroll
        for (int it = 0; it < 8; ++it) {
            int idx = it * 256 + tid;
            int r = idx >> 4, c = idx & 15;
            int gc = c ^ (r & 7);
            uint16_t* ldsA = As + (size_t)(it * 256 + wid * 64) * 8;
            uint16_t* ldsW = Ws + (size_t)(it * 256 + wid * 64) * 8;
            gload_lds16(Ab + (size_t)r * 128 + gc * 8, ldsA);
            gload_lds16(Wb + (size_t)r * 128 + gc * 8, ldsW);
        }
    }
    __syncthreads();

    const int wr = wid >> 1, wc = wid & 1;
    const int l15 = lane & 15, l4 = lane >> 4;

    f32x4 acc[4][4];
#pragma unroll
    for (int i = 0; i < 4; i++)
#pragma unroll
        for (int j = 0; j < 4; j++) acc[i][j] = (f32x4){0.f, 0.f, 0.f, 0.f};

#pragma unroll
    for (int kk = 0; kk < 4; ++kk) {
        bf16x8 af[4], bff[4];
#pragma unroll
        for (int ni = 0; ni < 4; ++ni) {
            int r = wc * 64 + ni * 16 + l15;
            int cc = (kk * 4 + l4) ^ (r & 7);
            af[ni] = *(const bf16x8*)(Ws + r * 128 + cc * 8);
        }
#pragma unroll
        for (int mi = 0; mi < 4; ++mi) {
            int r = wr * 64 + mi * 16 + l15;
            int cc = (kk * 4 + l4) ^ (r & 7);
            bff[mi] = *(const bf16x8*)(As + r * 128 + cc * 8);
        }
#pragma unroll
        for (int ni = 0; ni < 4; ++ni)
#pragma unroll
            for (int mi = 0; mi < 4; ++mi)
                acc[ni][mi] = __builtin_amdgcn_mfma_f32_16x16x32_bf16(
                    af[ni], bff[mi], acc[ni][mi], 0, 0, 0);
    }

    const int mode = jb.mode;

    if (mode == M_LN1 || mode == M_LN2) {
        // fused add-residual + LayerNorm over full 128-col rows
        __syncthreads();                      // all waves done reading Ws
        float* redS = (float*)Ws;             // [128][2]
        float* redQ = redS + 256;             // [128][2]
        float ps[4], qs[4];
#pragma unroll
        for (int mi = 0; mi < 4; ++mi) {
            int row = wr * 64 + mi * 16 + l15;
            int gm = m0 + row;
            float sum = 0.f, sq = 0.f;
#pragma unroll
            for (int ni = 0; ni < 4; ++ni) {
                int gn = wc * 64 + ni * 16 + l4 * 4;
                float r0 = 0.f, r1 = 0.f, r2 = 0.f, r3 = 0.f;
                if (gm < jb.M) {
                    if (mode == M_LN1) {
                        float4 rv = *(const float4*)((const float*)jb.resid + (size_t)gm * 128 + gn);
                        r0 = rv.x; r1 = rv.y; r2 = rv.z; r3 = rv.w;
                    } else {
                        ushort4 rv = *(const ushort4*)((const uint16_t*)jb.resid + (size_t)gm * 128 + gn);
                        r0 = bfu(rv.x); r1 = bfu(rv.y); r2 = bfu(rv.z); r3 = bfu(rv.w);
                    }
                }
                f32x4 t = acc[ni][mi];
                t.x += r0; t.y += r1; t.z += r2; t.w += r3;
                acc[ni][mi] = t;
                sum += t.x + t.y + t.z + t.w;
                sq  += t.x * t.x + t.y * t.y + t.z * t.z + t.w * t.w;
            }
            sum += __shfl_xor(sum, 16); sum += __shfl_xor(sum, 32);
            sq  += __shfl_xor(sq, 16);  sq  += __shfl_xor(sq, 32);
            ps[mi] = sum; qs[mi] = sq;
        }
        if (l4 == 0) {
#pragma unroll
            for (int mi = 0; mi < 4; ++mi) {
                int row = wr * 64 + mi * 16 + l15;
                redS[row * 2 + wc] = ps[mi];
                redQ[row * 2 + wc] = qs[mi];
            }
        }
        __syncthreads();
#pragma unroll
        for (int mi = 0; mi < 4; ++mi) {
            int row = wr * 64 + mi * 16 + l15;
            int gm = m0 + row;
            if (gm >= jb.M) continue;
            float S = redS[row * 2] + redS[row * 2 + 1];
            float Q = redQ[row * 2] + redQ[row * 2 + 1];
            float mean = S * (1.f / 128.f);
            float var  = Q * (1.f / 128.f) - mean * mean;
            float rstd = rsqrtf(var + 1e-5f);
#pragma unroll
            for (int ni = 0; ni < 4; ++ni) {
                int gn = wc * 64 + ni * 16 + l4 * 4;
                float4 gg = *(const float4*)(jb.lng + gn);
                float4 bb = *(const float4*)(jb.lnb + gn);
                f32x4 t = acc[ni][mi];
                float o0 = gg.x * (t.x - mean) * rstd + bb.x;
                float o1 = gg.y * (t.y - mean) * rstd + bb.y;
                float o2 = gg.z * (t.z - mean) * rstd + bb.z;
                float o3 = gg.w * (t.w - mean) * rstd + bb.w;
                if (mode == M_LN1) {
                    ushort4 o;
                    o.x = f2bf(o0); o.y = f2bf(o1); o.z = f2bf(o2); o.w = f2bf(o3);
                    *(ushort4*)((uint16_t*)jb.out + (size_t)gm * 128 + gn) = o;
                } else {
                    *(float4*)((float*)jb.out + (size_t)gm * 128 + gn) =
                        make_float4(o0, o1, o2, o3);
                }
            }
        }
        return;
    }

#pragma unroll
    for (int mi = 0; mi < 4; ++mi) {
        int gm = m0 + wr * 64 + mi * 16 + l15;
        if (gm >= jb.M) continue;
#pragma unroll
        for (int ni = 0; ni < 4; ++ni) {
            int gn = wc * 64 + ni * 16 + l4 * 4;
            f32x4 v = acc[ni][mi];
            if (mode == M_SIG || mode == M_GV) {
                float4 bb = *(const float4*)(jb.bias + gn);
                v.x = 1.f / (1.f + __expf(-(v.x + bb.x)));
                v.y = 1.f / (1.f + __expf(-(v.y + bb.y)));
                v.z = 1.f / (1.f + __expf(-(v.z + bb.z)));
                v.w = 1.f / (1.f + __expf(-(v.w + bb.w)));
            }
            if (mode == M_QS) { v.x *= QSC2; v.y *= QSC2; v.z *= QSC2; v.w *= QSC2; }
            if (mode == M_GV) {
                ushort4 vs = *(const ushort4*)(jb.aux + (size_t)gm * 128 + gn);
                v.x *= bfu(vs.x); v.y *= bfu(vs.y); v.z *= bfu(vs.z); v.w *= bfu(vs.w);
            }
            if (mode == M_KVIK || mode == M_KVIV || mode == M_GV) {
                int which = (mode == M_KVIK) ? 0 : 2;
                uint16_t* op = (uint16_t*)jb.out + (size_t)gm * 256 + gn * 2 + which;
                *reinterpret_cast<uint32_t*>(op)     = pk2bf(v.x, v.y);
                *reinterpret_cast<uint32_t*>(op + 4) = pk2bf(v.z, v.w);
            } else {
                ushort4 o;
                o.x = f2bf(v.x); o.y = f2bf(v.y); o.z = f2bf(v.z); o.w = f2bf(v.w);
                *reinterpret_cast<ushort4*>((uint16_t*)jb.out + (size_t)gm * 128 + gn) = o;
            }
        }
    }
}

// ---------------------------------------------------------------- prep casts (X, Xs, + zero bktcnt)
__global__ void castbf2_k(const float* __restrict__ in1, uint16_t* __restrict__ out1, int n1,
                          const float* __restrict__ in2, uint16_t* __restrict__ out2, int n2,
                          int* __restrict__ zero256)
{
    if (blockIdx.x == 0 && threadIdx.x < 256) zero256[threadIdx.x] = 0;
    int i = blockIdx.x * blockDim.x + threadIdx.x;
    int stride = gridDim.x * blockDim.x;
    for (; i < n1 + n2; i += stride) {
        float4 v;
        ushort4 o;
        if (i < n1) v = reinterpret_cast<const float4*>(in1)[i];
        else        v = reinterpret_cast<const float4*>(in2)[i - n1];
        o.x = f2bf(v.x); o.y = f2bf(v.y); o.z = f2bf(v.z); o.w = f2bf(v.w);
        if (i < n1) reinterpret_cast<ushort4*>(out1)[i] = o;
        else        reinterpret_cast<ushort4*>(out2)[i - n1] = o;
    }
}

// ---------------------------------------------------------------- 11-job weight transpose: WT[n*128+k] = bf16(W[k*Nc+coff+n])
struct WT11 { const float* src[11]; uint16_t* dst[11]; int nc[11]; int coff[11]; };
__global__ void castWT11_k(WT11 jb)
{
    int y = blockIdx.y;
    const float* W = jb.src[y];
    uint16_t* WT = jb.dst[y];
    int nc = jb.nc[y], coff = jb.coff[y];
    int i = blockIdx.x * 256 + threadIdx.x;   // 16384 per job
    int k = i >> 7, n = i & 127;              // coalesced read
    WT[(size_t)n * 128 + k] = f2bf(W[(size_t)k * nc + coff + n]);
}

// ---------------------------------------------------------------- dual D x 8 bias projection (outputs pre-scaled by log2e)
__global__ __launch_bounds__(256) void bias8_2_k(
    const uint16_t* __restrict__ A1, const float* __restrict__ w1, float* __restrict__ B1, int M1,
    const uint16_t* __restrict__ A2, const float* __restrict__ w2, float* __restrict__ B2, int M2)
{
    int lane = threadIdx.x & 63;
    int row = blockIdx.x * 4 + (threadIdx.x >> 6);
    const uint16_t* A; const float* w; float* B; int r;
    if (row < M1) { A = A1; w = w1; B = B1; r = row; }
    else if (row < M1 + M2) { A = A2; w = w2; B = B2; r = row - M1; }
    else return;
    uint32_t wv = *reinterpret_cast<const uint32_t*>(A + (size_t)r * 128 + 2 * lane);
    float x0 = bf_lo(wv), x1 = bf_hi(wv);
    const float4* wp = reinterpret_cast<const float4*>(w + (size_t)(2 * lane) * 8);
    float4 wa0 = wp[0], wa1 = wp[1];
    float4 wb0 = wp[2], wb1 = wp[3];
    float p[8];
    p[0] = x0 * wa0.x + x1 * wb0.x;  p[1] = x0 * wa0.y + x1 * wb0.y;
    p[2] = x0 * wa0.z + x1 * wb0.z;  p[3] = x0 * wa0.w + x1 * wb0.w;
    p[4] = x0 * wa1.x + x1 * wb1.x;  p[5] = x0 * wa1.y + x1 * wb1.y;
    p[6] = x0 * wa1.z + x1 * wb1.z;  p[7] = x0 * wa1.w + x1 * wb1.w;
    float rr = 0.f;
#pragma unroll
    for (int h = 0; h < 8; h++) {
        float v = p[h];
        v += __shfl_xor(v, 1);  v += __shfl_xor(v, 2);  v += __shfl_xor(v, 4);
        v += __shfl_xor(v, 8);  v += __shfl_xor(v, 16); v += __shfl_xor(v, 32);
        if (lane == h) rr = v;
    }
    if (lane < 8) B[(size_t)r * 8 + lane] = rr * LOG2E;
}

// ---------------------------------------------------------------- bucketed CSR build
#define NBKT_MAX 256

__global__ __launch_bounds__(256) void binH_k(
    const int* __restrict__ s1, const int* __restrict__ s2,
    int* __restrict__ bktcnt, int E1, int E2, int N, int shift, int nbkt, int chunk)
{
    __shared__ int hist[NBKT_MAX];
    int t = threadIdx.x;
    for (int i = t; i < nbkt; i += 256) hist[i] = 0;
    __syncthreads();
    int Et = E1 + E2;
    int base = blockIdx.x * chunk;
    int end = min(base + chunk, Et);
    for (int i = base + t; i < end; i += 256) {
        int seg = (i < E1) ? s1[i] : N + s2[i - E1];
        atomicAdd(&hist[seg >> shift], 1);
    }
    __syncthreads();
    for (int i = t; i < nbkt; i += 256)
        if (hist[i]) atomicAdd(&bktcnt[i], hist[i]);
}

__global__ __launch_bounds__(256) void bktscan_k(
    const int* __restrict__ bktcnt, int* __restrict__ bktbase,
    int* __restrict__ bktcur, int nbkt)
{
    __shared__ int wt[4];
    int t = threadIdx.x, lane = t & 63, w = t >> 6;
    int v = (t < nbkt) ? bktcnt[t] : 0;
    int s = v;
#pragma unroll
    for (int o = 1; o < 64; o <<= 1) { int x = __shfl_up(s, o); if (lane >= o) s += x; }
    if (lane == 63) wt[w] = s;
    __syncthreads();
    int add = 0;
    for (int i = 0; i < w; i++) add += wt[i];
    int excl = add + s - v;
    if (t < nbkt) { bktbase[t] = excl; bktcur[t] = excl; }
    if (t == nbkt - 1) bktbase[nbkt] = excl + v;
}

__global__ __launch_bounds__(256) void binA_k(
    const int* __restrict__ s1, const int* __restrict__ p1,
    const int* __restrict__ s2, const int* __restrict__ p2,
    int* __restrict__ bktcur, uint2* __restrict__ tmp,
    int E1, int E2, int N, int shift, int nbkt, int chunk)
{
    __shared__ int hist[NBKT_MAX];
    __shared__ int lcur[NBKT_MAX];
    int t = threadIdx.x;
    int Et = E1 + E2;
    int base = blockIdx.x * chunk;
    int end = min(base + chunk, Et);
    for (int i = t; i < nbkt; i += 256) hist[i] = 0;
    __syncthreads();
    for (int i = base + t; i < end; i += 256) {
        int seg = (i < E1) ? s1[i] : N + s2[i - E1];
        atomicAdd(&hist[seg >> shift], 1);
    }
    __syncthreads();
    for (int i = t; i < nbkt; i += 256) {
        int c = hist[i];
        lcur[i] = c ? atomicAdd(&bktcur[i], c) : 0;
    }
    __syncthreads();
    for (int i = base + t; i < end; i += 256) {
        int seg, pay;
        if (i < E1) { seg = s1[i]; pay = p1[i]; }
        else        { seg = N + s2[i - E1]; pay = p2[i - E1]; }
        int p = atomicAdd(&lcur[seg >> shift], 1);
        tmp[p] = make_uint2((uint32_t)seg, (uint32_t)pay);
    }
}

// one block per bucket: per-segment hist + LDS scan -> offs, then LDS-cursor scatter
__global__ __launch_bounds__(256) void binD_k(
    const uint2* __restrict__ tmp, const int* __restrict__ bktbase,
    int* __restrict__ offs, int* __restrict__ sorted, int NN, int spb, int Et)
{
    extern __shared__ int sh[];
    __shared__ int wt[4];
    int b = blockIdx.x, t = threadIdx.x;
    int s0 = b * spb;
    int segs = min(spb, NN - s0);
    for (int i = t; i < segs; i += 256) sh[i] = 0;
    __syncthreads();
    int p0 = bktbase[b], p1 = bktbase[b + 1];
    for (int i = p0 + t; i < p1; i += 256)
        atomicAdd(&sh[(int)tmp[i].x - s0], 1);
    __syncthreads();
    int e_per = spb >> 8;                 // 2 for spb=512
    int loc[4]; int ls = 0;
#pragma unroll 4
    for (int j = 0; j < 4; ++j) {
        if (j < e_per) {
            int idx = t * e_per + j;
            int v = (idx < segs) ? sh[idx] : 0;
            loc[j] = ls; ls += v;
        }
    }
    int lane = t & 63, w = t >> 6;
    int sc = ls;
#pragma unroll
    for (int o = 1; o < 64; o <<= 1) { int x = __shfl_up(sc, o); if (lane >= o) sc += x; }
    if (lane == 63) wt[w] = sc;
    __syncthreads();                      // also guards sh reads above
    int add = 0;
    for (int i = 0; i < w; i++) add += wt[i];
    int texcl = add + sc - ls;
#pragma unroll 4
    for (int j = 0; j < 4; ++j) {
        if (j < e_per) {
            int idx = t * e_per + j;
            if (idx < segs) {
                int pos = p0 + texcl + loc[j];
                offs[s0 + idx] = pos;
                sh[idx] = pos;            // becomes cursor
            }
        }
    }
    __syncthreads();
    for (int i = p0 + t; i < p1; i += 256) {
        uint2 pr = tmp[i];
        int p = atomicAdd(&sh[(int)pr.x - s0], 1);
        sorted[p] = (int)pr.y;
    }
    if (b == 0 && t == 0) offs[NN] = Et;
}

// ---------------------------------------------------------------- self-attention (max-free, exp2 domain)
#define SEDGE(J, IDX)                                                            \
    {                                                                            \
        int dst = sdst[IDX];                                                     \
        uint2 kv = *reinterpret_cast<const uint2*>(kb + ((size_t)dst << 8));     \
        float s = q0 * bf_lo(kv.x) + q1 * bf_hi(kv.x);                           \
        s += __shfl_xor(s, 1); s += __shfl_xor(s, 2); s += __shfl_xor(s, 4);     \
        float w = exp2f(s + bs);                                                 \
        pa##J = fmaf(w, bf_lo(kv.y), pa##J);                                     \
        pb##J = fmaf(w, bf_hi(kv.y), pb##J);                                     \
        dn##J += w;                                                              \
    }

__global__ __launch_bounds__(256) void self_attn_k(
    const uint16_t* __restrict__ Qb, const uint16_t* __restrict__ kvi,
    const float* __restrict__ bias1,
    const int* __restrict__ offs, const int* __restrict__ sdst,
    const uint16_t* __restrict__ g16, uint16_t* __restrict__ Aout, int N)
{
    int lane = threadIdx.x & 63;
    int n = blockIdx.x * 4 + (threadIdx.x >> 6);
    if (n >= N) return;
    uint32_t qw = *reinterpret_cast<const uint32_t*>(Qb + (size_t)n * 128 + 2 * lane);
    float q0 = bf_lo(qw), q1 = bf_hi(qw);
    float bs = bias1[(size_t)n * 8 + (lane >> 3)];
    int e0 = offs[n], e1 = offs[n + 1];
    const uint16_t* kb = kvi + lane * 4;
    float dn0 = 0.f, pa0 = 0.f, pb0 = 0.f;
    float dn1 = 0.f, pa1 = 0.f, pb1 = 0.f;
    int e = e0;
    for (; e + 4 <= e1; e += 4) {
        SEDGE(0, e)
        SEDGE(1, e + 1)
        SEDGE(0, e + 2)
        SEDGE(1, e + 3)
    }
    for (; e < e1; ++e) SEDGE(0, e)
    float den = dn0 + dn1, a0 = pa0 + pa1, a1 = pb0 + pb1;
    float inv = 1.f / (den + 1e-30f);
    uint32_t gw = *reinterpret_cast<const uint32_t*>(g16 + (size_t)n * 128 + 2 * lane);
    a0 *= inv * bf_lo(gw); a1 *= inv * bf_hi(gw);
    *reinterpret_cast<uint32_t*>(Aout + (size_t)n * 128 + 2 * lane) = pk2bf(a0, a1);
}

// ---------------------------------------------------------------- cross-attention (max-free, V pre-gated)
#define CEDGE(J, IDX)                                                            \
    {                                                                            \
        int src = ssrc[IDX];                                                     \
        uint2 kv = *reinterpret_cast<const uint2*>(kb + ((size_t)src << 8));     \
        float bss = bias_s[(size_t)src * 8 + (lane >> 3)];                       \
        float s = q0 * bf_lo(kv.x) + q1 * bf_hi(kv.x);                           \
        s += __shfl_xor(s, 1); s += __shfl_xor(s, 2); s += __shfl_xor(s, 4);     \
        float w = exp2f(s + bt + bss);                                           \
        pa##J = fmaf(w, bf_lo(kv.y), pa##J);                                     \
        pb##J = fmaf(w, bf_hi(kv.y), pb##J);                                     \
        dn##J += w;                                                              \
    }

__global__ __launch_bounds__(256) void cross_attn_k(
    const uint16_t* __restrict__ Qcb, const float* __restrict__ bias_t,
    const uint16_t* __restrict__ kvgi, const float* __restrict__ bias_s,
    const int* __restrict__ offs, const int* __restrict__ ssrc,
    const uint16_t* __restrict__ g16, uint16_t* __restrict__ Aout, int N)
{
    int lane = threadIdx.x & 63;
    int n = blockIdx.x * 4 + (threadIdx.x >> 6);
    if (n >= N) return;
    uint32_t qw = *reinterpret_cast<const uint32_t*>(Qcb + (size_t)n * 128 + 2 * lane);
    float q0 = bf_lo(qw), q1 = bf_hi(qw);
    float bt = bias_t[(size_t)n * 8 + (lane >> 3)];
    int e0 = offs[n], e1 = offs[n + 1];
    const uint16_t* kb = kvgi + lane * 4;
    float dn0 = 0.f, pa0 = 0.f, pb0 = 0.f;
    float dn1 = 0.f, pa1 = 0.f, pb1 = 0.f;
    int e = e0;
    for (; e + 4 <= e1; e += 4) {
        CEDGE(0, e)
        CEDGE(1, e + 1)
        CEDGE(0, e + 2)
        CEDGE(1, e + 3)
    }
    for (; e < e1; ++e) CEDGE(0, e)
    float den = dn0 + dn1, a0 = pa0 + pa1, a1 = pb0 + pb1;
    float inv = 1.f / (den + 1e-30f);
    uint32_t gw = *reinterpret_cast<const uint32_t*>(g16 + (size_t)n * 128 + 2 * lane);
    a0 *= inv * bf_lo(gw); a1 *= inv * bf_hi(gw);
    *reinterpret_cast<uint32_t*>(Aout + (size_t)n * 128 + 2 * lane) = pk2bf(a0, a1);
}

// ---------------------------------------------------------------- host
static inline size_t smax_(size_t a, size_t b) { return a > b ? a : b; }

extern "C" void kernel_launch(void* const* d_in, const int* in_sizes, int n_in,
                              void* d_out, int out_size, void* d_ws, size_t ws_size,
                              hipStream_t stream)
{
    const float* X          = (const float*)d_in[0];
    const float* Xs         = (const float*)d_in[1];
    const float* W_qkv      = (const float*)d_in[2];
    const float* w_bias     = (const float*)d_in[3];
    const float* W_gate     = (const float*)d_in[4];
    const float* b_gate     = (const float*)d_in[5];
    const float* W_o        = (const float*)d_in[6];
    const float* W_q        = (const float*)d_in[7];
    const float* W_kv       = (const float*)d_in[8];
    const float* w_bias_tgt = (const float*)d_in[9];
    const float* w_bias_src = (const float*)d_in[10];
    const float* W_gate_tgt = (const float*)d_in[11];
    const float* b_gate_tgt = (const float*)d_in[12];
    const float* W_gate_src = (const float*)d_in[13];
    const float* b_gate_src = (const float*)d_in[14];
    const float* W_o2       = (const float*)d_in[15];
    const float* ln1_g      = (const float*)d_in[16];
    const float* ln1_b      = (const float*)d_in[17];
    const float* ln2_g      = (const float*)d_in[18];
    const float* ln2_b      = (const float*)d_in[19];
    const int* nbr_src      = (const int*)d_in[20];
    const int* nbr_dst      = (const int*)d_in[21];
    const int* inc_tgt      = (const int*)d_in[22];
    const int* inc_src      = (const int*)d_in[23];

    const int N  = in_sizes[0] / 128;
    const int NS = in_sizes[1] / 128;
    const int E1 = in_sizes[20];
    const int E2 = in_sizes[22];
    const int Et = E1 + E2;
    const int NN = 2 * N;
    const int Npad  = (N + 127) & ~127;
    const int NSpad = (NS + 127) & ~127;

    // bucket geometry
    int shift = 9;
    while (((NN + (1 << shift) - 1) >> shift) > NBKT_MAX) ++shift;
    const int spb  = 1 << shift;
    const int nbkt = (NN + spb - 1) >> shift;

    char* ws = (char*)d_ws;
    size_t off = 0;
    auto alloc = [&](size_t bytes) -> void* {
        void* p = ws + off;
        off = (off + bytes + 255) & ~(size_t)255;
        return p;
    };

    uint16_t* Xb   = (uint16_t*)alloc((size_t)Npad * 128 * 2);
    uint16_t* Xsb  = (uint16_t*)alloc((size_t)NSpad * 128 * 2);
    uint16_t* WTq  = (uint16_t*)alloc((size_t)384 * 128 * 2);
    uint16_t* WTkv = (uint16_t*)alloc((size_t)256 * 128 * 2);
    uint16_t* WTg  = (uint16_t*)alloc((size_t)128 * 128 * 2);
    uint16_t* WTo  = (uint16_t*)alloc((size_t)128 * 128 * 2);
    uint16_t* WTq2 = (uint16_t*)alloc((size_t)128 * 128 * 2);
    uint16_t* WTgt = (uint16_t*)alloc((size_t)128 * 128 * 2);
    uint16_t* WTgs = (uint16_t*)alloc((size_t)128 * 128 * 2);
    uint16_t* WTo2 = (uint16_t*)alloc((size_t)128 * 128 * 2);
    size_t s1a = (size_t)Npad * 384 * 2;
    size_t s1b = (size_t)NSpad * 384 * 2;
    size_t s1c = (size_t)Et * 8;
    uint16_t* S1 = (uint16_t*)alloc(smax_(smax_(s1a, s1b), s1c));
    uint16_t* Qb   = S1;
    uint16_t* kvi  = S1 + (size_t)Npad * 128;
    uint16_t* kvgi = S1;
    uint16_t* V16  = S1 + (size_t)NSpad * 256;
    uint2*    tmp  = (uint2*)S1;          // CSR pairs; dead before S1 reused
    uint16_t* g16  = (uint16_t*)alloc((size_t)N * 128 * 2);
    uint16_t* Qcb  = (uint16_t*)alloc((size_t)N * 128 * 2);
    uint16_t* Awo  = (uint16_t*)alloc((size_t)Npad * 128 * 2);
    uint16_t* hb   = (uint16_t*)alloc((size_t)Npad * 128 * 2);
    float*    b8a  = (float*)alloc((size_t)N * 8 * 4);
    float*    b8s  = (float*)alloc((size_t)NS * 8 * 4);
    int* offs   = (int*)alloc((size_t)(NN + 1) * 4);
    int* sorted = (int*)alloc((size_t)Et * 4);
    int* bktcnt = (int*)alloc((size_t)NBKT_MAX * 4);
    int* bktbase= (int*)alloc((size_t)(NBKT_MAX + 1) * 4);
    int* bktcur = (int*)alloc((size_t)NBKT_MAX * 4);
    (void)ws_size; (void)n_in; (void)out_size;

    const int gA  = Npad / 128;
    const int gAs = NSpad / 128;
    const int gW  = (N + 3) / 4;
    const int BINB = 128;
    const int chunk = (Et + BINB - 1) / BINB;

    // 1. prep casts (+ zero bktcnt)
    castbf2_k<<<2048, 256, 0, stream>>>(X, Xb, N * 32, Xs, Xsb, NS * 32, bktcnt);
    // 2. weight transposes (11 jobs of 128x128)
    {
        WT11 jb;
        jb.src[0] = W_qkv; jb.dst[0] = WTq;          jb.nc[0] = 384; jb.coff[0] = 0;
        jb.src[1] = W_qkv; jb.dst[1] = WTq + 16384;  jb.nc[1] = 384; jb.coff[1] = 128;
        jb.src[2] = W_qkv; jb.dst[2] = WTq + 32768;  jb.nc[2] = 384; jb.coff[2] = 256;
        jb.src[3] = W_kv;  jb.dst[3] = WTkv;         jb.nc[3] = 256; jb.coff[3] = 0;
        jb.src[4] = W_kv;  jb.dst[4] = WTkv + 16384; jb.nc[4] = 256; jb.coff[4] = 128;
        jb.src[5] = W_gate;     jb.dst[5] = WTg;  jb.nc[5] = 128; jb.coff[5] = 0;
        jb.src[6] = W_o;        jb.dst[6] = WTo;  jb.nc[6] = 128; jb.coff[6] = 0;
        jb.src[7] = W_q;        jb.dst[7] = WTq2; jb.nc[7] = 128; jb.coff[7] = 0;
        jb.src[8] = W_gate_tgt; jb.dst[8] = WTgt; jb.nc[8] = 128; jb.coff[8] = 0;
        jb.src[9] = W_gate_src; jb.dst[9] = WTgs; jb.nc[9] = 128; jb.coff[9] = 0;
        jb.src[10]= W_o2;       jb.dst[10]= WTo2; jb.nc[10]= 128; jb.coff[10]= 0;
        castWT11_k<<<dim3(64, 11), 256, 0, stream>>>(jb);
    }

    // 3-6. bucketed CSR (both edge lists, 2N segments)
    binH_k<<<BINB, 256, 0, stream>>>(nbr_src, inc_tgt, bktcnt, E1, E2, N, shift, nbkt, chunk);
    bktscan_k<<<1, 256, 0, stream>>>(bktcnt, bktbase, bktcur, nbkt);
    binA_k<<<BINB, 256, 0, stream>>>(nbr_src, nbr_dst, inc_tgt, inc_src,
                                     bktcur, tmp, E1, E2, N, shift, nbkt, chunk);
    binD_k<<<nbkt, 256, spb * 4, stream>>>(tmp, bktbase, offs, sorted, NN, spb, Et);

    // 7. stage-1 projections: Q(x0.25*log2e), K, V interleaved, gate
    {
        GemmJobs jb;
        jb.j[0] = { Xb, WTq,         nullptr, nullptr, nullptr, nullptr, nullptr, Qb,  N, M_QS };
        jb.j[1] = { Xb, WTq + 16384, nullptr, nullptr, nullptr, nullptr, nullptr, kvi, N, M_KVIK };
        jb.j[2] = { Xb, WTq + 32768, nullptr, nullptr, nullptr, nullptr, nullptr, kvi, N, M_KVIV };
        jb.j[3] = { Xb, WTg,         b_gate,  nullptr, nullptr, nullptr, nullptr, g16, N, M_SIG };
        multi_gemm_k<<<dim3(gA, 4), 256, 0, stream>>>(jb);
    }
    // 8. bias projections for X and Xs
    bias8_2_k<<<(N + NS + 3) / 4, 256, 0, stream>>>(Xb, w_bias, b8a, N,
                                                    Xsb, w_bias_src, b8s, NS);
    // 9. self-attention
    self_attn_k<<<gW, 256, 0, stream>>>(Qb, kvi, b8a, offs, sorted, g16, Awo, N);
    // 10. W_o GEMM + fused add+LN -> hb (bf16)
    {
        GemmJobs jb;
        jb.j[0] = { Awo, WTo, nullptr, nullptr, X, ln1_g, ln1_b, hb, N, M_LN1 };
        multi_gemm_k<<<dim3(gA, 1), 256, 0, stream>>>(jb);
    }
    // 11. stage-2 projections (h-side and Xs-side in one dispatch)
    {
        GemmJobs jb;
        jb.j[0] = { hb,  WTq2,         nullptr,    nullptr, nullptr, nullptr, nullptr, Qcb,  N,  M_QS };
        jb.j[1] = { hb,  WTgt,         b_gate_tgt, nullptr, nullptr, nullptr, nullptr, g16,  N,  M_SIG };
        jb.j[2] = { Xsb, WTkv,         nullptr,    nullptr, nullptr, nullptr, nullptr, kvgi, NS, M_KVIK };
        jb.j[3] = { Xsb, WTkv + 16384, nullptr,    nullptr, nullptr, nullptr, nullptr, V16,  NS, M_BF16 };
        multi_gemm_k<<<dim3(gAs, 4), 256, 0, stream>>>(jb);
    }
    // 12. gv = sigmoid(Xs@Wgs+b) * Vc -> interleaved V slot
    {
        GemmJobs jb;
        jb.j[0] = { Xsb, WTgs, b_gate_src, V16, nullptr, nullptr, nullptr, kvgi, NS, M_GV };
        multi_gemm_k<<<dim3(gAs, 1), 256, 0, stream>>>(jb);
    }
    // 13. bias projection for h
    bias8_2_k<<<gW, 256, 0, stream>>>(hb, w_bias_tgt, b8a, N, nullptr, nullptr, nullptr, 0);
    // 14. cross-attention
    cross_attn_k<<<gW, 256, 0, stream>>>(Qcb, b8a, kvgi, b8s, offs + N, sorted, g16, Awo, N);
    // 15. W_o2 GEMM + fused add+LN -> d_out (f32)
    {
        GemmJobs jb;
        jb.j[0] = { Awo, WTo2, nullptr, nullptr, hb, ln2_g, ln2_b, d_out, N, M_LN2 };
        multi_gemm_k<<<dim3(gA, 1), 256, 0, stream>>>(jb);
    }
}

// Round 7
// 339.515 us; speedup vs baseline: 2.9487x; 1.2882x over previous
//
#include <hip/hip_runtime.h>
#include <stdint.h>

// ---------------------------------------------------------------- helpers
__device__ __forceinline__ float bf_lo(uint32_t w) { return __uint_as_float(w << 16); }
__device__ __forceinline__ float bf_hi(uint32_t w) { return __uint_as_float(w & 0xffff0000u); }
__device__ __forceinline__ float bfu(uint16_t u) { return __uint_as_float((uint32_t)u << 16); }
__device__ __forceinline__ uint16_t f2bf(float f) {
    uint32_t u = __float_as_uint(f);
    uint32_t r = ((u >> 16) & 1u) + 0x7fffu;   // round-to-nearest-even
    return (uint16_t)((u + r) >> 16);
}
__device__ __forceinline__ uint32_t pk2bf(float a, float b) {
    return (uint32_t)f2bf(a) | ((uint32_t)f2bf(b) << 16);
}
__device__ __forceinline__ void gload_lds16(const void* g, void* l) {
    __builtin_amdgcn_global_load_lds(
        (const __attribute__((address_space(1))) void*)g,
        (__attribute__((address_space(3))) void*)l, 16, 0, 0);
}

typedef __attribute__((ext_vector_type(8))) short bf16x8;
typedef __attribute__((ext_vector_type(4))) float f32x4;

#define LOG2E 1.4426950408889634f
#define QSC2  (0.25f * LOG2E)      // fold 1/sqrt(dk) and log2e into Q

// gemm epilogue modes
#define M_BF16 0   // bf16 out [M][128]
#define M_QS   1   // bf16 out, scaled by QSC2
#define M_SIG  2   // sigmoid(acc+bias), bf16 out
#define M_KVIK 3   // interleaved K slot of [M][256]
#define M_KVIV 4   // interleaved V slot
#define M_GV   5   // sigmoid(acc+bias) * aux -> interleaved V slot
#define M_LN1  6   // LN(residf32 + acc) -> bf16 out
#define M_LN2  7   // LN(residbf16 + acc) -> f32 out
#define M_B8   8   // cols 0..7 only -> f32 [M][8] (bias projections)

struct GemmJob {
    const uint16_t* A; const uint16_t* WT; const float* bias;
    const uint16_t* aux; const void* resid;
    const float* lng; const float* lnb;
    void* out; int M; int mode;
};
struct GemmJobs { GemmJob j[6]; };

// ---------------------------------------------------------------- MFMA GEMM (multi-job, multi-A)
// One 128x128 tile/block, whole K=128 in LDS, XOR swizzle both-sides (rule 21),
// D=C^T operand swap so lane's 4 acc elems are 4 consecutive columns.
__global__ __launch_bounds__(256) void multi_gemm_k(GemmJobs jobs)
{
    __shared__ uint16_t As[128 * 128];
    __shared__ uint16_t Ws[128 * 128];
    const GemmJob jb = jobs.j[blockIdx.y];
    const int m0 = blockIdx.x * 128;
    if (m0 >= jb.M) return;
    const int tid = threadIdx.x;
    const int wid = tid >> 6;
    const int lane = tid & 63;

    {
        const uint16_t* Ab = jb.A + (size_t)m0 * 128;
        const uint16_t* Wb = jb.WT;
#pragma unroll
        for (int it = 0; it < 8; ++it) {
            int idx = it * 256 + tid;
            int r = idx >> 4, c = idx & 15;
            int gc = c ^ (r & 7);
            uint16_t* ldsA = As + (size_t)(it * 256 + wid * 64) * 8;
            uint16_t* ldsW = Ws + (size_t)(it * 256 + wid * 64) * 8;
            gload_lds16(Ab + (size_t)r * 128 + gc * 8, ldsA);
            gload_lds16(Wb + (size_t)r * 128 + gc * 8, ldsW);
        }
    }
    __syncthreads();

    const int wr = wid >> 1, wc = wid & 1;
    const int l15 = lane & 15, l4 = lane >> 4;
    const int mode = jb.mode;

    if (mode == M_B8) {
        // only the first 16-col strip matters (cols 0..7 nonzero in WT)
        f32x4 acc[4];
#pragma unroll
        for (int i = 0; i < 4; i++) acc[i] = (f32x4){0.f, 0.f, 0.f, 0.f};
#pragma unroll
        for (int kk = 0; kk < 4; ++kk) {
            bf16x8 af0;
            {
                int r = l15;
                int cc = (kk * 4 + l4) ^ (r & 7);
                af0 = *(const bf16x8*)(Ws + r * 128 + cc * 8);
            }
#pragma unroll
            for (int mi = 0; mi < 4; ++mi) {
                int r = wr * 64 + mi * 16 + l15;
                int cc = (kk * 4 + l4) ^ (r & 7);
                bf16x8 bf = *(const bf16x8*)(As + r * 128 + cc * 8);
                acc[mi] = __builtin_amdgcn_mfma_f32_16x16x32_bf16(af0, bf, acc[mi], 0, 0, 0);
            }
        }
        if (wc == 0 && l4 < 2) {
#pragma unroll
            for (int mi = 0; mi < 4; ++mi) {
                int gm = m0 + wr * 64 + mi * 16 + l15;
                if (gm < jb.M) {
                    f32x4 v = acc[mi];
                    *(float4*)((float*)jb.out + (size_t)gm * 8 + l4 * 4) =
                        make_float4(v.x, v.y, v.z, v.w);
                }
            }
        }
        return;
    }

    f32x4 acc[4][4];
#pragma unroll
    for (int i = 0; i < 4; i++)
#pragma unroll
        for (int j = 0; j < 4; j++) acc[i][j] = (f32x4){0.f, 0.f, 0.f, 0.f};

#pragma unroll
    for (int kk = 0; kk < 4; ++kk) {
        bf16x8 af[4], bff[4];
#pragma unroll
        for (int ni = 0; ni < 4; ++ni) {
            int r = wc * 64 + ni * 16 + l15;
            int cc = (kk * 4 + l4) ^ (r & 7);
            af[ni] = *(const bf16x8*)(Ws + r * 128 + cc * 8);
        }
#pragma unroll
        for (int mi = 0; mi < 4; ++mi) {
            int r = wr * 64 + mi * 16 + l15;
            int cc = (kk * 4 + l4) ^ (r & 7);
            bff[mi] = *(const bf16x8*)(As + r * 128 + cc * 8);
        }
#pragma unroll
        for (int ni = 0; ni < 4; ++ni)
#pragma unroll
            for (int mi = 0; mi < 4; ++mi)
                acc[ni][mi] = __builtin_amdgcn_mfma_f32_16x16x32_bf16(
                    af[ni], bff[mi], acc[ni][mi], 0, 0, 0);
    }

    if (mode == M_LN1 || mode == M_LN2) {
        // fused add-residual + LayerNorm over full 128-col rows
        __syncthreads();                      // all waves done reading Ws
        float* redS = (float*)Ws;             // [128][2]
        float* redQ = redS + 256;             // [128][2]
        float ps[4], qs[4];
#pragma unroll
        for (int mi = 0; mi < 4; ++mi) {
            int row = wr * 64 + mi * 16 + l15;
            int gm = m0 + row;
            float sum = 0.f, sq = 0.f;
#pragma unroll
            for (int ni = 0; ni < 4; ++ni) {
                int gn = wc * 64 + ni * 16 + l4 * 4;
                float r0 = 0.f, r1 = 0.f, r2 = 0.f, r3 = 0.f;
                if (gm < jb.M) {
                    if (mode == M_LN1) {
                        float4 rv = *(const float4*)((const float*)jb.resid + (size_t)gm * 128 + gn);
                        r0 = rv.x; r1 = rv.y; r2 = rv.z; r3 = rv.w;
                    } else {
                        ushort4 rv = *(const ushort4*)((const uint16_t*)jb.resid + (size_t)gm * 128 + gn);
                        r0 = bfu(rv.x); r1 = bfu(rv.y); r2 = bfu(rv.z); r3 = bfu(rv.w);
                    }
                }
                f32x4 t = acc[ni][mi];
                t.x += r0; t.y += r1; t.z += r2; t.w += r3;
                acc[ni][mi] = t;
                sum += t.x + t.y + t.z + t.w;
                sq  += t.x * t.x + t.y * t.y + t.z * t.z + t.w * t.w;
            }
            sum += __shfl_xor(sum, 16); sum += __shfl_xor(sum, 32);
            sq  += __shfl_xor(sq, 16);  sq  += __shfl_xor(sq, 32);
            ps[mi] = sum; qs[mi] = sq;
        }
        if (l4 == 0) {
#pragma unroll
            for (int mi = 0; mi < 4; ++mi) {
                int row = wr * 64 + mi * 16 + l15;
                redS[row * 2 + wc] = ps[mi];
                redQ[row * 2 + wc] = qs[mi];
            }
        }
        __syncthreads();
#pragma unroll
        for (int mi = 0; mi < 4; ++mi) {
            int row = wr * 64 + mi * 16 + l15;
            int gm = m0 + row;
            if (gm >= jb.M) continue;
            float S = redS[row * 2] + redS[row * 2 + 1];
            float Q = redQ[row * 2] + redQ[row * 2 + 1];
            float mean = S * (1.f / 128.f);
            float var  = Q * (1.f / 128.f) - mean * mean;
            float rstd = rsqrtf(var + 1e-5f);
#pragma unroll
            for (int ni = 0; ni < 4; ++ni) {
                int gn = wc * 64 + ni * 16 + l4 * 4;
                float4 gg = *(const float4*)(jb.lng + gn);
                float4 bb = *(const float4*)(jb.lnb + gn);
                f32x4 t = acc[ni][mi];
                float o0 = gg.x * (t.x - mean) * rstd + bb.x;
                float o1 = gg.y * (t.y - mean) * rstd + bb.y;
                float o2 = gg.z * (t.z - mean) * rstd + bb.z;
                float o3 = gg.w * (t.w - mean) * rstd + bb.w;
                if (mode == M_LN1) {
                    ushort4 o;
                    o.x = f2bf(o0); o.y = f2bf(o1); o.z = f2bf(o2); o.w = f2bf(o3);
                    *(ushort4*)((uint16_t*)jb.out + (size_t)gm * 128 + gn) = o;
                } else {
                    *(float4*)((float*)jb.out + (size_t)gm * 128 + gn) =
                        make_float4(o0, o1, o2, o3);
                }
            }
        }
        return;
    }

#pragma unroll
    for (int mi = 0; mi < 4; ++mi) {
        int gm = m0 + wr * 64 + mi * 16 + l15;
        if (gm >= jb.M) continue;
#pragma unroll
        for (int ni = 0; ni < 4; ++ni) {
            int gn = wc * 64 + ni * 16 + l4 * 4;
            f32x4 v = acc[ni][mi];
            if (mode == M_SIG || mode == M_GV) {
                float4 bb = *(const float4*)(jb.bias + gn);
                v.x = 1.f / (1.f + __expf(-(v.x + bb.x)));
                v.y = 1.f / (1.f + __expf(-(v.y + bb.y)));
                v.z = 1.f / (1.f + __expf(-(v.z + bb.z)));
                v.w = 1.f / (1.f + __expf(-(v.w + bb.w)));
            }
            if (mode == M_QS) { v.x *= QSC2; v.y *= QSC2; v.z *= QSC2; v.w *= QSC2; }
            if (mode == M_GV) {
                ushort4 vs = *(const ushort4*)(jb.aux + (size_t)gm * 128 + gn);
                v.x *= bfu(vs.x); v.y *= bfu(vs.y); v.z *= bfu(vs.z); v.w *= bfu(vs.w);
            }
            if (mode == M_KVIK || mode == M_KVIV || mode == M_GV) {
                int which = (mode == M_KVIK) ? 0 : 2;
                uint16_t* op = (uint16_t*)jb.out + (size_t)gm * 256 + gn * 2 + which;
                *reinterpret_cast<uint32_t*>(op)     = pk2bf(v.x, v.y);
                *reinterpret_cast<uint32_t*>(op + 4) = pk2bf(v.z, v.w);
            } else {
                ushort4 o;
                o.x = f2bf(v.x); o.y = f2bf(v.y); o.z = f2bf(v.z); o.w = f2bf(v.w);
                *reinterpret_cast<ushort4*>((uint16_t*)jb.out + (size_t)gm * 128 + gn) = o;
            }
        }
    }
}

// ---------------------------------------------------------------- prep casts (X, Xs, + zero bktcnt)
__global__ void castbf2_k(const float* __restrict__ in1, uint16_t* __restrict__ out1, int n1,
                          const float* __restrict__ in2, uint16_t* __restrict__ out2, int n2,
                          int* __restrict__ zero256)
{
    if (blockIdx.x == 0 && threadIdx.x < 256) zero256[threadIdx.x] = 0;
    int i = blockIdx.x * blockDim.x + threadIdx.x;
    int stride = gridDim.x * blockDim.x;
    for (; i < n1 + n2; i += stride) {
        float4 v;
        ushort4 o;
        if (i < n1) v = reinterpret_cast<const float4*>(in1)[i];
        else        v = reinterpret_cast<const float4*>(in2)[i - n1];
        o.x = f2bf(v.x); o.y = f2bf(v.y); o.z = f2bf(v.z); o.w = f2bf(v.w);
        if (i < n1) reinterpret_cast<ushort4*>(out1)[i] = o;
        else        reinterpret_cast<ushort4*>(out2)[i - n1] = o;
    }
}

// ---------------------------------------------------------------- 14-job weight transpose
// normal: WT[n*128+k] = bf16(W[k*nc+coff+n]); nc==8 (bias pad): n<8 -> w[k*8+n]*LOG2E else 0
struct WT14 { const float* src[14]; uint16_t* dst[14]; int nc[14]; int coff[14]; };
__global__ void castWT14_k(WT14 jb)
{
    int y = blockIdx.y;
    const float* W = jb.src[y];
    uint16_t* WT = jb.dst[y];
    int nc = jb.nc[y], coff = jb.coff[y];
    int i = blockIdx.x * 256 + threadIdx.x;   // 16384 per job
    int k = i >> 7, n = i & 127;
    float v;
    if (nc == 8) v = (n < 8) ? W[k * 8 + n] * LOG2E : 0.f;
    else         v = W[(size_t)k * nc + coff + n];
    WT[(size_t)n * 128 + k] = f2bf(v);
}

// ---------------------------------------------------------------- bucketed CSR build
#define NBKT_MAX 256

__global__ __launch_bounds__(256) void binH_k(
    const int* __restrict__ s1, const int* __restrict__ s2,
    int* __restrict__ bktcnt, int E1, int E2, int N, int shift, int nbkt, int chunk)
{
    __shared__ int hist[NBKT_MAX];
    int t = threadIdx.x;
    for (int i = t; i < nbkt; i += 256) hist[i] = 0;
    __syncthreads();
    int Et = E1 + E2;
    int base = blockIdx.x * chunk;
    int end = min(base + chunk, Et);
    for (int i = base + t; i < end; i += 256) {
        int seg = (i < E1) ? s1[i] : N + s2[i - E1];
        atomicAdd(&hist[seg >> shift], 1);
    }
    __syncthreads();
    for (int i = t; i < nbkt; i += 256)
        if (hist[i]) atomicAdd(&bktcnt[i], hist[i]);
}

__global__ __launch_bounds__(256) void bktscan_k(
    const int* __restrict__ bktcnt, int* __restrict__ bktbase,
    int* __restrict__ bktcur, int nbkt)
{
    __shared__ int wt[4];
    int t = threadIdx.x, lane = t & 63, w = t >> 6;
    int v = (t < nbkt) ? bktcnt[t] : 0;
    int s = v;
#pragma unroll
    for (int o = 1; o < 64; o <<= 1) { int x = __shfl_up(s, o); if (lane >= o) s += x; }
    if (lane == 63) wt[w] = s;
    __syncthreads();
    int add = 0;
    for (int i = 0; i < w; i++) add += wt[i];
    int excl = add + s - v;
    if (t < nbkt) { bktbase[t] = excl; bktcur[t] = excl; }
    if (t == nbkt - 1) bktbase[nbkt] = excl + v;
}

__global__ __launch_bounds__(256) void binA_k(
    const int* __restrict__ s1, const int* __restrict__ p1,
    const int* __restrict__ s2, const int* __restrict__ p2,
    int* __restrict__ bktcur, uint2* __restrict__ tmp,
    int E1, int E2, int N, int shift, int nbkt, int chunk)
{
    __shared__ int hist[NBKT_MAX];
    __shared__ int lcur[NBKT_MAX];
    int t = threadIdx.x;
    int Et = E1 + E2;
    int base = blockIdx.x * chunk;
    int end = min(base + chunk, Et);
    for (int i = t; i < nbkt; i += 256) hist[i] = 0;
    __syncthreads();
    for (int i = base + t; i < end; i += 256) {
        int seg = (i < E1) ? s1[i] : N + s2[i - E1];
        atomicAdd(&hist[seg >> shift], 1);
    }
    __syncthreads();
    for (int i = t; i < nbkt; i += 256) {
        int c = hist[i];
        lcur[i] = c ? atomicAdd(&bktcur[i], c) : 0;
    }
    __syncthreads();
    for (int i = base + t; i < end; i += 256) {
        int seg, pay;
        if (i < E1) { seg = s1[i]; pay = p1[i]; }
        else        { seg = N + s2[i - E1]; pay = p2[i - E1]; }
        int p = atomicAdd(&lcur[seg >> shift], 1);
        tmp[p] = make_uint2((uint32_t)seg, (uint32_t)pay);
    }
}

// one block per bucket: per-segment hist + LDS scan -> offs, then LDS-cursor scatter
__global__ __launch_bounds__(256) void binD_k(
    const uint2* __restrict__ tmp, const int* __restrict__ bktbase,
    int* __restrict__ offs, int* __restrict__ sorted, int NN, int spb, int Et)
{
    extern __shared__ int sh[];
    __shared__ int wt[4];
    int b = blockIdx.x, t = threadIdx.x;
    int s0 = b * spb;
    int segs = min(spb, NN - s0);
    for (int i = t; i < segs; i += 256) sh[i] = 0;
    __syncthreads();
    int p0 = bktbase[b], p1 = bktbase[b + 1];
    for (int i = p0 + t; i < p1; i += 256)
        atomicAdd(&sh[(int)tmp[i].x - s0], 1);
    __syncthreads();
    int e_per = spb >> 8;                 // 2 for spb=512
    int loc[4]; int ls = 0;
#pragma unroll 4
    for (int j = 0; j < 4; ++j) {
        if (j < e_per) {
            int idx = t * e_per + j;
            int v = (idx < segs) ? sh[idx] : 0;
            loc[j] = ls; ls += v;
        }
    }
    int lane = t & 63, w = t >> 6;
    int sc = ls;
#pragma unroll
    for (int o = 1; o < 64; o <<= 1) { int x = __shfl_up(sc, o); if (lane >= o) sc += x; }
    if (lane == 63) wt[w] = sc;
    __syncthreads();
    int add = 0;
    for (int i = 0; i < w; i++) add += wt[i];
    int texcl = add + sc - ls;
#pragma unroll 4
    for (int j = 0; j < 4; ++j) {
        if (j < e_per) {
            int idx = t * e_per + j;
            if (idx < segs) {
                int pos = p0 + texcl + loc[j];
                offs[s0 + idx] = pos;
                sh[idx] = pos;            // becomes cursor
            }
        }
    }
    __syncthreads();
    for (int i = p0 + t; i < p1; i += 256) {
        uint2 pr = tmp[i];
        int p = atomicAdd(&sh[(int)pr.x - s0], 1);
        sorted[p] = (int)pr.y;
    }
    if (b == 0 && t == 0) offs[NN] = Et;
}

// ---------------------------------------------------------------- self-attention (max-free, exp2 domain)
#define SEDGE(J, IDX)                                                            \
    {                                                                            \
        int dst = sdst[IDX];                                                     \
        uint2 kv = *reinterpret_cast<const uint2*>(kb + ((size_t)dst << 8));     \
        float s = q0 * bf_lo(kv.x) + q1 * bf_hi(kv.x);                           \
        s += __shfl_xor(s, 1); s += __shfl_xor(s, 2); s += __shfl_xor(s, 4);     \
        float w = exp2f(s + bs);                                                 \
        pa##J = fmaf(w, bf_lo(kv.y), pa##J);                                     \
        pb##J = fmaf(w, bf_hi(kv.y), pb##J);                                     \
        dn##J += w;                                                              \
    }

__global__ __launch_bounds__(256) void self_attn_k(
    const uint16_t* __restrict__ Qb, const uint16_t* __restrict__ kvi,
    const float* __restrict__ bias1,
    const int* __restrict__ offs, const int* __restrict__ sdst,
    const uint16_t* __restrict__ g16, uint16_t* __restrict__ Aout, int N)
{
    int lane = threadIdx.x & 63;
    int n = blockIdx.x * 4 + (threadIdx.x >> 6);
    if (n >= N) return;
    uint32_t qw = *reinterpret_cast<const uint32_t*>(Qb + (size_t)n * 128 + 2 * lane);
    float q0 = bf_lo(qw), q1 = bf_hi(qw);
    float bs = bias1[(size_t)n * 8 + (lane >> 3)];
    int e0 = offs[n], e1 = offs[n + 1];
    const uint16_t* kb = kvi + lane * 4;
    float dn0 = 0.f, pa0 = 0.f, pb0 = 0.f;
    float dn1 = 0.f, pa1 = 0.f, pb1 = 0.f;
    int e = e0;
    for (; e + 4 <= e1; e += 4) {
        SEDGE(0, e)
        SEDGE(1, e + 1)
        SEDGE(0, e + 2)
        SEDGE(1, e + 3)
    }
    for (; e < e1; ++e) SEDGE(0, e)
    float den = dn0 + dn1, a0 = pa0 + pa1, a1 = pb0 + pb1;
    float inv = 1.f / (den + 1e-30f);
    uint32_t gw = *reinterpret_cast<const uint32_t*>(g16 + (size_t)n * 128 + 2 * lane);
    a0 *= inv * bf_lo(gw); a1 *= inv * bf_hi(gw);
    *reinterpret_cast<uint32_t*>(Aout + (size_t)n * 128 + 2 * lane) = pk2bf(a0, a1);
}

// ---------------------------------------------------------------- cross-attention (max-free, V pre-gated)
#define CEDGE(J, IDX)                                                            \
    {                                                                            \
        int src = ssrc[IDX];                                                     \
        uint2 kv = *reinterpret_cast<const uint2*>(kb + ((size_t)src << 8));     \
        float bss = bias_s[(size_t)src * 8 + (lane >> 3)];                       \
        float s = q0 * bf_lo(kv.x) + q1 * bf_hi(kv.x);                           \
        s += __shfl_xor(s, 1); s += __shfl_xor(s, 2); s += __shfl_xor(s, 4);     \
        float w = exp2f(s + bt + bss);                                           \
        pa##J = fmaf(w, bf_lo(kv.y), pa##J);                                     \
        pb##J = fmaf(w, bf_hi(kv.y), pb##J);                                     \
        dn##J += w;                                                              \
    }

__global__ __launch_bounds__(256) void cross_attn_k(
    const uint16_t* __restrict__ Qcb, const float* __restrict__ bias_t,
    const uint16_t* __restrict__ kvgi, const float* __restrict__ bias_s,
    const int* __restrict__ offs, const int* __restrict__ ssrc,
    const uint16_t* __restrict__ g16, uint16_t* __restrict__ Aout, int N)
{
    int lane = threadIdx.x & 63;
    int n = blockIdx.x * 4 + (threadIdx.x >> 6);
    if (n >= N) return;
    uint32_t qw = *reinterpret_cast<const uint32_t*>(Qcb + (size_t)n * 128 + 2 * lane);
    float q0 = bf_lo(qw), q1 = bf_hi(qw);
    float bt = bias_t[(size_t)n * 8 + (lane >> 3)];
    int e0 = offs[n], e1 = offs[n + 1];
    const uint16_t* kb = kvgi + lane * 4;
    float dn0 = 0.f, pa0 = 0.f, pb0 = 0.f;
    float dn1 = 0.f, pa1 = 0.f, pb1 = 0.f;
    int e = e0;
    for (; e + 4 <= e1; e += 4) {
        CEDGE(0, e)
        CEDGE(1, e + 1)
        CEDGE(0, e + 2)
        CEDGE(1, e + 3)
    }
    for (; e < e1; ++e) CEDGE(0, e)
    float den = dn0 + dn1, a0 = pa0 + pa1, a1 = pb0 + pb1;
    float inv = 1.f / (den + 1e-30f);
    uint32_t gw = *reinterpret_cast<const uint32_t*>(g16 + (size_t)n * 128 + 2 * lane);
    a0 *= inv * bf_lo(gw); a1 *= inv * bf_hi(gw);
    *reinterpret_cast<uint32_t*>(Aout + (size_t)n * 128 + 2 * lane) = pk2bf(a0, a1);
}

// ---------------------------------------------------------------- host
static inline size_t smax_(size_t a, size_t b) { return a > b ? a : b; }

extern "C" void kernel_launch(void* const* d_in, const int* in_sizes, int n_in,
                              void* d_out, int out_size, void* d_ws, size_t ws_size,
                              hipStream_t stream)
{
    const float* X          = (const float*)d_in[0];
    const float* Xs         = (const float*)d_in[1];
    const float* W_qkv      = (const float*)d_in[2];
    const float* w_bias     = (const float*)d_in[3];
    const float* W_gate     = (const float*)d_in[4];
    const float* b_gate     = (const float*)d_in[5];
    const float* W_o        = (const float*)d_in[6];
    const float* W_q        = (const float*)d_in[7];
    const float* W_kv       = (const float*)d_in[8];
    const float* w_bias_tgt = (const float*)d_in[9];
    const float* w_bias_src = (const float*)d_in[10];
    const float* W_gate_tgt = (const float*)d_in[11];
    const float* b_gate_tgt = (const float*)d_in[12];
    const float* W_gate_src = (const float*)d_in[13];
    const float* b_gate_src = (const float*)d_in[14];
    const float* W_o2       = (const float*)d_in[15];
    const float* ln1_g      = (const float*)d_in[16];
    const float* ln1_b      = (const float*)d_in[17];
    const float* ln2_g      = (const float*)d_in[18];
    const float* ln2_b      = (const float*)d_in[19];
    const int* nbr_src      = (const int*)d_in[20];
    const int* nbr_dst      = (const int*)d_in[21];
    const int* inc_tgt      = (const int*)d_in[22];
    const int* inc_src      = (const int*)d_in[23];

    const int N  = in_sizes[0] / 128;
    const int NS = in_sizes[1] / 128;
    const int E1 = in_sizes[20];
    const int E2 = in_sizes[22];
    const int Et = E1 + E2;
    const int NN = 2 * N;
    const int Npad  = (N + 127) & ~127;
    const int NSpad = (NS + 127) & ~127;

    // bucket geometry
    int shift = 9;
    while (((NN + (1 << shift) - 1) >> shift) > NBKT_MAX) ++shift;
    const int spb  = 1 << shift;
    const int nbkt = (NN + spb - 1) >> shift;

    char* ws = (char*)d_ws;
    size_t off = 0;
    auto alloc = [&](size_t bytes) -> void* {
        void* p = ws + off;
        off = (off + bytes + 255) & ~(size_t)255;
        return p;
    };

    uint16_t* Xb   = (uint16_t*)alloc((size_t)Npad * 128 * 2);
    uint16_t* Xsb  = (uint16_t*)alloc((size_t)NSpad * 128 * 2);
    uint16_t* WTq  = (uint16_t*)alloc((size_t)384 * 128 * 2);
    uint16_t* WTkv = (uint16_t*)alloc((size_t)256 * 128 * 2);
    uint16_t* WTg  = (uint16_t*)alloc((size_t)128 * 128 * 2);
    uint16_t* WTo  = (uint16_t*)alloc((size_t)128 * 128 * 2);
    uint16_t* WTq2 = (uint16_t*)alloc((size_t)128 * 128 * 2);
    uint16_t* WTgt = (uint16_t*)alloc((size_t)128 * 128 * 2);
    uint16_t* WTgs = (uint16_t*)alloc((size_t)128 * 128 * 2);
    uint16_t* WTo2 = (uint16_t*)alloc((size_t)128 * 128 * 2);
    uint16_t* WTb1 = (uint16_t*)alloc((size_t)128 * 128 * 2);   // w_bias pad
    uint16_t* WTbt = (uint16_t*)alloc((size_t)128 * 128 * 2);   // w_bias_tgt pad
    uint16_t* WTbs = (uint16_t*)alloc((size_t)128 * 128 * 2);   // w_bias_src pad
    size_t s1a = (size_t)Npad * 384 * 2;
    size_t s1b = (size_t)NSpad * 384 * 2;
    size_t s1c = (size_t)Et * 8;
    uint16_t* S1 = (uint16_t*)alloc(smax_(smax_(s1a, s1b), s1c));
    uint16_t* Qb   = S1;
    uint16_t* kvi  = S1 + (size_t)Npad * 128;
    uint16_t* kvgi = S1;
    uint16_t* V16  = S1 + (size_t)NSpad * 256;
    uint2*    tmp  = (uint2*)S1;          // CSR pairs; dead before S1 reused
    uint16_t* g16  = (uint16_t*)alloc((size_t)N * 128 * 2);
    uint16_t* Qcb  = (uint16_t*)alloc((size_t)N * 128 * 2);
    uint16_t* Awo  = (uint16_t*)alloc((size_t)Npad * 128 * 2);
    uint16_t* hb   = (uint16_t*)alloc((size_t)Npad * 128 * 2);
    float*    b8a  = (float*)alloc((size_t)N * 8 * 4);
    float*    b8s  = (float*)alloc((size_t)NS * 8 * 4);
    int* offs   = (int*)alloc((size_t)(NN + 1) * 4);
    int* sorted = (int*)alloc((size_t)Et * 4);
    int* bktcnt = (int*)alloc((size_t)NBKT_MAX * 4);
    int* bktbase= (int*)alloc((size_t)(NBKT_MAX + 1) * 4);
    int* bktcur = (int*)alloc((size_t)NBKT_MAX * 4);
    (void)ws_size; (void)n_in; (void)out_size;

    const int gA  = Npad / 128;
    const int gAs = NSpad / 128;
    const int gW  = (N + 3) / 4;
    const int BINB = 128;
    const int chunk = (Et + BINB - 1) / BINB;

    // 1. prep casts (+ zero bktcnt)
    castbf2_k<<<2048, 256, 0, stream>>>(X, Xb, N * 32, Xs, Xsb, NS * 32, bktcnt);
    // 2. weight transposes (11 weights + 3 zero-padded bias tiles)
    {
        WT14 jb;
        jb.src[0] = W_qkv; jb.dst[0] = WTq;          jb.nc[0] = 384; jb.coff[0] = 0;
        jb.src[1] = W_qkv; jb.dst[1] = WTq + 16384;  jb.nc[1] = 384; jb.coff[1] = 128;
        jb.src[2] = W_qkv; jb.dst[2] = WTq + 32768;  jb.nc[2] = 384; jb.coff[2] = 256;
        jb.src[3] = W_kv;  jb.dst[3] = WTkv;         jb.nc[3] = 256; jb.coff[3] = 0;
        jb.src[4] = W_kv;  jb.dst[4] = WTkv + 16384; jb.nc[4] = 256; jb.coff[4] = 128;
        jb.src[5] = W_gate;     jb.dst[5] = WTg;  jb.nc[5] = 128; jb.coff[5] = 0;
        jb.src[6] = W_o;        jb.dst[6] = WTo;  jb.nc[6] = 128; jb.coff[6] = 0;
        jb.src[7] = W_q;        jb.dst[7] = WTq2; jb.nc[7] = 128; jb.coff[7] = 0;
        jb.src[8] = W_gate_tgt; jb.dst[8] = WTgt; jb.nc[8] = 128; jb.coff[8] = 0;
        jb.src[9] = W_gate_src; jb.dst[9] = WTgs; jb.nc[9] = 128; jb.coff[9] = 0;
        jb.src[10]= W_o2;       jb.dst[10]= WTo2; jb.nc[10]= 128; jb.coff[10]= 0;
        jb.src[11]= w_bias;     jb.dst[11]= WTb1; jb.nc[11]= 8;   jb.coff[11]= 0;
        jb.src[12]= w_bias_tgt; jb.dst[12]= WTbt; jb.nc[12]= 8;   jb.coff[12]= 0;
        jb.src[13]= w_bias_src; jb.dst[13]= WTbs; jb.nc[13]= 8;   jb.coff[13]= 0;
        castWT14_k<<<dim3(64, 14), 256, 0, stream>>>(jb);
    }

    // 3-6. bucketed CSR (both edge lists, 2N segments)
    binH_k<<<BINB, 256, 0, stream>>>(nbr_src, inc_tgt, bktcnt, E1, E2, N, shift, nbkt, chunk);
    bktscan_k<<<1, 256, 0, stream>>>(bktcnt, bktbase, bktcur, nbkt);
    binA_k<<<BINB, 256, 0, stream>>>(nbr_src, nbr_dst, inc_tgt, inc_src,
                                     bktcur, tmp, E1, E2, N, shift, nbkt, chunk);
    binD_k<<<nbkt, 256, spb * 4, stream>>>(tmp, bktbase, offs, sorted, NN, spb, Et);

    // 7. stage-1 projections: Q(x0.25*log2e), K, V interleaved, gate, bias8
    {
        GemmJobs jb{};
        jb.j[0] = { Xb, WTq,         nullptr, nullptr, nullptr, nullptr, nullptr, Qb,  N, M_QS };
        jb.j[1] = { Xb, WTq + 16384, nullptr, nullptr, nullptr, nullptr, nullptr, kvi, N, M_KVIK };
        jb.j[2] = { Xb, WTq + 32768, nullptr, nullptr, nullptr, nullptr, nullptr, kvi, N, M_KVIV };
        jb.j[3] = { Xb, WTg,         b_gate,  nullptr, nullptr, nullptr, nullptr, g16, N, M_SIG };
        jb.j[4] = { Xb, WTb1,        nullptr, nullptr, nullptr, nullptr, nullptr, b8a, N, M_B8 };
        multi_gemm_k<<<dim3(gA, 5), 256, 0, stream>>>(jb);
    }
    // 8. self-attention
    self_attn_k<<<gW, 256, 0, stream>>>(Qb, kvi, b8a, offs, sorted, g16, Awo, N);
    // 9. W_o GEMM + fused add+LN -> hb (bf16)
    {
        GemmJobs jb{};
        jb.j[0] = { Awo, WTo, nullptr, nullptr, X, ln1_g, ln1_b, hb, N, M_LN1 };
        multi_gemm_k<<<dim3(gA, 1), 256, 0, stream>>>(jb);
    }
    // 10. stage-2 projections: Qc, gate_tgt, KV-K, V16, bias8_tgt
    {
        GemmJobs jb{};
        jb.j[0] = { hb,  WTq2,         nullptr,    nullptr, nullptr, nullptr, nullptr, Qcb,  N,  M_QS };
        jb.j[1] = { hb,  WTgt,         b_gate_tgt, nullptr, nullptr, nullptr, nullptr, g16,  N,  M_SIG };
        jb.j[2] = { Xsb, WTkv,         nullptr,    nullptr, nullptr, nullptr, nullptr, kvgi, NS, M_KVIK };
        jb.j[3] = { Xsb, WTkv + 16384, nullptr,    nullptr, nullptr, nullptr, nullptr, V16,  NS, M_BF16 };
        jb.j[4] = { hb,  WTbt,         nullptr,    nullptr, nullptr, nullptr, nullptr, b8a,  N,  M_B8 };
        multi_gemm_k<<<dim3(gAs, 5), 256, 0, stream>>>(jb);
    }
    // 11. gv = sigmoid(Xs@Wgs+b) * Vc -> interleaved V slot; bias8_src
    {
        GemmJobs jb{};
        jb.j[0] = { Xsb, WTgs, b_gate_src, V16, nullptr, nullptr, nullptr, kvgi, NS, M_GV };
        jb.j[1] = { Xsb, WTbs, nullptr, nullptr, nullptr, nullptr, nullptr, b8s,  NS, M_B8 };
        multi_gemm_k<<<dim3(gAs, 2), 256, 0, stream>>>(jb);
    }
    // 12. cross-attention
    cross_attn_k<<<gW, 256, 0, stream>>>(Qcb, b8a, kvgi, b8s, offs + N, sorted, g16, Awo, N);
    // 13. W_o2 GEMM + fused add+LN -> d_out (f32)
    {
        GemmJobs jb{};
        jb.j[0] = { Awo, WTo2, nullptr, nullptr, hb, ln2_g, ln2_b, d_out, N, M_LN2 };
        multi_gemm_k<<<dim3(gA, 1), 256, 0, stream>>>(jb);
    }
}